// Round 1
// baseline (15608.701 us; speedup 1.0000x reference)
//
#include <hip/hip_runtime.h>
#include <hip/hip_bf16.h>
#include <math.h>

#define LAYERS 6
#define BB 4
#define TT 1024
#define EE 768
#define HH 12
#define HS 64
#define VV 32000
#define FFD 3072
#define MROWS (BB * TT)   // 4096

// ---------------- reductions (block = 256 threads = 4 waves) ----------------
__device__ __forceinline__ float wave_sum(float v) {
#pragma unroll
    for (int o = 32; o > 0; o >>= 1) v += __shfl_xor(v, o);
    return v;
}
__device__ __forceinline__ float wave_max(float v) {
#pragma unroll
    for (int o = 32; o > 0; o >>= 1) v = fmaxf(v, __shfl_xor(v, o));
    return v;
}
__device__ __forceinline__ float block_sum256(float v, float* red) {
    v = wave_sum(v);
    int tid = threadIdx.x;
    if ((tid & 63) == 0) red[tid >> 6] = v;
    __syncthreads();
    float r = red[0] + red[1] + red[2] + red[3];
    __syncthreads();
    return r;
}
__device__ __forceinline__ float block_max256(float v, float* red) {
    v = wave_max(v);
    int tid = threadIdx.x;
    if ((tid & 63) == 0) red[tid >> 6] = v;
    __syncthreads();
    float r = fmaxf(fmaxf(red[0], red[1]), fmaxf(red[2], red[3]));
    __syncthreads();
    return r;
}

// ---------------- embedding: x = tok_emb[idx] + pos_emb[t] ----------------
__global__ __launch_bounds__(256) void embed_k(const int* __restrict__ idx,
                                               const float* __restrict__ tok,
                                               const float* __restrict__ pos,
                                               float* __restrict__ x) {
    int row = blockIdx.x;            // b*T + t
    int t = row & (TT - 1);
    int token = idx[row];
    const float* te = tok + (size_t)token * EE;
    const float* pe = pos + (size_t)t * EE;
    float* xr = x + (size_t)row * EE;
    for (int i = threadIdx.x; i < EE; i += 256) xr[i] = te[i] + pe[i];
}

// ---------------- LayerNorm (two-pass, row in LDS) ----------------
__global__ __launch_bounds__(256) void ln_k(const float* __restrict__ x,
                                            const float* __restrict__ g,
                                            const float* __restrict__ b,
                                            float* __restrict__ out) {
    __shared__ float sr[EE];
    __shared__ float red[4];
    int row = blockIdx.x;
    const float* xr = x + (size_t)row * EE;
    int tid = threadIdx.x;
    float s = 0.f;
    for (int i = tid; i < EE; i += 256) { float v = xr[i]; sr[i] = v; s += v; }
    s = block_sum256(s, red);
    float m = s * (1.0f / EE);
    float vs = 0.f;
    for (int i = tid; i < EE; i += 256) { float d = sr[i] - m; vs += d * d; }
    vs = block_sum256(vs, red);
    float rstd = rsqrtf(vs * (1.0f / EE) + 1e-5f);
    float* orow = out + (size_t)row * EE;
    for (int i = tid; i < EE; i += 256) orow[i] = (sr[i] - m) * rstd * g[i] + b[i];
}

// ---------------- SGEMM: C[M,N] (+)= A[M,K] @ B[K,N] (+bias) (relu) --------
// 64x64 tile, BK=16, 256 threads, 4x4 microtile.
template <bool BIAS, bool RELU, bool ACCUM>
__global__ __launch_bounds__(256) void sgemm_k(const float* __restrict__ A,
                                               const float* __restrict__ Bw,
                                               const float* __restrict__ bias,
                                               float* __restrict__ C,
                                               int N, int K) {
    __shared__ float As[64][17];
    __shared__ __align__(16) float Bs[16][64];
    const int tid = threadIdx.x;
    const int tx = tid & 15, ty = tid >> 4;
    const int m0 = blockIdx.y * 64, n0 = blockIdx.x * 64;

    float acc[4][4];
#pragma unroll
    for (int i = 0; i < 4; ++i)
#pragma unroll
        for (int j = 0; j < 4; ++j) acc[i][j] = 0.f;

    const int ar = tid >> 2, ac = (tid & 3) << 2;   // A tile: row 0..63, col chunk
    const int br = tid >> 4, bc = (tid & 15) << 2;  // B tile: row 0..15, col chunk

    for (int k0 = 0; k0 < K; k0 += 16) {
        float4 av = *reinterpret_cast<const float4*>(&A[(size_t)(m0 + ar) * K + k0 + ac]);
        As[ar][ac + 0] = av.x; As[ar][ac + 1] = av.y;
        As[ar][ac + 2] = av.z; As[ar][ac + 3] = av.w;
        *reinterpret_cast<float4*>(&Bs[br][bc]) =
            *reinterpret_cast<const float4*>(&Bw[(size_t)(k0 + br) * N + n0 + bc]);
        __syncthreads();
#pragma unroll
        for (int kk = 0; kk < 16; ++kk) {
            float a[4], b[4];
#pragma unroll
            for (int i = 0; i < 4; ++i) a[i] = As[ty * 4 + i][kk];
#pragma unroll
            for (int j = 0; j < 4; ++j) b[j] = Bs[kk][tx * 4 + j];
#pragma unroll
            for (int i = 0; i < 4; ++i)
#pragma unroll
                for (int j = 0; j < 4; ++j) acc[i][j] = fmaf(a[i], b[j], acc[i][j]);
        }
        __syncthreads();
    }

#pragma unroll
    for (int i = 0; i < 4; ++i) {
        int row = m0 + ty * 4 + i;
#pragma unroll
        for (int j = 0; j < 4; ++j) {
            int col = n0 + tx * 4 + j;
            float v = acc[i][j];
            if (BIAS) v += bias[col];
            if (RELU) v = fmaxf(v, 0.f);
            size_t off = (size_t)row * N + col;
            if (ACCUM) C[off] += v; else C[off] = v;
        }
    }
}

// ---------------- causal attention: one block per (b, h, tq) ----------------
__global__ __launch_bounds__(256) void attn_k(const float* __restrict__ q,
                                              const float* __restrict__ k,
                                              const float* __restrict__ v,
                                              float* __restrict__ o) {
    __shared__ float qs[HS];
    __shared__ float p[TT];
    __shared__ float red[4];
    __shared__ float ov[4][HS];

    int bid = blockIdx.x;           // b*H*T + h*T + tq
    int tq = bid & (TT - 1);
    int bh = bid >> 10;             // T == 1024
    int hh = bh % HH;
    int bI = bh / HH;
    int tid = threadIdx.x;

    const size_t rowbase = (size_t)bI * TT;
    const float* qrow = q + (rowbase + tq) * EE + hh * HS;
    if (tid < HS) qs[tid] = qrow[tid] * 0.125f;   // 1/sqrt(64)
    __syncthreads();

    const int nk = tq + 1;
    float lmax = -INFINITY;
    for (int j = tid; j < nk; j += 256) {
        const float* krow = k + (rowbase + j) * EE + hh * HS;
        float s = 0.f;
#pragma unroll
        for (int d = 0; d < HS; ++d) s = fmaf(qs[d], krow[d], s);
        p[j] = s;
        lmax = fmaxf(lmax, s);
    }
    float m = block_max256(lmax, red);
    float lsum = 0.f;
    for (int j = tid; j < nk; j += 256) {
        float e = __expf(p[j] - m);
        p[j] = e;
        lsum += e;
    }
    float S = block_sum256(lsum, red);
    float inv = 1.0f / S;

    int d = tid & 63, grp = tid >> 6;
    float accd = 0.f;
    for (int j = grp; j < nk; j += 4)
        accd = fmaf(p[j], v[(rowbase + j) * EE + hh * HS + d], accd);
    ov[grp][d] = accd;
    __syncthreads();
    if (tid < HS) {
        float r = (ov[0][tid] + ov[1][tid] + ov[2][tid] + ov[3][tid]) * inv;
        o[(rowbase + tq) * EE + hh * HS + tid] = r;
    }
}

// ---------------- per-row logsumexp loss ----------------
__global__ __launch_bounds__(256) void rowloss_k(const float* __restrict__ logits,
                                                 const int* __restrict__ targets,
                                                 float* __restrict__ rowloss) {
    __shared__ float red[4];
    int row = blockIdx.x;
    const float* lr = logits + (size_t)row * VV;
    int tid = threadIdx.x;
    float m = -INFINITY;
    for (int j = tid; j < VV; j += 256) m = fmaxf(m, lr[j]);
    m = block_max256(m, red);
    float s = 0.f;
    for (int j = tid; j < VV; j += 256) s += __expf(lr[j] - m);
    s = block_sum256(s, red);
    if (tid == 0) rowloss[row] = logf(s) + m - lr[targets[row]];
}

__global__ __launch_bounds__(256) void loss_final_k(const float* __restrict__ rowloss,
                                                    float* __restrict__ out) {
    __shared__ float red[4];
    float s = 0.f;
    for (int i = threadIdx.x; i < MROWS; i += 256) s += rowloss[i];
    s = block_sum256(s, red);
    if (threadIdx.x == 0) out[0] = s * (1.0f / MROWS);
}

// ---------------- launcher ----------------
extern "C" void kernel_launch(void* const* d_in, const int* in_sizes, int n_in,
                              void* d_out, int out_size, void* d_ws, size_t ws_size,
                              hipStream_t stream) {
    const int* idx      = (const int*)d_in[0];
    const int* targets  = (const int*)d_in[1];
    const float* tok    = (const float*)d_in[2];
    const float* pos    = (const float*)d_in[3];
    const float* Wq     = (const float*)d_in[4];
    const float* Wk     = (const float*)d_in[5];
    const float* Wv     = (const float*)d_in[6];
    const float* Wp     = (const float*)d_in[7];
    const float* bp     = (const float*)d_in[8];
    const float* W1     = (const float*)d_in[9];
    const float* b1     = (const float*)d_in[10];
    const float* W2     = (const float*)d_in[11];
    const float* b2     = (const float*)d_in[12];
    const float* ln1_g  = (const float*)d_in[13];
    const float* ln1_b  = (const float*)d_in[14];
    const float* ln2_g  = (const float*)d_in[15];
    const float* ln2_b  = (const float*)d_in[16];
    const float* lnf_g  = (const float*)d_in[17];
    const float* lnf_b  = (const float*)d_in[18];
    const float* Wlm    = (const float*)d_in[19];
    const float* blm    = (const float*)d_in[20];

    float* out = (float*)d_out;

    // workspace layout (units of U = MROWS*EE floats):
    // [0]=x  [1]=h (also attn out o)  [2]=q  [3]=k  [4]=v  [5]=extra
    // ff1 aliases [2..5] (MROWS*FFD = 4U)   rowloss at [6]
    float* ws = (float*)d_ws;
    const size_t U = (size_t)MROWS * EE;
    float* x   = ws;
    float* h   = ws + U;
    float* qb  = ws + 2 * U;
    float* kb  = ws + 3 * U;
    float* vb  = ws + 4 * U;
    float* ff1 = qb;                    // spans 4U
    float* rowloss = ws + 6 * U;

    dim3 blk(256);
    dim3 gEE(EE / 64, MROWS / 64);
    dim3 gFF(FFD / 64, MROWS / 64);
    dim3 gV(VV / 64, MROWS / 64);

    embed_k<<<MROWS, blk, 0, stream>>>(idx, tok, pos, x);

    for (int l = 0; l < LAYERS; ++l) {
        const float* wq = Wq + (size_t)l * EE * EE;
        const float* wk = Wk + (size_t)l * EE * EE;
        const float* wv = Wv + (size_t)l * EE * EE;
        const float* wp = Wp + (size_t)l * EE * EE;
        const float* w1 = W1 + (size_t)l * EE * FFD;
        const float* w2 = W2 + (size_t)l * FFD * EE;

        ln_k<<<MROWS, blk, 0, stream>>>(x, ln1_g + l * EE, ln1_b + l * EE, h);
        sgemm_k<false, false, false><<<gEE, blk, 0, stream>>>(h, wq, nullptr, qb, EE, EE);
        sgemm_k<false, false, false><<<gEE, blk, 0, stream>>>(h, wk, nullptr, kb, EE, EE);
        sgemm_k<false, false, false><<<gEE, blk, 0, stream>>>(h, wv, nullptr, vb, EE, EE);
        attn_k<<<BB * HH * TT, blk, 0, stream>>>(qb, kb, vb, h);   // o -> h
        sgemm_k<true, false, true><<<gEE, blk, 0, stream>>>(h, wp, bp + l * EE, x, EE, EE);
        ln_k<<<MROWS, blk, 0, stream>>>(x, ln2_g + l * EE, ln2_b + l * EE, h);
        sgemm_k<true, true, false><<<gFF, blk, 0, stream>>>(h, w1, b1 + l * FFD, ff1, FFD, EE);
        sgemm_k<true, false, true><<<gEE, blk, 0, stream>>>(ff1, w2, b2 + l * EE, x, EE, FFD);
    }

    ln_k<<<MROWS, blk, 0, stream>>>(x, lnf_g, lnf_b, h);
    sgemm_k<true, false, false><<<gV, blk, 0, stream>>>(h, Wlm, blm, out, VV, EE);
    rowloss_k<<<MROWS, blk, 0, stream>>>(out, targets, rowloss);
    loss_final_k<<<1, blk, 0, stream>>>(rowloss, out + (size_t)MROWS * VV);
}

// Round 2
// 8284.792 us; speedup vs baseline: 1.8840x; 1.8840x over previous
//
#include <hip/hip_runtime.h>
#include <hip/hip_bf16.h>
#include <math.h>

#define LAYERS 6
#define BB 4
#define TT 1024
#define EE 768
#define HH 12
#define HS 64
#define VV 32000
#define FFD 3072
#define MROWS (BB * TT)   // 4096
#define QS (3 * EE)       // 2304, fused qkv row stride

typedef __attribute__((ext_vector_type(8))) short bf16x8_t;
typedef __attribute__((ext_vector_type(4))) float f32x4_t;

// ---------------- helpers ----------------
__device__ __forceinline__ float wave_sum(float v) {
#pragma unroll
    for (int o = 32; o > 0; o >>= 1) v += __shfl_xor(v, o);
    return v;
}
__device__ __forceinline__ float wave_max(float v) {
#pragma unroll
    for (int o = 32; o > 0; o >>= 1) v = fmaxf(v, __shfl_xor(v, o));
    return v;
}
__device__ __forceinline__ float block_sum256(float v, float* red) {
    v = wave_sum(v);
    int tid = threadIdx.x;
    if ((tid & 63) == 0) red[tid >> 6] = v;
    __syncthreads();
    float r = red[0] + red[1] + red[2] + red[3];
    __syncthreads();
    return r;
}
__device__ __forceinline__ float block_max256(float v, float* red) {
    v = wave_max(v);
    int tid = threadIdx.x;
    if ((tid & 63) == 0) red[tid >> 6] = v;
    __syncthreads();
    float r = fmaxf(fmaxf(red[0], red[1]), fmaxf(red[2], red[3]));
    __syncthreads();
    return r;
}
__device__ __forceinline__ float bflo(unsigned int v) { return __uint_as_float(v << 16); }
__device__ __forceinline__ float bfhi(unsigned int v) { return __uint_as_float(v & 0xffff0000u); }

__device__ __forceinline__ void gload_lds16(const void* g, void* l) {
    __builtin_amdgcn_global_load_lds((const __attribute__((address_space(1))) void*)g,
                                     (__attribute__((address_space(3))) void*)l, 16, 0, 0);
}

// ---------------- embedding: x = tok_emb[idx] + pos_emb[t] (fp32) ----------------
__global__ __launch_bounds__(256) void embed_k(const int* __restrict__ idx,
                                               const float* __restrict__ tok,
                                               const float* __restrict__ pos,
                                               float* __restrict__ x) {
    int row = blockIdx.x;
    int t = row & (TT - 1);
    int token = idx[row];
    const float* te = tok + (size_t)token * EE;
    const float* pe = pos + (size_t)t * EE;
    float* xr = x + (size_t)row * EE;
    for (int i = threadIdx.x; i < EE; i += 256) xr[i] = te[i] + pe[i];
}

// ---------------- LayerNorm: fp32 in -> bf16 out ----------------
__global__ __launch_bounds__(256) void ln_k(const float* __restrict__ x,
                                            const float* __restrict__ g,
                                            const float* __restrict__ b,
                                            __hip_bfloat16* __restrict__ out) {
    __shared__ float sr[EE];
    __shared__ float red[4];
    int row = blockIdx.x;
    const float* xr = x + (size_t)row * EE;
    int tid = threadIdx.x;
    float s = 0.f;
    for (int i = tid; i < EE; i += 256) { float v = xr[i]; sr[i] = v; s += v; }
    s = block_sum256(s, red);
    float m = s * (1.0f / EE);
    float vs = 0.f;
    for (int i = tid; i < EE; i += 256) { float d = sr[i] - m; vs += d * d; }
    vs = block_sum256(vs, red);
    float rstd = rsqrtf(vs * (1.0f / EE) + 1e-5f);
    __hip_bfloat16* orow = out + (size_t)row * EE;
    for (int i = tid; i < EE; i += 256)
        orow[i] = __float2bfloat16((sr[i] - m) * rstd * g[i] + b[i]);
}

// ---------------- transpose-convert: W fp32 [R,C] -> WT bf16 [C,R] ----------------
__global__ __launch_bounds__(256) void tconv_k(const float* __restrict__ W,
                                               __hip_bfloat16* __restrict__ WT,
                                               int R, int C) {
    __shared__ float t[32][33];
    int c0 = blockIdx.x * 32, r0 = blockIdx.y * 32;
    int tx = threadIdx.x & 31, ty = threadIdx.x >> 5;   // ty: 0..7
#pragma unroll
    for (int i = 0; i < 4; ++i)
        t[ty + 8 * i][tx] = W[(size_t)(r0 + ty + 8 * i) * C + c0 + tx];
    __syncthreads();
#pragma unroll
    for (int i = 0; i < 4; ++i)
        WT[(size_t)(c0 + ty + 8 * i) * R + r0 + tx] = __float2bfloat16(t[tx][ty + 8 * i]);
}

// ---------------- MFMA GEMM: C[M,N] (+)= A[M,K] @ BT[N,K]^T (+bias)(relu) ----------
// 128x128 tile, BK=32, 256 threads (4 waves, 2x2 of 64x64), m97 structure.
template <bool BIAS, bool RELU, bool ACCUM, bool OBF16>
__global__ __launch_bounds__(256) void mgemm_k(const __hip_bfloat16* __restrict__ A,
                                               const __hip_bfloat16* __restrict__ BT,
                                               const float* __restrict__ bias,
                                               void* __restrict__ Cv,
                                               int M, int N, int K, int ntn) {
    __shared__ short As[128 * 32];
    __shared__ short Bs[128 * 32];

    // bijective XCD swizzle (all grids here are multiples of 8)
    int nwg = gridDim.x;
    int bid = blockIdx.x;
    int cpx = nwg >> 3;
    int swz = (bid & 7) * cpx + (bid >> 3);
    int tm = swz / ntn, tn = swz - tm * ntn;
    int m0 = tm * 128, n0 = tn * 128;

    int tid = threadIdx.x;
    int lane = tid & 63;
    int wave = tid >> 6;
    int wr = wave >> 1, wc = wave & 1;

    f32x4_t acc[4][4];
#pragma unroll
    for (int i = 0; i < 4; ++i)
#pragma unroll
        for (int j = 0; j < 4; ++j)
#pragma unroll
            for (int r = 0; r < 4; ++r) acc[i][j][r] = 0.f;

    const short* Ag = (const short*)A;
    const short* Bg = (const short*)BT;
    const int arow0 = tid >> 2;            // 0..63
    const int arow1 = (tid + 256) >> 2;    // 64..127
    const int acol = (tid & 3) * 8;

    const int fr = lane & 15;              // fragment row/col within 16
    const int kg = (lane >> 4) * 8;        // k-group offset (bf16 elems)

    for (int k0 = 0; k0 < K; k0 += 32) {
        gload_lds16(Ag + (size_t)(m0 + arow0) * K + k0 + acol, &As[tid * 8]);
        gload_lds16(Ag + (size_t)(m0 + arow1) * K + k0 + acol, &As[(tid + 256) * 8]);
        gload_lds16(Bg + (size_t)(n0 + arow0) * K + k0 + acol, &Bs[tid * 8]);
        gload_lds16(Bg + (size_t)(n0 + arow1) * K + k0 + acol, &Bs[(tid + 256) * 8]);
        __syncthreads();

        bf16x8_t af[4], bq[4];
#pragma unroll
        for (int mi = 0; mi < 4; ++mi)
            af[mi] = *(const bf16x8_t*)&As[(wr * 64 + mi * 16 + fr) * 32 + kg];
#pragma unroll
        for (int ni = 0; ni < 4; ++ni)
            bq[ni] = *(const bf16x8_t*)&Bs[(wc * 64 + ni * 16 + fr) * 32 + kg];
#pragma unroll
        for (int mi = 0; mi < 4; ++mi)
#pragma unroll
            for (int ni = 0; ni < 4; ++ni)
                acc[mi][ni] = __builtin_amdgcn_mfma_f32_16x16x32_bf16(af[mi], bq[ni], acc[mi][ni], 0, 0, 0);
        __syncthreads();
    }

    // epilogue — C layout: col = lane&15, row = (lane>>4)*4 + r  [measured m89/m91]
    float bvec[4];
    if (BIAS) {
#pragma unroll
        for (int ni = 0; ni < 4; ++ni) bvec[ni] = bias[n0 + wc * 64 + ni * 16 + fr];
    }
    const int rbase = m0 + wr * 64 + (lane >> 4) * 4;
    const int cbase = n0 + wc * 64 + fr;
#pragma unroll
    for (int mi = 0; mi < 4; ++mi) {
#pragma unroll
        for (int ni = 0; ni < 4; ++ni) {
#pragma unroll
            for (int r = 0; r < 4; ++r) {
                int row = rbase + mi * 16 + r;
                int col = cbase + ni * 16;
                float v = acc[mi][ni][r];
                if (BIAS) v += bvec[ni];
                if (RELU) v = fmaxf(v, 0.f);
                size_t off = (size_t)row * N + col;
                if (OBF16) {
                    ((__hip_bfloat16*)Cv)[off] = __float2bfloat16(v);
                } else {
                    float* Cf = (float*)Cv;
                    if (ACCUM) Cf[off] += v; else Cf[off] = v;
                }
            }
        }
    }
}

// ---------------- causal attention: one block per (b, h, tq); bf16 qkv ----------------
__global__ __launch_bounds__(256) void attn_k(const __hip_bfloat16* __restrict__ qkv,
                                              __hip_bfloat16* __restrict__ o) {
    __shared__ float qs[HS];
    __shared__ float p[TT];
    __shared__ float red[4];
    __shared__ float ov[4][HS];

    int bid = blockIdx.x;
    int tq = bid & (TT - 1);
    int bh = bid >> 10;
    int hh = bh % HH;
    int bI = bh / HH;
    int tid = threadIdx.x;

    const size_t rowbase = (size_t)bI * TT;
    const __hip_bfloat16* qrow = qkv + (rowbase + tq) * QS + hh * HS;
    if (tid < HS) qs[tid] = __bfloat162float(qrow[tid]) * 0.125f;
    __syncthreads();

    const int nk = tq + 1;
    float lmax = -INFINITY;
    for (int j = tid; j < nk; j += 256) {
        const uint4* kp = (const uint4*)(qkv + (rowbase + j) * QS + EE + hh * HS);
        float s = 0.f;
#pragma unroll
        for (int c = 0; c < 8; ++c) {
            uint4 u = kp[c];
            s = fmaf(qs[c * 8 + 0], bflo(u.x), s);
            s = fmaf(qs[c * 8 + 1], bfhi(u.x), s);
            s = fmaf(qs[c * 8 + 2], bflo(u.y), s);
            s = fmaf(qs[c * 8 + 3], bfhi(u.y), s);
            s = fmaf(qs[c * 8 + 4], bflo(u.z), s);
            s = fmaf(qs[c * 8 + 5], bfhi(u.z), s);
            s = fmaf(qs[c * 8 + 6], bflo(u.w), s);
            s = fmaf(qs[c * 8 + 7], bfhi(u.w), s);
        }
        p[j] = s;
        lmax = fmaxf(lmax, s);
    }
    float m = block_max256(lmax, red);
    float lsum = 0.f;
    for (int j = tid; j < nk; j += 256) {
        float e = __expf(p[j] - m);
        p[j] = e;
        lsum += e;
    }
    float S = block_sum256(lsum, red);
    float inv = 1.0f / S;

    int d = tid & 63, grp = tid >> 6;
    float accd = 0.f;
    for (int j = grp; j < nk; j += 4)
        accd = fmaf(p[j], __bfloat162float(qkv[(rowbase + j) * QS + 2 * EE + hh * HS + d]), accd);
    ov[grp][d] = accd;
    __syncthreads();
    if (tid < HS) {
        float r = (ov[0][tid] + ov[1][tid] + ov[2][tid] + ov[3][tid]) * inv;
        o[(rowbase + tq) * EE + hh * HS + tid] = __float2bfloat16(r);
    }
}

// ---------------- per-row logsumexp loss ----------------
__global__ __launch_bounds__(256) void rowloss_k(const float* __restrict__ logits,
                                                 const int* __restrict__ targets,
                                                 float* __restrict__ rowloss) {
    __shared__ float red[4];
    int row = blockIdx.x;
    const float* lr = logits + (size_t)row * VV;
    int tid = threadIdx.x;
    float m = -INFINITY;
    for (int j = tid; j < VV; j += 256) m = fmaxf(m, lr[j]);
    m = block_max256(m, red);
    float s = 0.f;
    for (int j = tid; j < VV; j += 256) s += __expf(lr[j] - m);
    s = block_sum256(s, red);
    if (tid == 0) rowloss[row] = logf(s) + m - lr[targets[row]];
}

__global__ __launch_bounds__(256) void loss_final_k(const float* __restrict__ rowloss,
                                                    float* __restrict__ out) {
    __shared__ float red[4];
    float s = 0.f;
    for (int i = threadIdx.x; i < MROWS; i += 256) s += rowloss[i];
    s = block_sum256(s, red);
    if (threadIdx.x == 0) out[0] = s * (1.0f / MROWS);
}

// ---------------- launcher ----------------
extern "C" void kernel_launch(void* const* d_in, const int* in_sizes, int n_in,
                              void* d_out, int out_size, void* d_ws, size_t ws_size,
                              hipStream_t stream) {
    const int* idx      = (const int*)d_in[0];
    const int* targets  = (const int*)d_in[1];
    const float* tok    = (const float*)d_in[2];
    const float* pos    = (const float*)d_in[3];
    const float* Wq     = (const float*)d_in[4];
    const float* Wk     = (const float*)d_in[5];
    const float* Wv     = (const float*)d_in[6];
    const float* Wp     = (const float*)d_in[7];
    const float* bp     = (const float*)d_in[8];
    const float* W1     = (const float*)d_in[9];
    const float* b1     = (const float*)d_in[10];
    const float* W2     = (const float*)d_in[11];
    const float* b2     = (const float*)d_in[12];
    const float* ln1_g  = (const float*)d_in[13];
    const float* ln1_b  = (const float*)d_in[14];
    const float* ln2_g  = (const float*)d_in[15];
    const float* ln2_b  = (const float*)d_in[16];
    const float* lnf_g  = (const float*)d_in[17];
    const float* lnf_b  = (const float*)d_in[18];
    const float* Wlm    = (const float*)d_in[19];
    const float* blm    = (const float*)d_in[20];

    float* out = (float*)d_out;

    // ---- workspace carve (bytes, 256-aligned regions) ----
    char* w = (char*)d_ws;
    float* x = (float*)w;                             w += (size_t)MROWS * EE * 4;        // 12.6 MB
    __hip_bfloat16* hbf = (__hip_bfloat16*)w;         w += (size_t)MROWS * EE * 2;        // 6.3 MB
    __hip_bfloat16* qkv = (__hip_bfloat16*)w;         w += (size_t)MROWS * QS * 2;        // 18.9 MB
    __hip_bfloat16* obf = (__hip_bfloat16*)w;         w += (size_t)MROWS * EE * 2;        // 6.3 MB
    __hip_bfloat16* ff1 = (__hip_bfloat16*)w;         w += (size_t)MROWS * FFD * 2;       // 25.2 MB
    __hip_bfloat16* qkvwT = (__hip_bfloat16*)w;       w += (size_t)QS * EE * 2;           // 3.5 MB
    __hip_bfloat16* wpT = (__hip_bfloat16*)w;         w += (size_t)EE * EE * 2;           // 1.2 MB
    __hip_bfloat16* w1T = (__hip_bfloat16*)w;         w += (size_t)FFD * EE * 2;          // 4.7 MB
    __hip_bfloat16* w2T = (__hip_bfloat16*)w;         w += (size_t)EE * FFD * 2;          // 4.7 MB
    __hip_bfloat16* wlmT = (__hip_bfloat16*)w;        w += (size_t)VV * EE * 2;           // 49.2 MB
    float* rowloss = (float*)w;                       w += (size_t)MROWS * 4;

    dim3 blk(256);

    embed_k<<<MROWS, blk, 0, stream>>>(idx, tok, pos, x);

    for (int l = 0; l < LAYERS; ++l) {
        const float* wq = Wq + (size_t)l * EE * EE;
        const float* wk = Wk + (size_t)l * EE * EE;
        const float* wv = Wv + (size_t)l * EE * EE;
        const float* wp = Wp + (size_t)l * EE * EE;
        const float* w1 = W1 + (size_t)l * EE * FFD;
        const float* w2 = W2 + (size_t)l * FFD * EE;

        // LN1 -> hbf
        ln_k<<<MROWS, blk, 0, stream>>>(x, ln1_g + l * EE, ln1_b + l * EE, hbf);
        // weights -> bf16 transposed
        tconv_k<<<dim3(EE / 32, EE / 32), blk, 0, stream>>>(wq, qkvwT, EE, EE);
        tconv_k<<<dim3(EE / 32, EE / 32), blk, 0, stream>>>(wk, qkvwT + (size_t)EE * EE, EE, EE);
        tconv_k<<<dim3(EE / 32, EE / 32), blk, 0, stream>>>(wv, qkvwT + (size_t)2 * EE * EE, EE, EE);
        // fused QKV GEMM: [4096,768] x [2304,768]^T -> qkv bf16
        mgemm_k<false, false, false, true><<<dim3((MROWS / 128) * (QS / 128)), blk, 0, stream>>>(
            hbf, qkvwT, nullptr, qkv, MROWS, QS, EE, QS / 128);
        // attention -> obf
        attn_k<<<BB * HH * TT, blk, 0, stream>>>(qkv, obf);
        // proj (+bias, accumulate into x fp32)
        tconv_k<<<dim3(EE / 32, EE / 32), blk, 0, stream>>>(wp, wpT, EE, EE);
        mgemm_k<true, false, true, false><<<dim3((MROWS / 128) * (EE / 128)), blk, 0, stream>>>(
            obf, wpT, bp + l * EE, x, MROWS, EE, EE, EE / 128);
        // LN2 -> hbf
        ln_k<<<MROWS, blk, 0, stream>>>(x, ln2_g + l * EE, ln2_b + l * EE, hbf);
        // FF1 (+bias, relu) -> ff1 bf16
        tconv_k<<<dim3(FFD / 32, EE / 32), blk, 0, stream>>>(w1, w1T, EE, FFD);
        mgemm_k<true, true, false, true><<<dim3((MROWS / 128) * (FFD / 128)), blk, 0, stream>>>(
            hbf, w1T, b1 + l * FFD, ff1, MROWS, FFD, EE, FFD / 128);
        // FF2 (+bias, accumulate into x fp32)
        tconv_k<<<dim3(EE / 32, FFD / 32), blk, 0, stream>>>(w2, w2T, FFD, EE);
        mgemm_k<true, false, true, false><<<dim3((MROWS / 128) * (EE / 128)), blk, 0, stream>>>(
            ff1, w2T, b2 + l * EE, x, MROWS, EE, FFD, EE / 128);
    }

    // final LN -> hbf
    ln_k<<<MROWS, blk, 0, stream>>>(x, lnf_g, lnf_b, hbf);
    // LM head: [4096,768] x [32000,768]^T -> out fp32
    tconv_k<<<dim3(VV / 32, EE / 32), blk, 0, stream>>>(Wlm, wlmT, EE, VV);
    mgemm_k<true, false, false, false><<<dim3((MROWS / 128) * (VV / 128)), blk, 0, stream>>>(
        hbf, wlmT, blm, out, MROWS, VV, EE, VV / 128);

    rowloss_k<<<MROWS, blk, 0, stream>>>(out, targets, rowloss);
    loss_final_k<<<1, blk, 0, stream>>>(rowloss, out + (size_t)MROWS * VV);
}

// Round 3
// 2126.831 us; speedup vs baseline: 7.3389x; 3.8954x over previous
//
#include <hip/hip_runtime.h>
#include <hip/hip_bf16.h>
#include <math.h>

#define LAYERS 6
#define BB 4
#define TT 1024
#define EE 768
#define HH 12
#define HS 64
#define VV 32000
#define FFD 3072
#define MROWS (BB * TT)   // 4096
#define QS (3 * EE)       // 2304, fused qkv row stride
#define KVB 64
#define QBLK 128

typedef __attribute__((ext_vector_type(8))) short bf16x8_t;
typedef __attribute__((ext_vector_type(4))) float f32x4_t;

// ---------------- helpers ----------------
__device__ __forceinline__ float wave_sum(float v) {
#pragma unroll
    for (int o = 32; o > 0; o >>= 1) v += __shfl_xor(v, o);
    return v;
}
__device__ __forceinline__ float wave_max(float v) {
#pragma unroll
    for (int o = 32; o > 0; o >>= 1) v = fmaxf(v, __shfl_xor(v, o));
    return v;
}
__device__ __forceinline__ float block_sum256(float v, float* red) {
    v = wave_sum(v);
    int tid = threadIdx.x;
    if ((tid & 63) == 0) red[tid >> 6] = v;
    __syncthreads();
    float r = red[0] + red[1] + red[2] + red[3];
    __syncthreads();
    return r;
}
__device__ __forceinline__ float block_max256(float v, float* red) {
    v = wave_max(v);
    int tid = threadIdx.x;
    if ((tid & 63) == 0) red[tid >> 6] = v;
    __syncthreads();
    float r = fmaxf(fmaxf(red[0], red[1]), fmaxf(red[2], red[3]));
    __syncthreads();
    return r;
}

__device__ __forceinline__ void gload_lds16(const void* g, void* l) {
    __builtin_amdgcn_global_load_lds((const __attribute__((address_space(1))) void*)g,
                                     (__attribute__((address_space(3))) void*)l, 16, 0, 0);
}

// ---------------- embedding ----------------
__global__ __launch_bounds__(256) void embed_k(const int* __restrict__ idx,
                                               const float* __restrict__ tok,
                                               const float* __restrict__ pos,
                                               float* __restrict__ x) {
    int row = blockIdx.x;
    int t = row & (TT - 1);
    int token = idx[row];
    const float* te = tok + (size_t)token * EE;
    const float* pe = pos + (size_t)t * EE;
    float* xr = x + (size_t)row * EE;
    for (int i = threadIdx.x; i < EE; i += 256) xr[i] = te[i] + pe[i];
}

// ---------------- LayerNorm: fp32 in -> bf16 out ----------------
__global__ __launch_bounds__(256) void ln_k(const float* __restrict__ x,
                                            const float* __restrict__ g,
                                            const float* __restrict__ b,
                                            __hip_bfloat16* __restrict__ out) {
    __shared__ float sr[EE];
    __shared__ float red[4];
    int row = blockIdx.x;
    const float* xr = x + (size_t)row * EE;
    int tid = threadIdx.x;
    float s = 0.f;
    for (int i = tid; i < EE; i += 256) { float v = xr[i]; sr[i] = v; s += v; }
    s = block_sum256(s, red);
    float m = s * (1.0f / EE);
    float vs = 0.f;
    for (int i = tid; i < EE; i += 256) { float d = sr[i] - m; vs += d * d; }
    vs = block_sum256(vs, red);
    float rstd = rsqrtf(vs * (1.0f / EE) + 1e-5f);
    __hip_bfloat16* orow = out + (size_t)row * EE;
    for (int i = tid; i < EE; i += 256)
        orow[i] = __float2bfloat16((sr[i] - m) * rstd * g[i] + b[i]);
}

// ---------------- transpose-convert: W fp32 [R,C] -> WT bf16 [C,R] ----------------
__global__ __launch_bounds__(256) void tconv_k(const float* __restrict__ W,
                                               __hip_bfloat16* __restrict__ WT,
                                               int R, int C) {
    __shared__ float t[32][33];
    int c0 = blockIdx.x * 32, r0 = blockIdx.y * 32;
    int tx = threadIdx.x & 31, ty = threadIdx.x >> 5;
#pragma unroll
    for (int i = 0; i < 4; ++i)
        t[ty + 8 * i][tx] = W[(size_t)(r0 + ty + 8 * i) * C + c0 + tx];
    __syncthreads();
#pragma unroll
    for (int i = 0; i < 4; ++i)
        WT[(size_t)(c0 + ty + 8 * i) * R + r0 + tx] = __float2bfloat16(t[tx][ty + 8 * i]);
}

// ---------------- MFMA GEMM (m97 structure, 128x128, BK=32) ----------------
template <bool BIAS, bool RELU, bool ACCUM, bool OBF16>
__global__ __launch_bounds__(256) void mgemm_k(const __hip_bfloat16* __restrict__ A,
                                               const __hip_bfloat16* __restrict__ BT,
                                               const float* __restrict__ bias,
                                               void* __restrict__ Cv,
                                               int M, int N, int K, int ntn) {
    __shared__ short As[128 * 32];
    __shared__ short Bs[128 * 32];

    int nwg = gridDim.x;
    int bid = blockIdx.x;
    int cpx = nwg >> 3;
    int swz = (bid & 7) * cpx + (bid >> 3);
    int tm = swz / ntn, tn = swz - tm * ntn;
    int m0 = tm * 128, n0 = tn * 128;

    int tid = threadIdx.x;
    int lane = tid & 63;
    int wave = tid >> 6;
    int wr = wave >> 1, wc = wave & 1;

    f32x4_t acc[4][4];
#pragma unroll
    for (int i = 0; i < 4; ++i)
#pragma unroll
        for (int j = 0; j < 4; ++j)
#pragma unroll
            for (int r = 0; r < 4; ++r) acc[i][j][r] = 0.f;

    const short* Ag = (const short*)A;
    const short* Bg = (const short*)BT;
    const int arow0 = tid >> 2;
    const int arow1 = (tid + 256) >> 2;
    const int acol = (tid & 3) * 8;

    const int fr = lane & 15;
    const int kg = (lane >> 4) * 8;

    for (int k0 = 0; k0 < K; k0 += 32) {
        gload_lds16(Ag + (size_t)(m0 + arow0) * K + k0 + acol, &As[tid * 8]);
        gload_lds16(Ag + (size_t)(m0 + arow1) * K + k0 + acol, &As[(tid + 256) * 8]);
        gload_lds16(Bg + (size_t)(n0 + arow0) * K + k0 + acol, &Bs[tid * 8]);
        gload_lds16(Bg + (size_t)(n0 + arow1) * K + k0 + acol, &Bs[(tid + 256) * 8]);
        __syncthreads();

        bf16x8_t af[4], bq[4];
#pragma unroll
        for (int mi = 0; mi < 4; ++mi)
            af[mi] = *(const bf16x8_t*)&As[(wr * 64 + mi * 16 + fr) * 32 + kg];
#pragma unroll
        for (int ni = 0; ni < 4; ++ni)
            bq[ni] = *(const bf16x8_t*)&Bs[(wc * 64 + ni * 16 + fr) * 32 + kg];
#pragma unroll
        for (int mi = 0; mi < 4; ++mi)
#pragma unroll
            for (int ni = 0; ni < 4; ++ni)
                acc[mi][ni] = __builtin_amdgcn_mfma_f32_16x16x32_bf16(af[mi], bq[ni], acc[mi][ni], 0, 0, 0);
        __syncthreads();
    }

    float bvec[4];
    if (BIAS) {
#pragma unroll
        for (int ni = 0; ni < 4; ++ni) bvec[ni] = bias[n0 + wc * 64 + ni * 16 + fr];
    }
    const int rbase = m0 + wr * 64 + (lane >> 4) * 4;
    const int cbase = n0 + wc * 64 + fr;
#pragma unroll
    for (int mi = 0; mi < 4; ++mi) {
#pragma unroll
        for (int ni = 0; ni < 4; ++ni) {
#pragma unroll
            for (int r = 0; r < 4; ++r) {
                int row = rbase + mi * 16 + r;
                int col = cbase + ni * 16;
                float v = acc[mi][ni][r];
                if (BIAS) v += bvec[ni];
                if (RELU) v = fmaxf(v, 0.f);
                size_t off = (size_t)row * N + col;
                if (OBF16) {
                    ((__hip_bfloat16*)Cv)[off] = __float2bfloat16(v);
                } else {
                    float* Cf = (float*)Cv;
                    if (ACCUM) Cf[off] += v; else Cf[off] = v;
                }
            }
        }
    }
}

// ---------------- MFMA flash attention ----------------
// grid (48, 8): x = b*H+h, y = q-tile slot (heavy-first). 256 threads = 4 waves.
// Wave owns 32 q-rows. KV iterated in 64-key tiles; K and V^T staged in
// XOR-swizzled LDS (byte ^= (row&7)<<4 kills the 128B-stride bank conflict).
__global__ __launch_bounds__(256) void fattn_k(const __hip_bfloat16* __restrict__ qkv,
                                               __hip_bfloat16* __restrict__ o) {
    __shared__ short Ks[KVB * HS];        // [key][d], swizzled
    __shared__ short Vt[HS * KVB];        // [d][key], swizzled
    __shared__ short Pl[4 * 32 * KVB];    // per-wave P [32][64], swizzled

    const int bh = blockIdx.x;
    const int hh = bh % HH;
    const int bI = bh / HH;
    const int qt = (TT / QBLK - 1) - blockIdx.y;   // heavy tiles first
    const int q0 = qt * QBLK;

    const int tid = threadIdx.x;
    const int lane = tid & 63;
    const int wave = tid >> 6;
    const int fr = lane & 15;
    const int hi4 = lane >> 4;

    const size_t rowbase = (size_t)bI * TT;
    const int wq0 = q0 + wave * 32;

    // Q fragments, pre-scaled by 1/8 (exact exponent shift in bf16)
    bf16x8_t qf[2][2];
#pragma unroll
    for (int mi = 0; mi < 2; ++mi)
#pragma unroll
        for (int kc = 0; kc < 2; ++kc) {
            const short* src = (const short*)qkv +
                (rowbase + wq0 + mi * 16 + fr) * QS + hh * HS + kc * 32 + hi4 * 8;
            bf16x8_t v = *(const bf16x8_t*)src;
#pragma unroll
            for (int e = 0; e < 8; ++e) {
                float f = __uint_as_float(((unsigned)(unsigned short)v[e]) << 16) * 0.125f;
                v[e] = (short)(__float_as_uint(f) >> 16);
            }
            qf[mi][kc] = v;
        }

    f32x4_t oa[2][4];
    float m_r[2][4], l_r[2][4];
#pragma unroll
    for (int mi = 0; mi < 2; ++mi)
#pragma unroll
        for (int r = 0; r < 4; ++r) {
            m_r[mi][r] = -INFINITY;
            l_r[mi][r] = 0.f;
#pragma unroll
            for (int nd = 0; nd < 4; ++nd) oa[mi][nd][r] = 0.f;
        }

    const int skey = tid >> 2;            // 0..63
    const int sd0 = (tid & 3) * 16;       // 0,16,32,48
    const int niter = 2 * (qt + 1);

    for (int it = 0; it < niter; ++it) {
        const int kv0 = it * KVB;
        __syncthreads();   // previous iter's LDS reads done
        // ---- stage K and V^T ----
        {
            const short* kg = (const short*)qkv + (rowbase + kv0 + skey) * QS + EE + hh * HS + sd0;
            uint4 ka = *(const uint4*)kg;
            uint4 kb2 = *(const uint4*)(kg + 8);
            const int rs = (skey & 7) << 4;
            char* kbp = (char*)Ks;
            *(uint4*)(kbp + ((skey * 128 + sd0 * 2) ^ rs)) = ka;
            *(uint4*)(kbp + ((skey * 128 + sd0 * 2 + 16) ^ rs)) = kb2;

            const short* vg = (const short*)qkv + (rowbase + kv0 + skey) * QS + 2 * EE + hh * HS + sd0;
            uint4 va = *(const uint4*)vg;
            uint4 vb2 = *(const uint4*)(vg + 8);
            char* vbp = (char*)Vt;
            const short* vs0 = (const short*)&va;
#pragma unroll
            for (int e = 0; e < 8; ++e) {
                int dd = sd0 + e;
                *(short*)(vbp + ((dd * 128 + skey * 2) ^ ((dd & 7) << 4))) = vs0[e];
            }
            const short* vs1 = (const short*)&vb2;
#pragma unroll
            for (int e = 0; e < 8; ++e) {
                int dd = sd0 + 8 + e;
                *(short*)(vbp + ((dd * 128 + skey * 2) ^ ((dd & 7) << 4))) = vs1[e];
            }
        }
        __syncthreads();

        // ---- S = Q K^T ----
        f32x4_t sa[2][4];
#pragma unroll
        for (int mi = 0; mi < 2; ++mi)
#pragma unroll
            for (int ni = 0; ni < 4; ++ni)
#pragma unroll
                for (int r = 0; r < 4; ++r) sa[mi][ni][r] = 0.f;
#pragma unroll
        for (int kc = 0; kc < 2; ++kc) {
            bf16x8_t kf[4];
#pragma unroll
            for (int ni = 0; ni < 4; ++ni) {
                int krow = ni * 16 + fr;
                kf[ni] = *(const bf16x8_t*)((char*)Ks +
                    ((krow * 128 + (kc * 32 + hi4 * 8) * 2) ^ ((krow & 7) << 4)));
            }
#pragma unroll
            for (int mi = 0; mi < 2; ++mi)
#pragma unroll
                for (int ni = 0; ni < 4; ++ni)
                    sa[mi][ni] = __builtin_amdgcn_mfma_f32_16x16x32_bf16(qf[mi][kc], kf[ni], sa[mi][ni], 0, 0, 0);
        }

        // ---- causal mask (only near-diagonal tiles) ----
        if (kv0 + KVB - 1 > wq0) {
#pragma unroll
            for (int mi = 0; mi < 2; ++mi)
#pragma unroll
                for (int ni = 0; ni < 4; ++ni)
#pragma unroll
                    for (int r = 0; r < 4; ++r) {
                        int qrow = wq0 + mi * 16 + hi4 * 4 + r;
                        int key = kv0 + ni * 16 + fr;
                        if (key > qrow) sa[mi][ni][r] = -1e30f;
                    }
        }

        // ---- online softmax (row = mi*16 + hi4*4 + r; cols across fr-group) ----
        char* Pw = (char*)Pl + wave * 4096;
#pragma unroll
        for (int mi = 0; mi < 2; ++mi)
#pragma unroll
            for (int r = 0; r < 4; ++r) {
                float mx = fmaxf(fmaxf(sa[mi][0][r], sa[mi][1][r]),
                                 fmaxf(sa[mi][2][r], sa[mi][3][r]));
#pragma unroll
                for (int off = 1; off < 16; off <<= 1) mx = fmaxf(mx, __shfl_xor(mx, off));
                float mnew = fmaxf(m_r[mi][r], mx);
                float al = __expf(m_r[mi][r] - mnew);
                m_r[mi][r] = mnew;
                float ps = 0.f;
#pragma unroll
                for (int ni = 0; ni < 4; ++ni) {
                    float p = __expf(sa[mi][ni][r] - mnew);
                    sa[mi][ni][r] = p;
                    ps += p;
                }
#pragma unroll
                for (int off = 1; off < 16; off <<= 1) ps += __shfl_xor(ps, off);
                l_r[mi][r] = l_r[mi][r] * al + ps;
#pragma unroll
                for (int nd = 0; nd < 4; ++nd) oa[mi][nd][r] *= al;
            }

        // ---- write P (bf16) to per-wave swizzled LDS ----
#pragma unroll
        for (int mi = 0; mi < 2; ++mi)
#pragma unroll
            for (int ni = 0; ni < 4; ++ni)
#pragma unroll
                for (int r = 0; r < 4; ++r) {
                    int prow = mi * 16 + hi4 * 4 + r;
                    *(__hip_bfloat16*)(Pw + ((prow * 128 + (ni * 16 + fr) * 2) ^ ((prow & 7) << 4))) =
                        __float2bfloat16(sa[mi][ni][r]);
                }

        // ---- O += P V ----
#pragma unroll
        for (int kc = 0; kc < 2; ++kc) {
            bf16x8_t pf[2], vf[4];
#pragma unroll
            for (int mi = 0; mi < 2; ++mi) {
                int prow = mi * 16 + fr;
                pf[mi] = *(const bf16x8_t*)(Pw +
                    ((prow * 128 + (kc * 32 + hi4 * 8) * 2) ^ ((prow & 7) << 4)));
            }
#pragma unroll
            for (int nd = 0; nd < 4; ++nd) {
                int vrow = nd * 16 + fr;
                vf[nd] = *(const bf16x8_t*)((char*)Vt +
                    ((vrow * 128 + (kc * 32 + hi4 * 8) * 2) ^ ((vrow & 7) << 4)));
            }
#pragma unroll
            for (int mi = 0; mi < 2; ++mi)
#pragma unroll
                for (int nd = 0; nd < 4; ++nd)
                    oa[mi][nd] = __builtin_amdgcn_mfma_f32_16x16x32_bf16(pf[mi], vf[nd], oa[mi][nd], 0, 0, 0);
        }
    }

    // ---- epilogue: O / l -> global ----
#pragma unroll
    for (int mi = 0; mi < 2; ++mi)
#pragma unroll
        for (int r = 0; r < 4; ++r) {
            float inv = 1.0f / l_r[mi][r];
            int row = wq0 + mi * 16 + hi4 * 4 + r;
            __hip_bfloat16* orow = o + (rowbase + row) * EE + hh * HS;
#pragma unroll
            for (int nd = 0; nd < 4; ++nd)
                orow[nd * 16 + fr] = __float2bfloat16(oa[mi][nd][r] * inv);
        }
}

// ---------------- per-row logsumexp loss ----------------
__global__ __launch_bounds__(256) void rowloss_k(const float* __restrict__ logits,
                                                 const int* __restrict__ targets,
                                                 float* __restrict__ rowloss) {
    __shared__ float red[4];
    int row = blockIdx.x;
    const float* lr = logits + (size_t)row * VV;
    int tid = threadIdx.x;
    float m = -INFINITY;
    for (int j = tid; j < VV; j += 256) m = fmaxf(m, lr[j]);
    m = block_max256(m, red);
    float s = 0.f;
    for (int j = tid; j < VV; j += 256) s += __expf(lr[j] - m);
    s = block_sum256(s, red);
    if (tid == 0) rowloss[row] = logf(s) + m - lr[targets[row]];
}

__global__ __launch_bounds__(256) void loss_final_k(const float* __restrict__ rowloss,
                                                    float* __restrict__ out) {
    __shared__ float red[4];
    float s = 0.f;
    for (int i = threadIdx.x; i < MROWS; i += 256) s += rowloss[i];
    s = block_sum256(s, red);
    if (threadIdx.x == 0) out[0] = s * (1.0f / MROWS);
}

// ---------------- launcher ----------------
extern "C" void kernel_launch(void* const* d_in, const int* in_sizes, int n_in,
                              void* d_out, int out_size, void* d_ws, size_t ws_size,
                              hipStream_t stream) {
    const int* idx      = (const int*)d_in[0];
    const int* targets  = (const int*)d_in[1];
    const float* tok    = (const float*)d_in[2];
    const float* pos    = (const float*)d_in[3];
    const float* Wq     = (const float*)d_in[4];
    const float* Wk     = (const float*)d_in[5];
    const float* Wv     = (const float*)d_in[6];
    const float* Wp     = (const float*)d_in[7];
    const float* bp     = (const float*)d_in[8];
    const float* W1     = (const float*)d_in[9];
    const float* b1     = (const float*)d_in[10];
    const float* W2     = (const float*)d_in[11];
    const float* b2     = (const float*)d_in[12];
    const float* ln1_g  = (const float*)d_in[13];
    const float* ln1_b  = (const float*)d_in[14];
    const float* ln2_g  = (const float*)d_in[15];
    const float* ln2_b  = (const float*)d_in[16];
    const float* lnf_g  = (const float*)d_in[17];
    const float* lnf_b  = (const float*)d_in[18];
    const float* Wlm    = (const float*)d_in[19];
    const float* blm    = (const float*)d_in[20];

    float* out = (float*)d_out;

    char* w = (char*)d_ws;
    float* x = (float*)w;                             w += (size_t)MROWS * EE * 4;
    __hip_bfloat16* hbf = (__hip_bfloat16*)w;         w += (size_t)MROWS * EE * 2;
    __hip_bfloat16* qkv = (__hip_bfloat16*)w;         w += (size_t)MROWS * QS * 2;
    __hip_bfloat16* obf = (__hip_bfloat16*)w;         w += (size_t)MROWS * EE * 2;
    __hip_bfloat16* ff1 = (__hip_bfloat16*)w;         w += (size_t)MROWS * FFD * 2;
    __hip_bfloat16* qkvwT = (__hip_bfloat16*)w;       w += (size_t)QS * EE * 2;
    __hip_bfloat16* wpT = (__hip_bfloat16*)w;         w += (size_t)EE * EE * 2;
    __hip_bfloat16* w1T = (__hip_bfloat16*)w;         w += (size_t)FFD * EE * 2;
    __hip_bfloat16* w2T = (__hip_bfloat16*)w;         w += (size_t)EE * FFD * 2;
    __hip_bfloat16* wlmT = (__hip_bfloat16*)w;        w += (size_t)VV * EE * 2;
    float* rowloss = (float*)w;                       w += (size_t)MROWS * 4;

    dim3 blk(256);

    embed_k<<<MROWS, blk, 0, stream>>>(idx, tok, pos, x);

    for (int l = 0; l < LAYERS; ++l) {
        const float* wq = Wq + (size_t)l * EE * EE;
        const float* wk = Wk + (size_t)l * EE * EE;
        const float* wv = Wv + (size_t)l * EE * EE;
        const float* wp = Wp + (size_t)l * EE * EE;
        const float* w1 = W1 + (size_t)l * EE * FFD;
        const float* w2 = W2 + (size_t)l * FFD * EE;

        ln_k<<<MROWS, blk, 0, stream>>>(x, ln1_g + l * EE, ln1_b + l * EE, hbf);
        tconv_k<<<dim3(EE / 32, EE / 32), blk, 0, stream>>>(wq, qkvwT, EE, EE);
        tconv_k<<<dim3(EE / 32, EE / 32), blk, 0, stream>>>(wk, qkvwT + (size_t)EE * EE, EE, EE);
        tconv_k<<<dim3(EE / 32, EE / 32), blk, 0, stream>>>(wv, qkvwT + (size_t)2 * EE * EE, EE, EE);
        mgemm_k<false, false, false, true><<<dim3((MROWS / 128) * (QS / 128)), blk, 0, stream>>>(
            hbf, qkvwT, nullptr, qkv, MROWS, QS, EE, QS / 128);
        fattn_k<<<dim3(BB * HH, TT / QBLK), blk, 0, stream>>>(qkv, obf);
        tconv_k<<<dim3(EE / 32, EE / 32), blk, 0, stream>>>(wp, wpT, EE, EE);
        mgemm_k<true, false, true, false><<<dim3((MROWS / 128) * (EE / 128)), blk, 0, stream>>>(
            obf, wpT, bp + l * EE, x, MROWS, EE, EE, EE / 128);
        ln_k<<<MROWS, blk, 0, stream>>>(x, ln2_g + l * EE, ln2_b + l * EE, hbf);
        tconv_k<<<dim3(FFD / 32, EE / 32), blk, 0, stream>>>(w1, w1T, EE, FFD);
        mgemm_k<true, true, false, true><<<dim3((MROWS / 128) * (FFD / 128)), blk, 0, stream>>>(
            hbf, w1T, b1 + l * FFD, ff1, MROWS, FFD, EE, FFD / 128);
        tconv_k<<<dim3(EE / 32, FFD / 32), blk, 0, stream>>>(w2, w2T, FFD, EE);
        mgemm_k<true, false, true, false><<<dim3((MROWS / 128) * (EE / 128)), blk, 0, stream>>>(
            ff1, w2T, b2 + l * EE, x, MROWS, EE, FFD, EE / 128);
    }

    ln_k<<<MROWS, blk, 0, stream>>>(x, lnf_g, lnf_b, hbf);
    tconv_k<<<dim3(VV / 32, EE / 32), blk, 0, stream>>>(Wlm, wlmT, EE, VV);
    mgemm_k<true, false, false, false><<<dim3((MROWS / 128) * (VV / 128)), blk, 0, stream>>>(
        hbf, wlmT, blm, out, MROWS, VV, EE, VV / 128);

    rowloss_k<<<MROWS, blk, 0, stream>>>(out, targets, rowloss);
    loss_final_k<<<1, blk, 0, stream>>>(rowloss, out + (size_t)MROWS * VV);
}

// Round 4
// 1960.793 us; speedup vs baseline: 7.9604x; 1.0847x over previous
//
#include <hip/hip_runtime.h>
#include <hip/hip_bf16.h>
#include <math.h>

#define LAYERS 6
#define BB 4
#define TT 1024
#define EE 768
#define HH 12
#define HS 64
#define VV 32000
#define FFD 3072
#define MROWS (BB * TT)   // 4096
#define QS (3 * EE)       // 2304, fused qkv row stride
#define KVB 64
#define QBLK 128
#define NTN_LM (VV / 128) // 250

typedef __attribute__((ext_vector_type(8))) short bf16x8_t;
typedef __attribute__((ext_vector_type(4))) float f32x4_t;

// ---------------- helpers ----------------
__device__ __forceinline__ float wave_sum(float v) {
#pragma unroll
    for (int o = 32; o > 0; o >>= 1) v += __shfl_xor(v, o);
    return v;
}
__device__ __forceinline__ float wave_max(float v) {
#pragma unroll
    for (int o = 32; o > 0; o >>= 1) v = fmaxf(v, __shfl_xor(v, o));
    return v;
}
__device__ __forceinline__ float block_sum256(float v, float* red) {
    v = wave_sum(v);
    int tid = threadIdx.x;
    if ((tid & 63) == 0) red[tid >> 6] = v;
    __syncthreads();
    float r = red[0] + red[1] + red[2] + red[3];
    __syncthreads();
    return r;
}
__device__ __forceinline__ float block_max256(float v, float* red) {
    v = wave_max(v);
    int tid = threadIdx.x;
    if ((tid & 63) == 0) red[tid >> 6] = v;
    __syncthreads();
    float r = fmaxf(fmaxf(red[0], red[1]), fmaxf(red[2], red[3]));
    __syncthreads();
    return r;
}

__device__ __forceinline__ void gload_lds16(const void* g, void* l) {
    __builtin_amdgcn_global_load_lds((const __attribute__((address_space(1))) void*)g,
                                     (__attribute__((address_space(3))) void*)l, 16, 0, 0);
}

// ---------------- embedding ----------------
__global__ __launch_bounds__(256) void embed_k(const int* __restrict__ idx,
                                               const float* __restrict__ tok,
                                               const float* __restrict__ pos,
                                               float* __restrict__ x) {
    int row = blockIdx.x;
    int t = row & (TT - 1);
    int token = idx[row];
    const float* te = tok + (size_t)token * EE;
    const float* pe = pos + (size_t)t * EE;
    float* xr = x + (size_t)row * EE;
    for (int i = threadIdx.x; i < EE; i += 256) xr[i] = te[i] + pe[i];
}

// ---------------- LayerNorm: fp32 in -> bf16 out ----------------
__global__ __launch_bounds__(256) void ln_k(const float* __restrict__ x,
                                            const float* __restrict__ g,
                                            const float* __restrict__ b,
                                            __hip_bfloat16* __restrict__ out) {
    __shared__ float sr[EE];
    __shared__ float red[4];
    int row = blockIdx.x;
    const float* xr = x + (size_t)row * EE;
    int tid = threadIdx.x;
    float s = 0.f;
    for (int i = tid; i < EE; i += 256) { float v = xr[i]; sr[i] = v; s += v; }
    s = block_sum256(s, red);
    float m = s * (1.0f / EE);
    float vs = 0.f;
    for (int i = tid; i < EE; i += 256) { float d = sr[i] - m; vs += d * d; }
    vs = block_sum256(vs, red);
    float rstd = rsqrtf(vs * (1.0f / EE) + 1e-5f);
    __hip_bfloat16* orow = out + (size_t)row * EE;
    for (int i = tid; i < EE; i += 256)
        orow[i] = __float2bfloat16((sr[i] - m) * rstd * g[i] + b[i]);
}

// ---------------- batched transpose-convert: W fp32 [R,C] -> WT bf16 [C,R] ------
// grid.z = layer; W += z*wstride, WT += z*tstride.
__global__ __launch_bounds__(256) void tconv_b_k(const float* __restrict__ W,
                                                 __hip_bfloat16* __restrict__ WT,
                                                 int R, int C,
                                                 size_t wstride, size_t tstride) {
    __shared__ float t[32][33];
    const float* Wl = W + (size_t)blockIdx.z * wstride;
    __hip_bfloat16* Tl = WT + (size_t)blockIdx.z * tstride;
    int c0 = blockIdx.x * 32, r0 = blockIdx.y * 32;
    int tx = threadIdx.x & 31, ty = threadIdx.x >> 5;
#pragma unroll
    for (int i = 0; i < 4; ++i)
        t[ty + 8 * i][tx] = Wl[(size_t)(r0 + ty + 8 * i) * C + c0 + tx];
    __syncthreads();
#pragma unroll
    for (int i = 0; i < 4; ++i)
        Tl[(size_t)(c0 + ty + 8 * i) * R + r0 + tx] = __float2bfloat16(t[tx][ty + 8 * i]);
}

// ---------------- MFMA GEMM (m97 structure, 128x128, BK=32) ----------------
// COLMAJ: tm-fast tile order (B-panel L2 reuse, for N >> M weights like LM head).
// LSE: epilogue emits per-(row, col-block) online-logsumexp partials (m, l).
template <bool BIAS, bool RELU, bool ACCUM, bool OBF16, bool COLMAJ, bool LSE>
__global__ __launch_bounds__(256) void mgemm_k(const __hip_bfloat16* __restrict__ A,
                                               const __hip_bfloat16* __restrict__ BT,
                                               const float* __restrict__ bias,
                                               void* __restrict__ Cv,
                                               int M, int N, int K,
                                               int ntm, int ntn,
                                               float2* __restrict__ partials) {
    __shared__ __align__(16) short As[128 * 32];
    __shared__ __align__(16) short Bs[128 * 32];

    int nwg = gridDim.x;
    int bid = blockIdx.x;
    int cpx = nwg >> 3;
    int swz = (bid & 7) * cpx + (bid >> 3);
    int tm, tn;
    if (COLMAJ) { tn = swz / ntm; tm = swz - tn * ntm; }
    else        { tm = swz / ntn; tn = swz - tm * ntn; }
    int m0 = tm * 128, n0 = tn * 128;

    int tid = threadIdx.x;
    int lane = tid & 63;
    int wave = tid >> 6;
    int wr = wave >> 1, wc = wave & 1;

    f32x4_t acc[4][4];
#pragma unroll
    for (int i = 0; i < 4; ++i)
#pragma unroll
        for (int j = 0; j < 4; ++j)
#pragma unroll
            for (int r = 0; r < 4; ++r) acc[i][j][r] = 0.f;

    const short* Ag = (const short*)A;
    const short* Bg = (const short*)BT;
    const int arow0 = tid >> 2;
    const int arow1 = (tid + 256) >> 2;
    const int acol = (tid & 3) * 8;

    const int fr = lane & 15;
    const int kg = (lane >> 4) * 8;

    for (int k0 = 0; k0 < K; k0 += 32) {
        gload_lds16(Ag + (size_t)(m0 + arow0) * K + k0 + acol, &As[tid * 8]);
        gload_lds16(Ag + (size_t)(m0 + arow1) * K + k0 + acol, &As[(tid + 256) * 8]);
        gload_lds16(Bg + (size_t)(n0 + arow0) * K + k0 + acol, &Bs[tid * 8]);
        gload_lds16(Bg + (size_t)(n0 + arow1) * K + k0 + acol, &Bs[(tid + 256) * 8]);
        __syncthreads();

        bf16x8_t af[4], bq[4];
#pragma unroll
        for (int mi = 0; mi < 4; ++mi)
            af[mi] = *(const bf16x8_t*)&As[(wr * 64 + mi * 16 + fr) * 32 + kg];
#pragma unroll
        for (int ni = 0; ni < 4; ++ni)
            bq[ni] = *(const bf16x8_t*)&Bs[(wc * 64 + ni * 16 + fr) * 32 + kg];
#pragma unroll
        for (int mi = 0; mi < 4; ++mi)
#pragma unroll
            for (int ni = 0; ni < 4; ++ni)
                acc[mi][ni] = __builtin_amdgcn_mfma_f32_16x16x32_bf16(af[mi], bq[ni], acc[mi][ni], 0, 0, 0);
        __syncthreads();
    }

    float bvec[4];
    if (BIAS) {
#pragma unroll
        for (int ni = 0; ni < 4; ++ni) bvec[ni] = bias[n0 + wc * 64 + ni * 16 + fr];
    }
    const int rbase = m0 + wr * 64 + (lane >> 4) * 4;
    const int cbase = n0 + wc * 64 + fr;
#pragma unroll
    for (int mi = 0; mi < 4; ++mi) {
#pragma unroll
        for (int r = 0; r < 4; ++r) {
            int row = rbase + mi * 16 + r;
            float v4[4];
#pragma unroll
            for (int ni = 0; ni < 4; ++ni) {
                float v = acc[mi][ni][r];
                if (BIAS) v += bvec[ni];
                if (RELU) v = fmaxf(v, 0.f);
                v4[ni] = v;
                size_t off = (size_t)row * N + cbase + ni * 16;
                if (OBF16) {
                    ((__hip_bfloat16*)Cv)[off] = __float2bfloat16(v);
                } else {
                    float* Cf = (float*)Cv;
                    if (ACCUM) Cf[off] += v; else Cf[off] = v;
                }
            }
            if (LSE) {
                // per-row (over this block's 128-col slice) max & sumexp;
                // 16 fr-lanes share the same row.
                float mrow = fmaxf(fmaxf(v4[0], v4[1]), fmaxf(v4[2], v4[3]));
#pragma unroll
                for (int o = 1; o < 16; o <<= 1) mrow = fmaxf(mrow, __shfl_xor(mrow, o));
                float srow = 0.f;
#pragma unroll
                for (int ni = 0; ni < 4; ++ni) srow += __expf(v4[ni] - mrow);
#pragma unroll
                for (int o = 1; o < 16; o <<= 1) srow += __shfl_xor(srow, o);
                if (fr == 0) {
                    float* red = (float*)As;   // loop done: LDS free
                    int idx = wave * 64 + mi * 16 + (lane >> 4) * 4 + r;
                    red[idx * 2] = mrow;
                    red[idx * 2 + 1] = srow;
                }
            }
        }
    }

    if (LSE) {
        __syncthreads();
        if (wc == 0) {   // waves 0 (wr=0) and 2 (wr=1) merge the two col-halves
            const float* red = (const float*)As;
            int i0 = (wr * 2 + 0) * 64 + lane;
            int i1 = (wr * 2 + 1) * 64 + lane;
            float ma = red[i0 * 2], la = red[i0 * 2 + 1];
            float mb = red[i1 * 2], lb = red[i1 * 2 + 1];
            float Mx = fmaxf(ma, mb);
            float Ls = la * __expf(ma - Mx) + lb * __expf(mb - Mx);
            partials[(size_t)(m0 + wr * 64 + lane) * ntn + tn] = make_float2(Mx, Ls);
        }
    }
}

// ---------------- MFMA flash attention (unchanged from r3) ----------------
__global__ __launch_bounds__(256) void fattn_k(const __hip_bfloat16* __restrict__ qkv,
                                               __hip_bfloat16* __restrict__ o) {
    __shared__ short Ks[KVB * HS];
    __shared__ short Vt[HS * KVB];
    __shared__ short Pl[4 * 32 * KVB];

    const int bh = blockIdx.x;
    const int hh = bh % HH;
    const int bI = bh / HH;
    const int qt = (TT / QBLK - 1) - blockIdx.y;
    const int q0 = qt * QBLK;

    const int tid = threadIdx.x;
    const int lane = tid & 63;
    const int wave = tid >> 6;
    const int fr = lane & 15;
    const int hi4 = lane >> 4;

    const size_t rowbase = (size_t)bI * TT;
    const int wq0 = q0 + wave * 32;

    bf16x8_t qf[2][2];
#pragma unroll
    for (int mi = 0; mi < 2; ++mi)
#pragma unroll
        for (int kc = 0; kc < 2; ++kc) {
            const short* src = (const short*)qkv +
                (rowbase + wq0 + mi * 16 + fr) * QS + hh * HS + kc * 32 + hi4 * 8;
            bf16x8_t v = *(const bf16x8_t*)src;
#pragma unroll
            for (int e = 0; e < 8; ++e) {
                float f = __uint_as_float(((unsigned)(unsigned short)v[e]) << 16) * 0.125f;
                v[e] = (short)(__float_as_uint(f) >> 16);
            }
            qf[mi][kc] = v;
        }

    f32x4_t oa[2][4];
    float m_r[2][4], l_r[2][4];
#pragma unroll
    for (int mi = 0; mi < 2; ++mi)
#pragma unroll
        for (int r = 0; r < 4; ++r) {
            m_r[mi][r] = -INFINITY;
            l_r[mi][r] = 0.f;
#pragma unroll
            for (int nd = 0; nd < 4; ++nd) oa[mi][nd][r] = 0.f;
        }

    const int skey = tid >> 2;
    const int sd0 = (tid & 3) * 16;
    const int niter = 2 * (qt + 1);

    for (int it = 0; it < niter; ++it) {
        const int kv0 = it * KVB;
        __syncthreads();
        {
            const short* kg = (const short*)qkv + (rowbase + kv0 + skey) * QS + EE + hh * HS + sd0;
            uint4 ka = *(const uint4*)kg;
            uint4 kb2 = *(const uint4*)(kg + 8);
            const int rs = (skey & 7) << 4;
            char* kbp = (char*)Ks;
            *(uint4*)(kbp + ((skey * 128 + sd0 * 2) ^ rs)) = ka;
            *(uint4*)(kbp + ((skey * 128 + sd0 * 2 + 16) ^ rs)) = kb2;

            const short* vg = (const short*)qkv + (rowbase + kv0 + skey) * QS + 2 * EE + hh * HS + sd0;
            uint4 va = *(const uint4*)vg;
            uint4 vb2 = *(const uint4*)(vg + 8);
            char* vbp = (char*)Vt;
            const short* vs0 = (const short*)&va;
#pragma unroll
            for (int e = 0; e < 8; ++e) {
                int dd = sd0 + e;
                *(short*)(vbp + ((dd * 128 + skey * 2) ^ ((dd & 7) << 4))) = vs0[e];
            }
            const short* vs1 = (const short*)&vb2;
#pragma unroll
            for (int e = 0; e < 8; ++e) {
                int dd = sd0 + 8 + e;
                *(short*)(vbp + ((dd * 128 + skey * 2) ^ ((dd & 7) << 4))) = vs1[e];
            }
        }
        __syncthreads();

        f32x4_t sa[2][4];
#pragma unroll
        for (int mi = 0; mi < 2; ++mi)
#pragma unroll
            for (int ni = 0; ni < 4; ++ni)
#pragma unroll
                for (int r = 0; r < 4; ++r) sa[mi][ni][r] = 0.f;
#pragma unroll
        for (int kc = 0; kc < 2; ++kc) {
            bf16x8_t kf[4];
#pragma unroll
            for (int ni = 0; ni < 4; ++ni) {
                int krow = ni * 16 + fr;
                kf[ni] = *(const bf16x8_t*)((char*)Ks +
                    ((krow * 128 + (kc * 32 + hi4 * 8) * 2) ^ ((krow & 7) << 4)));
            }
#pragma unroll
            for (int mi = 0; mi < 2; ++mi)
#pragma unroll
                for (int ni = 0; ni < 4; ++ni)
                    sa[mi][ni] = __builtin_amdgcn_mfma_f32_16x16x32_bf16(qf[mi][kc], kf[ni], sa[mi][ni], 0, 0, 0);
        }

        if (kv0 + KVB - 1 > wq0) {
#pragma unroll
            for (int mi = 0; mi < 2; ++mi)
#pragma unroll
                for (int ni = 0; ni < 4; ++ni)
#pragma unroll
                    for (int r = 0; r < 4; ++r) {
                        int qrow = wq0 + mi * 16 + hi4 * 4 + r;
                        int key = kv0 + ni * 16 + fr;
                        if (key > qrow) sa[mi][ni][r] = -1e30f;
                    }
        }

        char* Pw = (char*)Pl + wave * 4096;
#pragma unroll
        for (int mi = 0; mi < 2; ++mi)
#pragma unroll
            for (int r = 0; r < 4; ++r) {
                float mx = fmaxf(fmaxf(sa[mi][0][r], sa[mi][1][r]),
                                 fmaxf(sa[mi][2][r], sa[mi][3][r]));
#pragma unroll
                for (int off = 1; off < 16; off <<= 1) mx = fmaxf(mx, __shfl_xor(mx, off));
                float mnew = fmaxf(m_r[mi][r], mx);
                float al = __expf(m_r[mi][r] - mnew);
                m_r[mi][r] = mnew;
                float ps = 0.f;
#pragma unroll
                for (int ni = 0; ni < 4; ++ni) {
                    float p = __expf(sa[mi][ni][r] - mnew);
                    sa[mi][ni][r] = p;
                    ps += p;
                }
#pragma unroll
                for (int off = 1; off < 16; off <<= 1) ps += __shfl_xor(ps, off);
                l_r[mi][r] = l_r[mi][r] * al + ps;
#pragma unroll
                for (int nd = 0; nd < 4; ++nd) oa[mi][nd][r] *= al;
            }

#pragma unroll
        for (int mi = 0; mi < 2; ++mi)
#pragma unroll
            for (int ni = 0; ni < 4; ++ni)
#pragma unroll
                for (int r = 0; r < 4; ++r) {
                    int prow = mi * 16 + hi4 * 4 + r;
                    *(__hip_bfloat16*)(Pw + ((prow * 128 + (ni * 16 + fr) * 2) ^ ((prow & 7) << 4))) =
                        __float2bfloat16(sa[mi][ni][r]);
                }

#pragma unroll
        for (int kc = 0; kc < 2; ++kc) {
            bf16x8_t pf[2], vf[4];
#pragma unroll
            for (int mi = 0; mi < 2; ++mi) {
                int prow = mi * 16 + fr;
                pf[mi] = *(const bf16x8_t*)(Pw +
                    ((prow * 128 + (kc * 32 + hi4 * 8) * 2) ^ ((prow & 7) << 4)));
            }
#pragma unroll
            for (int nd = 0; nd < 4; ++nd) {
                int vrow = nd * 16 + fr;
                vf[nd] = *(const bf16x8_t*)((char*)Vt +
                    ((vrow * 128 + (kc * 32 + hi4 * 8) * 2) ^ ((vrow & 7) << 4)));
            }
#pragma unroll
            for (int mi = 0; mi < 2; ++mi)
#pragma unroll
                for (int nd = 0; nd < 4; ++nd)
                    oa[mi][nd] = __builtin_amdgcn_mfma_f32_16x16x32_bf16(pf[mi], vf[nd], oa[mi][nd], 0, 0, 0);
        }
    }

#pragma unroll
    for (int mi = 0; mi < 2; ++mi)
#pragma unroll
        for (int r = 0; r < 4; ++r) {
            float inv = 1.0f / l_r[mi][r];
            int row = wq0 + mi * 16 + hi4 * 4 + r;
            __hip_bfloat16* orow = o + (rowbase + row) * EE + hh * HS;
#pragma unroll
            for (int nd = 0; nd < 4; ++nd)
                orow[nd * 16 + fr] = __float2bfloat16(oa[mi][nd][r] * inv);
        }
}

// ---------------- loss: merge per-block LSE partials ----------------
__global__ __launch_bounds__(256) void rowloss2_k(const float2* __restrict__ partials,
                                                  const float* __restrict__ logits,
                                                  const int* __restrict__ targets,
                                                  float* __restrict__ rowloss, int ntn) {
    __shared__ float red[4];
    int row = blockIdx.x;
    int tid = threadIdx.x;
    float m = -INFINITY, l = 0.f;
    if (tid < ntn) {
        float2 p = partials[(size_t)row * ntn + tid];
        m = p.x; l = p.y;
    }
    float mg = block_max256(m, red);
    float s = (tid < ntn) ? l * __expf(m - mg) : 0.f;
    s = block_sum256(s, red);
    if (tid == 0)
        rowloss[row] = mg + logf(s) - logits[(size_t)row * VV + targets[row]];
}

__global__ __launch_bounds__(256) void loss_final_k(const float* __restrict__ rowloss,
                                                    float* __restrict__ out) {
    __shared__ float red[4];
    float s = 0.f;
    for (int i = threadIdx.x; i < MROWS; i += 256) s += rowloss[i];
    s = block_sum256(s, red);
    if (threadIdx.x == 0) out[0] = s * (1.0f / MROWS);
}

// ---------------- launcher ----------------
extern "C" void kernel_launch(void* const* d_in, const int* in_sizes, int n_in,
                              void* d_out, int out_size, void* d_ws, size_t ws_size,
                              hipStream_t stream) {
    const int* idx      = (const int*)d_in[0];
    const int* targets  = (const int*)d_in[1];
    const float* tok    = (const float*)d_in[2];
    const float* pos    = (const float*)d_in[3];
    const float* Wq     = (const float*)d_in[4];
    const float* Wk     = (const float*)d_in[5];
    const float* Wv     = (const float*)d_in[6];
    const float* Wp     = (const float*)d_in[7];
    const float* bp     = (const float*)d_in[8];
    const float* W1     = (const float*)d_in[9];
    const float* b1     = (const float*)d_in[10];
    const float* W2     = (const float*)d_in[11];
    const float* b2     = (const float*)d_in[12];
    const float* ln1_g  = (const float*)d_in[13];
    const float* ln1_b  = (const float*)d_in[14];
    const float* ln2_g  = (const float*)d_in[15];
    const float* ln2_b  = (const float*)d_in[16];
    const float* lnf_g  = (const float*)d_in[17];
    const float* lnf_b  = (const float*)d_in[18];
    const float* Wlm    = (const float*)d_in[19];
    const float* blm    = (const float*)d_in[20];

    float* out = (float*)d_out;

    // ---- workspace carve ----
    char* w = (char*)d_ws;
    float* x = (float*)w;                             w += (size_t)MROWS * EE * 4;
    __hip_bfloat16* hbf = (__hip_bfloat16*)w;         w += (size_t)MROWS * EE * 2;
    __hip_bfloat16* qkv = (__hip_bfloat16*)w;         w += (size_t)MROWS * QS * 2;
    __hip_bfloat16* obf = (__hip_bfloat16*)w;         w += (size_t)MROWS * EE * 2;
    __hip_bfloat16* ff1 = (__hip_bfloat16*)w;         w += (size_t)MROWS * FFD * 2;
    float2* partials = (float2*)ff1;                  // aliases ff1: dead by LM-head time
    __hip_bfloat16* wlmT = (__hip_bfloat16*)w;        w += (size_t)VV * EE * 2;
    float* rowloss = (float*)w;                       w += (size_t)MROWS * 4 + 256;
    __hip_bfloat16* wbase = (__hip_bfloat16*)w;       // layer weights from here

    const size_t base_used = (size_t)(w - (char*)d_ws);
    const size_t per_layer_w = ((size_t)QS * EE + (size_t)EE * EE +
                                (size_t)FFD * EE + (size_t)EE * FFD) * 2;  // bytes
    const bool hoist = ws_size >= base_used + per_layer_w * LAYERS;
    const int nlw = hoist ? LAYERS : 1;

    __hip_bfloat16* qkvwT = wbase;
    __hip_bfloat16* wpT   = qkvwT + (size_t)nlw * QS * EE;
    __hip_bfloat16* w1T   = wpT   + (size_t)nlw * EE * EE;
    __hip_bfloat16* w2T   = w1T   + (size_t)nlw * FFD * EE;

    dim3 blk(256);

    embed_k<<<MROWS, blk, 0, stream>>>(idx, tok, pos, x);

    if (hoist) {
        // all-layer weight conversion up front (z = layer)
        tconv_b_k<<<dim3(EE / 32, EE / 32, LAYERS), blk, 0, stream>>>(
            Wq, qkvwT, EE, EE, (size_t)EE * EE, (size_t)QS * EE);
        tconv_b_k<<<dim3(EE / 32, EE / 32, LAYERS), blk, 0, stream>>>(
            Wk, qkvwT + (size_t)EE * EE, EE, EE, (size_t)EE * EE, (size_t)QS * EE);
        tconv_b_k<<<dim3(EE / 32, EE / 32, LAYERS), blk, 0, stream>>>(
            Wv, qkvwT + (size_t)2 * EE * EE, EE, EE, (size_t)EE * EE, (size_t)QS * EE);
        tconv_b_k<<<dim3(EE / 32, EE / 32, LAYERS), blk, 0, stream>>>(
            Wp, wpT, EE, EE, (size_t)EE * EE, (size_t)EE * EE);
        tconv_b_k<<<dim3(FFD / 32, EE / 32, LAYERS), blk, 0, stream>>>(
            W1, w1T, EE, FFD, (size_t)EE * FFD, (size_t)FFD * EE);
        tconv_b_k<<<dim3(EE / 32, FFD / 32, LAYERS), blk, 0, stream>>>(
            W2, w2T, FFD, EE, (size_t)FFD * EE, (size_t)EE * FFD);
    }
    tconv_b_k<<<dim3(VV / 32, EE / 32, 1), blk, 0, stream>>>(Wlm, wlmT, EE, VV, 0, 0);

    for (int l = 0; l < LAYERS; ++l) {
        __hip_bfloat16* qkvwT_l = qkvwT + (hoist ? (size_t)l * QS * EE : 0);
        __hip_bfloat16* wpT_l   = wpT   + (hoist ? (size_t)l * EE * EE : 0);
        __hip_bfloat16* w1T_l   = w1T   + (hoist ? (size_t)l * FFD * EE : 0);
        __hip_bfloat16* w2T_l   = w2T   + (hoist ? (size_t)l * EE * FFD : 0);
        if (!hoist) {
            tconv_b_k<<<dim3(EE / 32, EE / 32, 1), blk, 0, stream>>>(
                Wq + (size_t)l * EE * EE, qkvwT_l, EE, EE, 0, 0);
            tconv_b_k<<<dim3(EE / 32, EE / 32, 1), blk, 0, stream>>>(
                Wk + (size_t)l * EE * EE, qkvwT_l + (size_t)EE * EE, EE, EE, 0, 0);
            tconv_b_k<<<dim3(EE / 32, EE / 32, 1), blk, 0, stream>>>(
                Wv + (size_t)l * EE * EE, qkvwT_l + (size_t)2 * EE * EE, EE, EE, 0, 0);
            tconv_b_k<<<dim3(EE / 32, EE / 32, 1), blk, 0, stream>>>(
                Wp + (size_t)l * EE * EE, wpT_l, EE, EE, 0, 0);
            tconv_b_k<<<dim3(FFD / 32, EE / 32, 1), blk, 0, stream>>>(
                W1 + (size_t)l * EE * FFD, w1T_l, EE, FFD, 0, 0);
            tconv_b_k<<<dim3(EE / 32, FFD / 32, 1), blk, 0, stream>>>(
                W2 + (size_t)l * FFD * EE, w2T_l, FFD, EE, 0, 0);
        }

        ln_k<<<MROWS, blk, 0, stream>>>(x, ln1_g + l * EE, ln1_b + l * EE, hbf);
        mgemm_k<false, false, false, true, false, false>
            <<<dim3((MROWS / 128) * (QS / 128)), blk, 0, stream>>>(
            hbf, qkvwT_l, nullptr, qkv, MROWS, QS, EE, MROWS / 128, QS / 128, nullptr);
        fattn_k<<<dim3(BB * HH, TT / QBLK), blk, 0, stream>>>(qkv, obf);
        mgemm_k<true, false, true, false, false, false>
            <<<dim3((MROWS / 128) * (EE / 128)), blk, 0, stream>>>(
            obf, wpT_l, bp + l * EE, x, MROWS, EE, EE, MROWS / 128, EE / 128, nullptr);
        ln_k<<<MROWS, blk, 0, stream>>>(x, ln2_g + l * EE, ln2_b + l * EE, hbf);
        mgemm_k<true, true, false, true, false, false>
            <<<dim3((MROWS / 128) * (FFD / 128)), blk, 0, stream>>>(
            hbf, w1T_l, b1 + l * FFD, ff1, MROWS, FFD, EE, MROWS / 128, FFD / 128, nullptr);
        mgemm_k<true, false, true, false, false, false>
            <<<dim3((MROWS / 128) * (EE / 128)), blk, 0, stream>>>(
            ff1, w2T_l, b2 + l * EE, x, MROWS, EE, FFD, MROWS / 128, EE / 128, nullptr);
    }

    ln_k<<<MROWS, blk, 0, stream>>>(x, lnf_g, lnf_b, hbf);
    // LM head: col-major tile order (B-panel reuse) + fused LSE partials
    mgemm_k<true, false, false, false, true, true>
        <<<dim3((MROWS / 128) * (VV / 128)), blk, 0, stream>>>(
        hbf, wlmT, blm, out, MROWS, VV, EE, MROWS / 128, NTN_LM, partials);

    rowloss2_k<<<MROWS, blk, 0, stream>>>(partials, out, targets, rowloss, NTN_LM);
    loss_final_k<<<1, blk, 0, stream>>>(rowloss, out + (size_t)MROWS * VV);
}

// Round 5
// 1945.402 us; speedup vs baseline: 8.0234x; 1.0079x over previous
//
#include <hip/hip_runtime.h>
#include <hip/hip_bf16.h>
#include <math.h>

#define LAYERS 6
#define BB 4
#define TT 1024
#define EE 768
#define HH 12
#define HS 64
#define VV 32000
#define FFD 3072
#define MROWS (BB * TT)   // 4096
#define QS (3 * EE)       // 2304, fused qkv row stride
#define KVB 64
#define QBLK 128
#define NPART (VV / 256)  // 125 LSE partial blocks per row

typedef __attribute__((ext_vector_type(8))) short bf16x8_t;
typedef __attribute__((ext_vector_type(4))) float f32x4_t;

// ---------------- helpers ----------------
__device__ __forceinline__ float wave_sum(float v) {
#pragma unroll
    for (int o = 32; o > 0; o >>= 1) v += __shfl_xor(v, o);
    return v;
}
__device__ __forceinline__ float wave_max(float v) {
#pragma unroll
    for (int o = 32; o > 0; o >>= 1) v = fmaxf(v, __shfl_xor(v, o));
    return v;
}
__device__ __forceinline__ float block_sum256(float v, float* red) {
    v = wave_sum(v);
    int tid = threadIdx.x;
    if ((tid & 63) == 0) red[tid >> 6] = v;
    __syncthreads();
    float r = red[0] + red[1] + red[2] + red[3];
    __syncthreads();
    return r;
}
__device__ __forceinline__ float block_max256(float v, float* red) {
    v = wave_max(v);
    int tid = threadIdx.x;
    if ((tid & 63) == 0) red[tid >> 6] = v;
    __syncthreads();
    float r = fmaxf(fmaxf(red[0], red[1]), fmaxf(red[2], red[3]));
    __syncthreads();
    return r;
}

__device__ __forceinline__ void gload_lds16(const void* g, void* l) {
    __builtin_amdgcn_global_load_lds((const __attribute__((address_space(1))) void*)g,
                                     (__attribute__((address_space(3))) void*)l, 16, 0, 0);
}

// ---------------- embedding ----------------
__global__ __launch_bounds__(256) void embed_k(const int* __restrict__ idx,
                                               const float* __restrict__ tok,
                                               const float* __restrict__ pos,
                                               float* __restrict__ x) {
    int row = blockIdx.x;
    int t = row & (TT - 1);
    int token = idx[row];
    const float* te = tok + (size_t)token * EE;
    const float* pe = pos + (size_t)t * EE;
    float* xr = x + (size_t)row * EE;
    for (int i = threadIdx.x; i < EE; i += 256) xr[i] = te[i] + pe[i];
}

// ---------------- LayerNorm: fp32 in -> bf16 out ----------------
__global__ __launch_bounds__(256) void ln_k(const float* __restrict__ x,
                                            const float* __restrict__ g,
                                            const float* __restrict__ b,
                                            __hip_bfloat16* __restrict__ out) {
    __shared__ float sr[EE];
    __shared__ float red[4];
    int row = blockIdx.x;
    const float* xr = x + (size_t)row * EE;
    int tid = threadIdx.x;
    float s = 0.f;
    for (int i = tid; i < EE; i += 256) { float v = xr[i]; sr[i] = v; s += v; }
    s = block_sum256(s, red);
    float m = s * (1.0f / EE);
    float vs = 0.f;
    for (int i = tid; i < EE; i += 256) { float d = sr[i] - m; vs += d * d; }
    vs = block_sum256(vs, red);
    float rstd = rsqrtf(vs * (1.0f / EE) + 1e-5f);
    __hip_bfloat16* orow = out + (size_t)row * EE;
    for (int i = tid; i < EE; i += 256)
        orow[i] = __float2bfloat16((sr[i] - m) * rstd * g[i] + b[i]);
}

// ---------------- batched transpose-convert: W fp32 [R,C] -> WT bf16 [C,R] ------
__global__ __launch_bounds__(256) void tconv_b_k(const float* __restrict__ W,
                                                 __hip_bfloat16* __restrict__ WT,
                                                 int R, int C,
                                                 size_t wstride, size_t tstride) {
    __shared__ float t[32][33];
    const float* Wl = W + (size_t)blockIdx.z * wstride;
    __hip_bfloat16* Tl = WT + (size_t)blockIdx.z * tstride;
    int c0 = blockIdx.x * 32, r0 = blockIdx.y * 32;
    int tx = threadIdx.x & 31, ty = threadIdx.x >> 5;
#pragma unroll
    for (int i = 0; i < 4; ++i)
        t[ty + 8 * i][tx] = Wl[(size_t)(r0 + ty + 8 * i) * C + c0 + tx];
    __syncthreads();
#pragma unroll
    for (int i = 0; i < 4; ++i)
        Tl[(size_t)(c0 + ty + 8 * i) * R + r0 + tx] = __float2bfloat16(t[tx][ty + 8 * i]);
}

// ---------------- MFMA GEMM (m97 structure, 128x128, BK=32) — round-3 form ------
template <bool BIAS, bool RELU, bool ACCUM, bool OBF16>
__global__ __launch_bounds__(256) void mgemm_k(const __hip_bfloat16* __restrict__ A,
                                               const __hip_bfloat16* __restrict__ BT,
                                               const float* __restrict__ bias,
                                               void* __restrict__ Cv,
                                               int M, int N, int K, int ntn) {
    __shared__ __align__(16) short As[128 * 32];
    __shared__ __align__(16) short Bs[128 * 32];

    int nwg = gridDim.x;
    int bid = blockIdx.x;
    int cpx = nwg >> 3;
    int swz = (bid & 7) * cpx + (bid >> 3);
    int tm = swz / ntn, tn = swz - tm * ntn;
    int m0 = tm * 128, n0 = tn * 128;

    int tid = threadIdx.x;
    int lane = tid & 63;
    int wave = tid >> 6;
    int wr = wave >> 1, wc = wave & 1;

    f32x4_t acc[4][4];
#pragma unroll
    for (int i = 0; i < 4; ++i)
#pragma unroll
        for (int j = 0; j < 4; ++j)
#pragma unroll
            for (int r = 0; r < 4; ++r) acc[i][j][r] = 0.f;

    const short* Ag = (const short*)A;
    const short* Bg = (const short*)BT;
    const int arow0 = tid >> 2;
    const int arow1 = (tid + 256) >> 2;
    const int acol = (tid & 3) * 8;

    const int fr = lane & 15;
    const int kg = (lane >> 4) * 8;

    for (int k0 = 0; k0 < K; k0 += 32) {
        gload_lds16(Ag + (size_t)(m0 + arow0) * K + k0 + acol, &As[tid * 8]);
        gload_lds16(Ag + (size_t)(m0 + arow1) * K + k0 + acol, &As[(tid + 256) * 8]);
        gload_lds16(Bg + (size_t)(n0 + arow0) * K + k0 + acol, &Bs[tid * 8]);
        gload_lds16(Bg + (size_t)(n0 + arow1) * K + k0 + acol, &Bs[(tid + 256) * 8]);
        __syncthreads();

        bf16x8_t af[4], bq[4];
#pragma unroll
        for (int mi = 0; mi < 4; ++mi)
            af[mi] = *(const bf16x8_t*)&As[(wr * 64 + mi * 16 + fr) * 32 + kg];
#pragma unroll
        for (int ni = 0; ni < 4; ++ni)
            bq[ni] = *(const bf16x8_t*)&Bs[(wc * 64 + ni * 16 + fr) * 32 + kg];
#pragma unroll
        for (int mi = 0; mi < 4; ++mi)
#pragma unroll
            for (int ni = 0; ni < 4; ++ni)
                acc[mi][ni] = __builtin_amdgcn_mfma_f32_16x16x32_bf16(af[mi], bq[ni], acc[mi][ni], 0, 0, 0);
        __syncthreads();
    }

    float bvec[4];
    if (BIAS) {
#pragma unroll
        for (int ni = 0; ni < 4; ++ni) bvec[ni] = bias[n0 + wc * 64 + ni * 16 + fr];
    }
    const int rbase = m0 + wr * 64 + (lane >> 4) * 4;
    const int cbase = n0 + wc * 64 + fr;
#pragma unroll
    for (int mi = 0; mi < 4; ++mi) {
#pragma unroll
        for (int ni = 0; ni < 4; ++ni) {
#pragma unroll
            for (int r = 0; r < 4; ++r) {
                int row = rbase + mi * 16 + r;
                int col = cbase + ni * 16;
                float v = acc[mi][ni][r];
                if (BIAS) v += bvec[ni];
                if (RELU) v = fmaxf(v, 0.f);
                size_t off = (size_t)row * N + col;
                if (OBF16) {
                    ((__hip_bfloat16*)Cv)[off] = __float2bfloat16(v);
                } else {
                    float* Cf = (float*)Cv;
                    if (ACCUM) Cf[off] += v; else Cf[off] = v;
                }
            }
        }
    }
}

// ---------------- 256x256 8-phase MFMA GEMM (T2+T3+T4+T5), BK=64, 512 thr -------
// Per K-tile: 4 phases; phase p = (ah = p>>1 row-half, s = p&1 col-strip).
// Staging (half-tile = 2 gload_lds, issued only after its target half is dead):
//   ph0: (t+1).A1   ph1: (t+1).B1   ph2: (t+2).A0   ph3: (t+2).B0
// One counted vmcnt(4) per tile at ph3 (drain vmcnt(0) only at t==nt-2).
// LDS swizzle: byte ^= (row&7)<<4 on ds_read; gload_lds dest linear, global
// source inverse-swizzled (rule 21).
__device__ __forceinline__ bf16x8_t ldsrd256(const short* base, int row, int colb) {
    return *(const bf16x8_t*)((const char*)base + ((row << 7) + (colb ^ ((row & 7) << 4))));
}

template <bool BIAS, bool RELU, bool OBF16, bool LSE>
__global__ __launch_bounds__(512, 2) void mgemm256_k(const __hip_bfloat16* __restrict__ A,
                                                     const __hip_bfloat16* __restrict__ BT,
                                                     const float* __restrict__ bias,
                                                     void* __restrict__ Cv,
                                                     int M, int N, int K,
                                                     int ntn, int npart,
                                                     float2* __restrict__ partials) {
    __shared__ __align__(16) short lds[2][2][2][8192];   // [buf][A/B][half][128*64]

    const int nwg = gridDim.x;
    const int bid = blockIdx.x;
    const int cpx = nwg >> 3;
    const int swz = (bid & 7) * cpx + (bid >> 3);
    const int tm = swz / ntn, tn = swz - tm * ntn;
    const int m0 = tm * 256, n0 = tn * 256;

    const int tid = threadIdx.x;
    const int lane = tid & 63;
    const int wave = tid >> 6;
    const int wm = wave >> 2;       // 0..1
    const int wn = wave & 3;        // 0..3
    const int fr = lane & 15;
    const int hi4 = lane >> 4;

    const short* Ag = (const short*)A;
    const short* Bg = (const short*)BT;
    const int nt = K >> 6;          // 12

    // stage one 128x64 half: 2 gload_lds, linear LDS dest, inverse-swizzled src
    auto stage_half = [&](const short* g, int grow0, int k0, short* lbase) {
#pragma unroll
        for (int sub = 0; sub < 2; ++sub) {
            int d = sub * 8192 + tid * 16;
            int row = d >> 7;
            int cb = d & 127;
            int col = (cb ^ ((row & 7) << 4)) >> 1;
            gload_lds16(g + (size_t)(grow0 + row) * K + k0 + col, (char*)lbase + d);
        }
    };

    f32x4_t acc[2][2][4][2];
#pragma unroll
    for (int ah = 0; ah < 2; ++ah)
#pragma unroll
        for (int s = 0; s < 2; ++s)
#pragma unroll
            for (int mi = 0; mi < 4; ++mi)
#pragma unroll
                for (int ni = 0; ni < 2; ++ni)
#pragma unroll
                    for (int r = 0; r < 4; ++r) acc[ah][s][mi][ni][r] = 0.f;

    // prologue: tile0 all 4 halves + tile1 A0,B0  (12 loads)
    stage_half(Ag, m0 + 0,   0,  &lds[0][0][0][0]);
    stage_half(Bg, n0 + 0,   0,  &lds[0][1][0][0]);
    stage_half(Ag, m0 + 128, 0,  &lds[0][0][1][0]);
    stage_half(Bg, n0 + 128, 0,  &lds[0][1][1][0]);
    stage_half(Ag, m0 + 0,   64, &lds[1][0][0][0]);
    stage_half(Bg, n0 + 0,   64, &lds[1][1][0][0]);
    asm volatile("s_waitcnt vmcnt(4)" ::: "memory");
    __builtin_amdgcn_s_barrier();

    for (int t = 0; t < nt; ++t) {
        const int c = t & 1, o = c ^ 1;
        bf16x8_t a[4][2];
#pragma unroll
        for (int p = 0; p < 4; ++p) {
            const int ah = p >> 1, s = p & 1;
            // ---- ds_reads for this phase ----
            if (s == 0) {
#pragma unroll
                for (int mi = 0; mi < 4; ++mi)
#pragma unroll
                    for (int kk = 0; kk < 2; ++kk)
                        a[mi][kk] = ldsrd256(&lds[c][0][ah][0],
                                             wm * 64 + mi * 16 + fr, kk * 64 + hi4 * 16);
            }
            bf16x8_t b[2][2];
#pragma unroll
            for (int ni = 0; ni < 2; ++ni)
#pragma unroll
                for (int kk = 0; kk < 2; ++kk)
                    b[ni][kk] = ldsrd256(&lds[c][1][s][0],
                                         wn * 32 + ni * 16 + fr, kk * 64 + hi4 * 16);
            // ---- stage (target half died last phase; prev post-barrier protects) ----
            if (p == 0 && t + 1 < nt) stage_half(Ag, m0 + 128, (t + 1) * 64, &lds[o][0][1][0]);
            if (p == 1 && t + 1 < nt) stage_half(Bg, n0 + 128, (t + 1) * 64, &lds[o][1][1][0]);
            if (p == 2 && t + 2 < nt) stage_half(Ag, m0 + 0,   (t + 2) * 64, &lds[c][0][0][0]);
            if (p == 3 && t + 2 < nt) stage_half(Bg, n0 + 0,   (t + 2) * 64, &lds[c][1][0][0]);
            // ---- tile-boundary counted wait (never 0 until drain) ----
            if (p == 3) {
                if (t < nt - 2)       asm volatile("s_waitcnt vmcnt(4)" ::: "memory");
                else if (t == nt - 2) asm volatile("s_waitcnt vmcnt(0)" ::: "memory");
            }
            __builtin_amdgcn_s_barrier();
            asm volatile("s_waitcnt lgkmcnt(0)" ::: "memory");
            __builtin_amdgcn_sched_barrier(0);
            __builtin_amdgcn_s_setprio(1);
#pragma unroll
            for (int mi = 0; mi < 4; ++mi)
#pragma unroll
                for (int ni = 0; ni < 2; ++ni)
#pragma unroll
                    for (int kk = 0; kk < 2; ++kk)
                        acc[ah][s][mi][ni] = __builtin_amdgcn_mfma_f32_16x16x32_bf16(
                            a[mi][kk], b[ni][kk], acc[ah][s][mi][ni], 0, 0, 0);
            __builtin_amdgcn_s_setprio(0);
            __builtin_amdgcn_s_barrier();
        }
    }

    // ---- epilogue ----
    float bv[2][2];
    if (BIAS) {
#pragma unroll
        for (int s = 0; s < 2; ++s)
#pragma unroll
            for (int ni = 0; ni < 2; ++ni)
                bv[s][ni] = bias[n0 + s * 128 + wn * 32 + ni * 16 + fr];
    }
    float2* red = (float2*)&lds[0][0][0][0];   // vmcnt drained; all reads done
#pragma unroll
    for (int ah = 0; ah < 2; ++ah) {
#pragma unroll
        for (int mi = 0; mi < 4; ++mi) {
#pragma unroll
            for (int r = 0; r < 4; ++r) {
                const int rb = ah * 128 + wm * 64 + mi * 16 + hi4 * 4 + r;
                const size_t grow = (size_t)(m0 + rb);
                float v[2][2];
#pragma unroll
                for (int s = 0; s < 2; ++s)
#pragma unroll
                    for (int ni = 0; ni < 2; ++ni) {
                        float vv = acc[ah][s][mi][ni][r];
                        if (BIAS) vv += bv[s][ni];
                        if (RELU) vv = fmaxf(vv, 0.f);
                        v[s][ni] = vv;
                        size_t off = grow * N + n0 + s * 128 + wn * 32 + ni * 16 + fr;
                        if (OBF16) ((__hip_bfloat16*)Cv)[off] = __float2bfloat16(vv);
                        else       ((float*)Cv)[off] = vv;
                    }
                if (LSE) {
                    float mx = fmaxf(fmaxf(v[0][0], v[0][1]), fmaxf(v[1][0], v[1][1]));
#pragma unroll
                    for (int off2 = 1; off2 < 16; off2 <<= 1) mx = fmaxf(mx, __shfl_xor(mx, off2));
                    float sm = 0.f;
#pragma unroll
                    for (int s = 0; s < 2; ++s)
#pragma unroll
                        for (int ni = 0; ni < 2; ++ni) sm += __expf(v[s][ni] - mx);
#pragma unroll
                    for (int off2 = 1; off2 < 16; off2 <<= 1) sm += __shfl_xor(sm, off2);
                    if (fr == 0) red[rb * 4 + wn] = make_float2(mx, sm);
                }
            }
        }
    }
    if (LSE) {
        __syncthreads();
        if (tid < 256) {
            float2 p0 = red[tid * 4 + 0], p1 = red[tid * 4 + 1];
            float2 p2 = red[tid * 4 + 2], p3 = red[tid * 4 + 3];
            float M2 = fmaxf(fmaxf(p0.x, p1.x), fmaxf(p2.x, p3.x));
            float L2 = p0.y * __expf(p0.x - M2) + p1.y * __expf(p1.x - M2) +
                       p2.y * __expf(p2.x - M2) + p3.y * __expf(p3.x - M2);
            partials[(size_t)(m0 + tid) * npart + tn] = make_float2(M2, L2);
        }
    }
}

// ---------------- MFMA flash attention (unchanged) ----------------
__global__ __launch_bounds__(256) void fattn_k(const __hip_bfloat16* __restrict__ qkv,
                                               __hip_bfloat16* __restrict__ o) {
    __shared__ short Ks[KVB * HS];
    __shared__ short Vt[HS * KVB];
    __shared__ short Pl[4 * 32 * KVB];

    const int bh = blockIdx.x;
    const int hh = bh % HH;
    const int bI = bh / HH;
    const int qt = (TT / QBLK - 1) - blockIdx.y;
    const int q0 = qt * QBLK;

    const int tid = threadIdx.x;
    const int lane = tid & 63;
    const int wave = tid >> 6;
    const int fr = lane & 15;
    const int hi4 = lane >> 4;

    const size_t rowbase = (size_t)bI * TT;
    const int wq0 = q0 + wave * 32;

    bf16x8_t qf[2][2];
#pragma unroll
    for (int mi = 0; mi < 2; ++mi)
#pragma unroll
        for (int kc = 0; kc < 2; ++kc) {
            const short* src = (const short*)qkv +
                (rowbase + wq0 + mi * 16 + fr) * QS + hh * HS + kc * 32 + hi4 * 8;
            bf16x8_t v = *(const bf16x8_t*)src;
#pragma unroll
            for (int e = 0; e < 8; ++e) {
                float f = __uint_as_float(((unsigned)(unsigned short)v[e]) << 16) * 0.125f;
                v[e] = (short)(__float_as_uint(f) >> 16);
            }
            qf[mi][kc] = v;
        }

    f32x4_t oa[2][4];
    float m_r[2][4], l_r[2][4];
#pragma unroll
    for (int mi = 0; mi < 2; ++mi)
#pragma unroll
        for (int r = 0; r < 4; ++r) {
            m_r[mi][r] = -INFINITY;
            l_r[mi][r] = 0.f;
#pragma unroll
            for (int nd = 0; nd < 4; ++nd) oa[mi][nd][r] = 0.f;
        }

    const int skey = tid >> 2;
    const int sd0 = (tid & 3) * 16;
    const int niter = 2 * (qt + 1);

    for (int it = 0; it < niter; ++it) {
        const int kv0 = it * KVB;
        __syncthreads();
        {
            const short* kg = (const short*)qkv + (rowbase + kv0 + skey) * QS + EE + hh * HS + sd0;
            uint4 ka = *(const uint4*)kg;
            uint4 kb2 = *(const uint4*)(kg + 8);
            const int rs = (skey & 7) << 4;
            char* kbp = (char*)Ks;
            *(uint4*)(kbp + ((skey * 128 + sd0 * 2) ^ rs)) = ka;
            *(uint4*)(kbp + ((skey * 128 + sd0 * 2 + 16) ^ rs)) = kb2;

            const short* vg = (const short*)qkv + (rowbase + kv0 + skey) * QS + 2 * EE + hh * HS + sd0;
            uint4 va = *(const uint4*)vg;
            uint4 vb2 = *(const uint4*)(vg + 8);
            char* vbp = (char*)Vt;
            const short* vs0 = (const short*)&va;
#pragma unroll
            for (int e = 0; e < 8; ++e) {
                int dd = sd0 + e;
                *(short*)(vbp + ((dd * 128 + skey * 2) ^ ((dd & 7) << 4))) = vs0[e];
            }
            const short* vs1 = (const short*)&vb2;
#pragma unroll
            for (int e = 0; e < 8; ++e) {
                int dd = sd0 + 8 + e;
                *(short*)(vbp + ((dd * 128 + skey * 2) ^ ((dd & 7) << 4))) = vs1[e];
            }
        }
        __syncthreads();

        f32x4_t sa[2][4];
#pragma unroll
        for (int mi = 0; mi < 2; ++mi)
#pragma unroll
            for (int ni = 0; ni < 4; ++ni)
#pragma unroll
                for (int r = 0; r < 4; ++r) sa[mi][ni][r] = 0.f;
#pragma unroll
        for (int kc = 0; kc < 2; ++kc) {
            bf16x8_t kf[4];
#pragma unroll
            for (int ni = 0; ni < 4; ++ni) {
                int krow = ni * 16 + fr;
                kf[ni] = *(const bf16x8_t*)((char*)Ks +
                    ((krow * 128 + (kc * 32 + hi4 * 8) * 2) ^ ((krow & 7) << 4)));
            }
#pragma unroll
            for (int mi = 0; mi < 2; ++mi)
#pragma unroll
                for (int ni = 0; ni < 4; ++ni)
                    sa[mi][ni] = __builtin_amdgcn_mfma_f32_16x16x32_bf16(qf[mi][kc], kf[ni], sa[mi][ni], 0, 0, 0);
        }

        if (kv0 + KVB - 1 > wq0) {
#pragma unroll
            for (int mi = 0; mi < 2; ++mi)
#pragma unroll
                for (int ni = 0; ni < 4; ++ni)
#pragma unroll
                    for (int r = 0; r < 4; ++r) {
                        int qrow = wq0 + mi * 16 + hi4 * 4 + r;
                        int key = kv0 + ni * 16 + fr;
                        if (key > qrow) sa[mi][ni][r] = -1e30f;
                    }
        }

        char* Pw = (char*)Pl + wave * 4096;
#pragma unroll
        for (int mi = 0; mi < 2; ++mi)
#pragma unroll
            for (int r = 0; r < 4; ++r) {
                float mx = fmaxf(fmaxf(sa[mi][0][r], sa[mi][1][r]),
                                 fmaxf(sa[mi][2][r], sa[mi][3][r]));
#pragma unroll
                for (int off = 1; off < 16; off <<= 1) mx = fmaxf(mx, __shfl_xor(mx, off));
                float mnew = fmaxf(m_r[mi][r], mx);
                float al = __expf(m_r[mi][r] - mnew);
                m_r[mi][r] = mnew;
                float ps = 0.f;
#pragma unroll
                for (int ni = 0; ni < 4; ++ni) {
                    float p = __expf(sa[mi][ni][r] - mnew);
                    sa[mi][ni][r] = p;
                    ps += p;
                }
#pragma unroll
                for (int off = 1; off < 16; off <<= 1) ps += __shfl_xor(ps, off);
                l_r[mi][r] = l_r[mi][r] * al + ps;
#pragma unroll
                for (int nd = 0; nd < 4; ++nd) oa[mi][nd][r] *= al;
            }

#pragma unroll
        for (int mi = 0; mi < 2; ++mi)
#pragma unroll
            for (int ni = 0; ni < 4; ++ni)
#pragma unroll
                for (int r = 0; r < 4; ++r) {
                    int prow = mi * 16 + hi4 * 4 + r;
                    *(__hip_bfloat16*)(Pw + ((prow * 128 + (ni * 16 + fr) * 2) ^ ((prow & 7) << 4))) =
                        __float2bfloat16(sa[mi][ni][r]);
                }

#pragma unroll
        for (int kc = 0; kc < 2; ++kc) {
            bf16x8_t pf[2], vf[4];
#pragma unroll
            for (int mi = 0; mi < 2; ++mi) {
                int prow = mi * 16 + fr;
                pf[mi] = *(const bf16x8_t*)(Pw +
                    ((prow * 128 + (kc * 32 + hi4 * 8) * 2) ^ ((prow & 7) << 4)));
            }
#pragma unroll
            for (int nd = 0; nd < 4; ++nd) {
                int vrow = nd * 16 + fr;
                vf[nd] = *(const bf16x8_t*)((char*)Vt +
                    ((vrow * 128 + (kc * 32 + hi4 * 8) * 2) ^ ((vrow & 7) << 4)));
            }
#pragma unroll
            for (int mi = 0; mi < 2; ++mi)
#pragma unroll
                for (int nd = 0; nd < 4; ++nd)
                    oa[mi][nd] = __builtin_amdgcn_mfma_f32_16x16x32_bf16(pf[mi], vf[nd], oa[mi][nd], 0, 0, 0);
        }
    }

#pragma unroll
    for (int mi = 0; mi < 2; ++mi)
#pragma unroll
        for (int r = 0; r < 4; ++r) {
            float inv = 1.0f / l_r[mi][r];
            int row = wq0 + mi * 16 + hi4 * 4 + r;
            __hip_bfloat16* orow = o + (rowbase + row) * EE + hh * HS;
#pragma unroll
            for (int nd = 0; nd < 4; ++nd)
                orow[nd * 16 + fr] = __float2bfloat16(oa[mi][nd][r] * inv);
        }
}

// ---------------- loss: merge per-block LSE partials ----------------
__global__ __launch_bounds__(256) void rowloss2_k(const float2* __restrict__ partials,
                                                  const float* __restrict__ logits,
                                                  const int* __restrict__ targets,
                                                  float* __restrict__ rowloss, int ntn) {
    __shared__ float red[4];
    int row = blockIdx.x;
    int tid = threadIdx.x;
    float m = -INFINITY, l = 0.f;
    if (tid < ntn) {
        float2 p = partials[(size_t)row * ntn + tid];
        m = p.x; l = p.y;
    }
    float mg = block_max256(m, red);
    float s = (tid < ntn) ? l * __expf(m - mg) : 0.f;
    s = block_sum256(s, red);
    if (tid == 0)
        rowloss[row] = mg + logf(s) - logits[(size_t)row * VV + targets[row]];
}

__global__ __launch_bounds__(256) void loss_final_k(const float* __restrict__ rowloss,
                                                    float* __restrict__ out) {
    __shared__ float red[4];
    float s = 0.f;
    for (int i = threadIdx.x; i < MROWS; i += 256) s += rowloss[i];
    s = block_sum256(s, red);
    if (threadIdx.x == 0) out[0] = s * (1.0f / MROWS);
}

// ---------------- launcher ----------------
extern "C" void kernel_launch(void* const* d_in, const int* in_sizes, int n_in,
                              void* d_out, int out_size, void* d_ws, size_t ws_size,
                              hipStream_t stream) {
    const int* idx      = (const int*)d_in[0];
    const int* targets  = (const int*)d_in[1];
    const float* tok    = (const float*)d_in[2];
    const float* pos    = (const float*)d_in[3];
    const float* Wq     = (const float*)d_in[4];
    const float* Wk     = (const float*)d_in[5];
    const float* Wv     = (const float*)d_in[6];
    const float* Wp     = (const float*)d_in[7];
    const float* bp     = (const float*)d_in[8];
    const float* W1     = (const float*)d_in[9];
    const float* b1     = (const float*)d_in[10];
    const float* W2     = (const float*)d_in[11];
    const float* b2     = (const float*)d_in[12];
    const float* ln1_g  = (const float*)d_in[13];
    const float* ln1_b  = (const float*)d_in[14];
    const float* ln2_g  = (const float*)d_in[15];
    const float* ln2_b  = (const float*)d_in[16];
    const float* lnf_g  = (const float*)d_in[17];
    const float* lnf_b  = (const float*)d_in[18];
    const float* Wlm    = (const float*)d_in[19];
    const float* blm    = (const float*)d_in[20];

    float* out = (float*)d_out;

    // ---- workspace carve ----
    char* w = (char*)d_ws;
    float* x = (float*)w;                             w += (size_t)MROWS * EE * 4;
    __hip_bfloat16* hbf = (__hip_bfloat16*)w;         w += (size_t)MROWS * EE * 2;
    __hip_bfloat16* qkv = (__hip_bfloat16*)w;         w += (size_t)MROWS * QS * 2;
    __hip_bfloat16* obf = (__hip_bfloat16*)w;         w += (size_t)MROWS * EE * 2;
    __hip_bfloat16* ff1 = (__hip_bfloat16*)w;         w += (size_t)MROWS * FFD * 2;
    float2* partials = (float2*)ff1;                  // aliases ff1: dead by LM-head time
    __hip_bfloat16* wlmT = (__hip_bfloat16*)w;        w += (size_t)VV * EE * 2;
    float* rowloss = (float*)w;                       w += (size_t)MROWS * 4 + 256;
    __hip_bfloat16* wbase = (__hip_bfloat16*)w;       // layer weights from here

    const size_t base_used = (size_t)(w - (char*)d_ws);
    const size_t per_layer_w = ((size_t)QS * EE + (size_t)EE * EE +
                                (size_t)FFD * EE + (size_t)EE * FFD) * 2;
    const bool hoist = ws_size >= base_used + per_layer_w * LAYERS;
    const int nlw = hoist ? LAYERS : 1;

    __hip_bfloat16* qkvwT = wbase;
    __hip_bfloat16* wpT   = qkvwT + (size_t)nlw * QS * EE;
    __hip_bfloat16* w1T   = wpT   + (size_t)nlw * EE * EE;
    __hip_bfloat16* w2T   = w1T   + (size_t)nlw * FFD * EE;

    dim3 blk(256);

    embed_k<<<MROWS, blk, 0, stream>>>(idx, tok, pos, x);

    if (hoist) {
        tconv_b_k<<<dim3(EE / 32, EE / 32, LAYERS), blk, 0, stream>>>(
            Wq, qkvwT, EE, EE, (size_t)EE * EE, (size_t)QS * EE);
        tconv_b_k<<<dim3(EE / 32, EE / 32, LAYERS), blk, 0, stream>>>(
            Wk, qkvwT + (size_t)EE * EE, EE, EE, (size_t)EE * EE, (size_t)QS * EE);
        tconv_b_k<<<dim3(EE / 32, EE / 32, LAYERS), blk, 0, stream>>>(
            Wv, qkvwT + (size_t)2 * EE * EE, EE, EE, (size_t)EE * EE, (size_t)QS * EE);
        tconv_b_k<<<dim3(EE / 32, EE / 32, LAYERS), blk, 0, stream>>>(
            Wp, wpT, EE, EE, (size_t)EE * EE, (size_t)EE * EE);
        tconv_b_k<<<dim3(FFD / 32, EE / 32, LAYERS), blk, 0, stream>>>(
            W1, w1T, EE, FFD, (size_t)EE * FFD, (size_t)FFD * EE);
        tconv_b_k<<<dim3(EE / 32, FFD / 32, LAYERS), blk, 0, stream>>>(
            W2, w2T, FFD, EE, (size_t)FFD * EE, (size_t)EE * FFD);
    }
    tconv_b_k<<<dim3(VV / 32, EE / 32, 1), blk, 0, stream>>>(Wlm, wlmT, EE, VV, 0, 0);

    for (int l = 0; l < LAYERS; ++l) {
        __hip_bfloat16* qkvwT_l = qkvwT + (hoist ? (size_t)l * QS * EE : 0);
        __hip_bfloat16* wpT_l   = wpT   + (hoist ? (size_t)l * EE * EE : 0);
        __hip_bfloat16* w1T_l   = w1T   + (hoist ? (size_t)l * FFD * EE : 0);
        __hip_bfloat16* w2T_l   = w2T   + (hoist ? (size_t)l * EE * FFD : 0);
        if (!hoist) {
            tconv_b_k<<<dim3(EE / 32, EE / 32, 1), blk, 0, stream>>>(
                Wq + (size_t)l * EE * EE, qkvwT_l, EE, EE, 0, 0);
            tconv_b_k<<<dim3(EE / 32, EE / 32, 1), blk, 0, stream>>>(
                Wk + (size_t)l * EE * EE, qkvwT_l + (size_t)EE * EE, EE, EE, 0, 0);
            tconv_b_k<<<dim3(EE / 32, EE / 32, 1), blk, 0, stream>>>(
                Wv + (size_t)l * EE * EE, qkvwT_l + (size_t)2 * EE * EE, EE, EE, 0, 0);
            tconv_b_k<<<dim3(EE / 32, EE / 32, 1), blk, 0, stream>>>(
                Wp + (size_t)l * EE * EE, wpT_l, EE, EE, 0, 0);
            tconv_b_k<<<dim3(FFD / 32, EE / 32, 1), blk, 0, stream>>>(
                W1 + (size_t)l * EE * FFD, w1T_l, EE, FFD, 0, 0);
            tconv_b_k<<<dim3(EE / 32, FFD / 32, 1), blk, 0, stream>>>(
                W2 + (size_t)l * FFD * EE, w2T_l, FFD, EE, 0, 0);
        }

        ln_k<<<MROWS, blk, 0, stream>>>(x, ln1_g + l * EE, ln1_b + l * EE, hbf);
        mgemm_k<false, false, false, true><<<dim3((MROWS / 128) * (QS / 128)), blk, 0, stream>>>(
            hbf, qkvwT_l, nullptr, qkv, MROWS, QS, EE, QS / 128);
        fattn_k<<<dim3(BB * HH, TT / QBLK), blk, 0, stream>>>(qkv, obf);
        mgemm_k<true, false, true, false><<<dim3((MROWS / 128) * (EE / 128)), blk, 0, stream>>>(
            obf, wpT_l, bp + l * EE, x, MROWS, EE, EE, EE / 128);
        ln_k<<<MROWS, blk, 0, stream>>>(x, ln2_g + l * EE, ln2_b + l * EE, hbf);
        mgemm_k<true, true, false, true><<<dim3((MROWS / 128) * (FFD / 128)), blk, 0, stream>>>(
            hbf, w1T_l, b1 + l * FFD, ff1, MROWS, FFD, EE, FFD / 128);
        mgemm_k<true, false, true, false><<<dim3((MROWS / 128) * (EE / 128)), blk, 0, stream>>>(
            ff1, w2T_l, b2 + l * EE, x, MROWS, EE, FFD, EE / 128);
    }

    ln_k<<<MROWS, blk, 0, stream>>>(x, lnf_g, lnf_b, hbf);
    // LM head: 256x256 8-phase kernel + fused LSE partials
    mgemm256_k<true, false, false, true><<<dim3((MROWS / 256) * (VV / 256)), dim3(512), 0, stream>>>(
        hbf, wlmT, blm, out, MROWS, VV, EE, VV / 256, NPART, partials);

    rowloss2_k<<<MROWS, blk, 0, stream>>>(partials, out, targets, rowloss, NPART);
    loss_final_k<<<1, blk, 0, stream>>>(rowloss, out + (size_t)MROWS * VV);
}

// Round 6
// 1849.848 us; speedup vs baseline: 8.4378x; 1.0517x over previous
//
#include <hip/hip_runtime.h>
#include <hip/hip_bf16.h>
#include <math.h>

#define LAYERS 6
#define BB 4
#define TT 1024
#define EE 768
#define HH 12
#define HS 64
#define VV 32000
#define FFD 3072
#define MROWS (BB * TT)   // 4096
#define QS (3 * EE)       // 2304, fused qkv row stride
#define KVB 64
#define QBLK 128
#define NPART (VV / 256)  // 125 LSE partial blocks per row

typedef __attribute__((ext_vector_type(8))) short bf16x8_t;
typedef __attribute__((ext_vector_type(4))) float f32x4_t;

// ---------------- helpers ----------------
__device__ __forceinline__ float wave_sum(float v) {
#pragma unroll
    for (int o = 32; o > 0; o >>= 1) v += __shfl_xor(v, o);
    return v;
}
__device__ __forceinline__ float wave_max(float v) {
#pragma unroll
    for (int o = 32; o > 0; o >>= 1) v = fmaxf(v, __shfl_xor(v, o));
    return v;
}
__device__ __forceinline__ float block_sum256(float v, float* red) {
    v = wave_sum(v);
    int tid = threadIdx.x;
    if ((tid & 63) == 0) red[tid >> 6] = v;
    __syncthreads();
    float r = red[0] + red[1] + red[2] + red[3];
    __syncthreads();
    return r;
}
__device__ __forceinline__ float block_max256(float v, float* red) {
    v = wave_max(v);
    int tid = threadIdx.x;
    if ((tid & 63) == 0) red[tid >> 6] = v;
    __syncthreads();
    float r = fmaxf(fmaxf(red[0], red[1]), fmaxf(red[2], red[3]));
    __syncthreads();
    return r;
}

__device__ __forceinline__ void gload_lds16(const void* g, void* l) {
    __builtin_amdgcn_global_load_lds((const __attribute__((address_space(1))) void*)g,
                                     (__attribute__((address_space(3))) void*)l, 16, 0, 0);
}

// pack two f32 -> u32 of 2 bf16 (lo at low address)
__device__ __forceinline__ unsigned pk2bf(float lo, float hi) {
    __hip_bfloat162 h2 = __float22bfloat162_rn(make_float2(lo, hi));
    return *reinterpret_cast<unsigned*>(&h2);
}

// ---------------- embedding ----------------
__global__ __launch_bounds__(256) void embed_k(const int* __restrict__ idx,
                                               const float* __restrict__ tok,
                                               const float* __restrict__ pos,
                                               float* __restrict__ x) {
    int row = blockIdx.x;
    int t = row & (TT - 1);
    int token = idx[row];
    const float* te = tok + (size_t)token * EE;
    const float* pe = pos + (size_t)t * EE;
    float* xr = x + (size_t)row * EE;
    for (int i = threadIdx.x; i < EE; i += 256) xr[i] = te[i] + pe[i];
}

// ---------------- LayerNorm: fp32 in -> bf16 out ----------------
__global__ __launch_bounds__(256) void ln_k(const float* __restrict__ x,
                                            const float* __restrict__ g,
                                            const float* __restrict__ b,
                                            __hip_bfloat16* __restrict__ out) {
    __shared__ float sr[EE];
    __shared__ float red[4];
    int row = blockIdx.x;
    const float* xr = x + (size_t)row * EE;
    int tid = threadIdx.x;
    float s = 0.f;
    for (int i = tid; i < EE; i += 256) { float v = xr[i]; sr[i] = v; s += v; }
    s = block_sum256(s, red);
    float m = s * (1.0f / EE);
    float vs = 0.f;
    for (int i = tid; i < EE; i += 256) { float d = sr[i] - m; vs += d * d; }
    vs = block_sum256(vs, red);
    float rstd = rsqrtf(vs * (1.0f / EE) + 1e-5f);
    __hip_bfloat16* orow = out + (size_t)row * EE;
    for (int i = tid; i < EE; i += 256)
        orow[i] = __float2bfloat16((sr[i] - m) * rstd * g[i] + b[i]);
}

// ---------------- batched transpose-convert: W fp32 [R,C] -> WT bf16 [C,R] ------
__global__ __launch_bounds__(256) void tconv_b_k(const float* __restrict__ W,
                                                 __hip_bfloat16* __restrict__ WT,
                                                 int R, int C,
                                                 size_t wstride, size_t tstride) {
    __shared__ float t[32][33];
    const float* Wl = W + (size_t)blockIdx.z * wstride;
    __hip_bfloat16* Tl = WT + (size_t)blockIdx.z * tstride;
    int c0 = blockIdx.x * 32, r0 = blockIdx.y * 32;
    int tx = threadIdx.x & 31, ty = threadIdx.x >> 5;
#pragma unroll
    for (int i = 0; i < 4; ++i)
        t[ty + 8 * i][tx] = Wl[(size_t)(r0 + ty + 8 * i) * C + c0 + tx];
    __syncthreads();
#pragma unroll
    for (int i = 0; i < 4; ++i)
        Tl[(size_t)(c0 + ty + 8 * i) * R + r0 + tx] = __float2bfloat16(t[tx][ty + 8 * i]);
}

// ---------------- MFMA GEMM (m97 structure, 128x128, BK=32) ----------------
template <bool BIAS, bool RELU, bool ACCUM, bool OBF16>
__global__ __launch_bounds__(256) void mgemm_k(const __hip_bfloat16* __restrict__ A,
                                               const __hip_bfloat16* __restrict__ BT,
                                               const float* __restrict__ bias,
                                               void* __restrict__ Cv,
                                               int M, int N, int K, int ntn) {
    __shared__ __align__(16) short As[128 * 32];
    __shared__ __align__(16) short Bs[128 * 32];

    int nwg = gridDim.x;
    int bid = blockIdx.x;
    int cpx = nwg >> 3;
    int swz = (bid & 7) * cpx + (bid >> 3);
    int tm = swz / ntn, tn = swz - tm * ntn;
    int m0 = tm * 128, n0 = tn * 128;

    int tid = threadIdx.x;
    int lane = tid & 63;
    int wave = tid >> 6;
    int wr = wave >> 1, wc = wave & 1;

    f32x4_t acc[4][4];
#pragma unroll
    for (int i = 0; i < 4; ++i)
#pragma unroll
        for (int j = 0; j < 4; ++j)
#pragma unroll
            for (int r = 0; r < 4; ++r) acc[i][j][r] = 0.f;

    const short* Ag = (const short*)A;
    const short* Bg = (const short*)BT;
    const int arow0 = tid >> 2;
    const int arow1 = (tid + 256) >> 2;
    const int acol = (tid & 3) * 8;

    const int fr = lane & 15;
    const int kg = (lane >> 4) * 8;

    for (int k0 = 0; k0 < K; k0 += 32) {
        gload_lds16(Ag + (size_t)(m0 + arow0) * K + k0 + acol, &As[tid * 8]);
        gload_lds16(Ag + (size_t)(m0 + arow1) * K + k0 + acol, &As[(tid + 256) * 8]);
        gload_lds16(Bg + (size_t)(n0 + arow0) * K + k0 + acol, &Bs[tid * 8]);
        gload_lds16(Bg + (size_t)(n0 + arow1) * K + k0 + acol, &Bs[(tid + 256) * 8]);
        __syncthreads();

        bf16x8_t af[4], bq[4];
#pragma unroll
        for (int mi = 0; mi < 4; ++mi)
            af[mi] = *(const bf16x8_t*)&As[(wr * 64 + mi * 16 + fr) * 32 + kg];
#pragma unroll
        for (int ni = 0; ni < 4; ++ni)
            bq[ni] = *(const bf16x8_t*)&Bs[(wc * 64 + ni * 16 + fr) * 32 + kg];
#pragma unroll
        for (int mi = 0; mi < 4; ++mi)
#pragma unroll
            for (int ni = 0; ni < 4; ++ni)
                acc[mi][ni] = __builtin_amdgcn_mfma_f32_16x16x32_bf16(af[mi], bq[ni], acc[mi][ni], 0, 0, 0);
        __syncthreads();
    }

    float bvec[4];
    if (BIAS) {
#pragma unroll
        for (int ni = 0; ni < 4; ++ni) bvec[ni] = bias[n0 + wc * 64 + ni * 16 + fr];
    }
    const int rbase = m0 + wr * 64 + (lane >> 4) * 4;
    const int cbase = n0 + wc * 64 + fr;
#pragma unroll
    for (int mi = 0; mi < 4; ++mi) {
#pragma unroll
        for (int ni = 0; ni < 4; ++ni) {
#pragma unroll
            for (int r = 0; r < 4; ++r) {
                int row = rbase + mi * 16 + r;
                int col = cbase + ni * 16;
                float v = acc[mi][ni][r];
                if (BIAS) v += bvec[ni];
                if (RELU) v = fmaxf(v, 0.f);
                size_t off = (size_t)row * N + col;
                if (OBF16) {
                    ((__hip_bfloat16*)Cv)[off] = __float2bfloat16(v);
                } else {
                    float* Cf = (float*)Cv;
                    if (ACCUM) Cf[off] += v; else Cf[off] = v;
                }
            }
        }
    }
}

// ---------------- 256x256 8-phase MFMA GEMM (unchanged from r5) ----------------
__device__ __forceinline__ bf16x8_t ldsrd256(const short* base, int row, int colb) {
    return *(const bf16x8_t*)((const char*)base + ((row << 7) + (colb ^ ((row & 7) << 4))));
}

template <bool BIAS, bool RELU, bool OBF16, bool LSE>
__global__ __launch_bounds__(512, 2) void mgemm256_k(const __hip_bfloat16* __restrict__ A,
                                                     const __hip_bfloat16* __restrict__ BT,
                                                     const float* __restrict__ bias,
                                                     void* __restrict__ Cv,
                                                     int M, int N, int K,
                                                     int ntn, int npart,
                                                     float2* __restrict__ partials) {
    __shared__ __align__(16) short lds[2][2][2][8192];   // [buf][A/B][half][128*64]

    const int nwg = gridDim.x;
    const int bid = blockIdx.x;
    const int cpx = nwg >> 3;
    const int swz = (bid & 7) * cpx + (bid >> 3);
    const int tm = swz / ntn, tn = swz - tm * ntn;
    const int m0 = tm * 256, n0 = tn * 256;

    const int tid = threadIdx.x;
    const int lane = tid & 63;
    const int wave = tid >> 6;
    const int wm = wave >> 2;       // 0..1
    const int wn = wave & 3;        // 0..3
    const int fr = lane & 15;
    const int hi4 = lane >> 4;

    const short* Ag = (const short*)A;
    const short* Bg = (const short*)BT;
    const int nt = K >> 6;          // 12

    auto stage_half = [&](const short* g, int grow0, int k0, short* lbase) {
#pragma unroll
        for (int sub = 0; sub < 2; ++sub) {
            int d = sub * 8192 + tid * 16;
            int row = d >> 7;
            int cb = d & 127;
            int col = (cb ^ ((row & 7) << 4)) >> 1;
            gload_lds16(g + (size_t)(grow0 + row) * K + k0 + col, (char*)lbase + d);
        }
    };

    f32x4_t acc[2][2][4][2];
#pragma unroll
    for (int ah = 0; ah < 2; ++ah)
#pragma unroll
        for (int s = 0; s < 2; ++s)
#pragma unroll
            for (int mi = 0; mi < 4; ++mi)
#pragma unroll
                for (int ni = 0; ni < 2; ++ni)
#pragma unroll
                    for (int r = 0; r < 4; ++r) acc[ah][s][mi][ni][r] = 0.f;

    stage_half(Ag, m0 + 0,   0,  &lds[0][0][0][0]);
    stage_half(Bg, n0 + 0,   0,  &lds[0][1][0][0]);
    stage_half(Ag, m0 + 128, 0,  &lds[0][0][1][0]);
    stage_half(Bg, n0 + 128, 0,  &lds[0][1][1][0]);
    stage_half(Ag, m0 + 0,   64, &lds[1][0][0][0]);
    stage_half(Bg, n0 + 0,   64, &lds[1][1][0][0]);
    asm volatile("s_waitcnt vmcnt(4)" ::: "memory");
    __builtin_amdgcn_s_barrier();

    for (int t = 0; t < nt; ++t) {
        const int c = t & 1, o = c ^ 1;
        bf16x8_t a[4][2];
#pragma unroll
        for (int p = 0; p < 4; ++p) {
            const int ah = p >> 1, s = p & 1;
            if (s == 0) {
#pragma unroll
                for (int mi = 0; mi < 4; ++mi)
#pragma unroll
                    for (int kk = 0; kk < 2; ++kk)
                        a[mi][kk] = ldsrd256(&lds[c][0][ah][0],
                                             wm * 64 + mi * 16 + fr, kk * 64 + hi4 * 16);
            }
            bf16x8_t b[2][2];
#pragma unroll
            for (int ni = 0; ni < 2; ++ni)
#pragma unroll
                for (int kk = 0; kk < 2; ++kk)
                    b[ni][kk] = ldsrd256(&lds[c][1][s][0],
                                         wn * 32 + ni * 16 + fr, kk * 64 + hi4 * 16);
            if (p == 0 && t + 1 < nt) stage_half(Ag, m0 + 128, (t + 1) * 64, &lds[o][0][1][0]);
            if (p == 1 && t + 1 < nt) stage_half(Bg, n0 + 128, (t + 1) * 64, &lds[o][1][1][0]);
            if (p == 2 && t + 2 < nt) stage_half(Ag, m0 + 0,   (t + 2) * 64, &lds[c][0][0][0]);
            if (p == 3 && t + 2 < nt) stage_half(Bg, n0 + 0,   (t + 2) * 64, &lds[c][1][0][0]);
            if (p == 3) {
                if (t < nt - 2)       asm volatile("s_waitcnt vmcnt(4)" ::: "memory");
                else if (t == nt - 2) asm volatile("s_waitcnt vmcnt(0)" ::: "memory");
            }
            __builtin_amdgcn_s_barrier();
            asm volatile("s_waitcnt lgkmcnt(0)" ::: "memory");
            __builtin_amdgcn_sched_barrier(0);
            __builtin_amdgcn_s_setprio(1);
#pragma unroll
            for (int mi = 0; mi < 4; ++mi)
#pragma unroll
                for (int ni = 0; ni < 2; ++ni)
#pragma unroll
                    for (int kk = 0; kk < 2; ++kk)
                        acc[ah][s][mi][ni] = __builtin_amdgcn_mfma_f32_16x16x32_bf16(
                            a[mi][kk], b[ni][kk], acc[ah][s][mi][ni], 0, 0, 0);
            __builtin_amdgcn_s_setprio(0);
            __builtin_amdgcn_s_barrier();
        }
    }

    float bv[2][2];
    if (BIAS) {
#pragma unroll
        for (int s = 0; s < 2; ++s)
#pragma unroll
            for (int ni = 0; ni < 2; ++ni)
                bv[s][ni] = bias[n0 + s * 128 + wn * 32 + ni * 16 + fr];
    }
    float2* red = (float2*)&lds[0][0][0][0];
#pragma unroll
    for (int ah = 0; ah < 2; ++ah) {
#pragma unroll
        for (int mi = 0; mi < 4; ++mi) {
#pragma unroll
            for (int r = 0; r < 4; ++r) {
                const int rb = ah * 128 + wm * 64 + mi * 16 + hi4 * 4 + r;
                const size_t grow = (size_t)(m0 + rb);
                float v[2][2];
#pragma unroll
                for (int s = 0; s < 2; ++s)
#pragma unroll
                    for (int ni = 0; ni < 2; ++ni) {
                        float vv = acc[ah][s][mi][ni][r];
                        if (BIAS) vv += bv[s][ni];
                        if (RELU) vv = fmaxf(vv, 0.f);
                        v[s][ni] = vv;
                        size_t off = grow * N + n0 + s * 128 + wn * 32 + ni * 16 + fr;
                        if (OBF16) ((__hip_bfloat16*)Cv)[off] = __float2bfloat16(vv);
                        else       ((float*)Cv)[off] = vv;
                    }
                if (LSE) {
                    float mx = fmaxf(fmaxf(v[0][0], v[0][1]), fmaxf(v[1][0], v[1][1]));
#pragma unroll
                    for (int off2 = 1; off2 < 16; off2 <<= 1) mx = fmaxf(mx, __shfl_xor(mx, off2));
                    float sm = 0.f;
#pragma unroll
                    for (int s = 0; s < 2; ++s)
#pragma unroll
                        for (int ni = 0; ni < 2; ++ni) sm += __expf(v[s][ni] - mx);
#pragma unroll
                    for (int off2 = 1; off2 < 16; off2 <<= 1) sm += __shfl_xor(sm, off2);
                    if (fr == 0) red[rb * 4 + wn] = make_float2(mx, sm);
                }
            }
        }
    }
    if (LSE) {
        __syncthreads();
        if (tid < 256) {
            float2 p0 = red[tid * 4 + 0], p1 = red[tid * 4 + 1];
            float2 p2 = red[tid * 4 + 2], p3 = red[tid * 4 + 3];
            float M2 = fmaxf(fmaxf(p0.x, p1.x), fmaxf(p2.x, p3.x));
            float L2 = p0.y * __expf(p0.x - M2) + p1.y * __expf(p1.x - M2) +
                       p2.y * __expf(p2.x - M2) + p3.y * __expf(p3.x - M2);
            partials[(size_t)(m0 + tid) * npart + tn] = make_float2(M2, L2);
        }
    }
}

// ---------------- MFMA flash attention v2: swapped QK^T, in-lane softmax -------
// S^T = mfma(K, Q): lane (fr,hi4) holds S[q = wq0+mi*16+fr][key = kv0+ni*16+hi4*4+r]
// -> whole q-row lives in the 4-lane group {fr, fr+16, fr+32, fr+48}.
__global__ __launch_bounds__(256) void fattn_k(const __hip_bfloat16* __restrict__ qkv,
                                               __hip_bfloat16* __restrict__ o) {
    __shared__ short Ks[KVB * HS];
    __shared__ short Vt[HS * KVB];
    __shared__ short Pl[4 * 32 * KVB];

    const int bh = blockIdx.x;
    const int hh = bh % HH;
    const int bI = bh / HH;
    const int qt = (TT / QBLK - 1) - blockIdx.y;   // heavy tiles first
    const int q0 = qt * QBLK;

    const int tid = threadIdx.x;
    const int lane = tid & 63;
    const int wave = tid >> 6;
    const int fr = lane & 15;
    const int hi4 = lane >> 4;

    const size_t rowbase = (size_t)bI * TT;
    const int wq0 = q0 + wave * 32;

    // Q fragments, pre-scaled by 1/8 (exact exponent shift in bf16)
    bf16x8_t qf[2][2];
#pragma unroll
    for (int mi = 0; mi < 2; ++mi)
#pragma unroll
        for (int kc = 0; kc < 2; ++kc) {
            const short* src = (const short*)qkv +
                (rowbase + wq0 + mi * 16 + fr) * QS + hh * HS + kc * 32 + hi4 * 8;
            bf16x8_t v = *(const bf16x8_t*)src;
#pragma unroll
            for (int e = 0; e < 8; ++e) {
                float f = __uint_as_float(((unsigned)(unsigned short)v[e]) << 16) * 0.125f;
                v[e] = (short)(__float_as_uint(f) >> 16);
            }
            qf[mi][kc] = v;
        }

    f32x4_t oa[2][4];
    float m_r[2], l_r[2];
#pragma unroll
    for (int mi = 0; mi < 2; ++mi) {
        m_r[mi] = -INFINITY;
        l_r[mi] = 0.f;
#pragma unroll
        for (int nd = 0; nd < 4; ++nd)
#pragma unroll
            for (int r = 0; r < 4; ++r) oa[mi][nd][r] = 0.f;
    }

    const int skey = tid >> 2;
    const int sd0 = (tid & 3) * 16;
    const int niter = 2 * (qt + 1);

    for (int it = 0; it < niter; ++it) {
        const int kv0 = it * KVB;
        __syncthreads();
        // ---- stage K and V^T ----
        {
            const short* kg = (const short*)qkv + (rowbase + kv0 + skey) * QS + EE + hh * HS + sd0;
            uint4 ka = *(const uint4*)kg;
            uint4 kb2 = *(const uint4*)(kg + 8);
            const int rs = (skey & 7) << 4;
            char* kbp = (char*)Ks;
            *(uint4*)(kbp + ((skey * 128 + sd0 * 2) ^ rs)) = ka;
            *(uint4*)(kbp + ((skey * 128 + sd0 * 2 + 16) ^ rs)) = kb2;

            const short* vg = (const short*)qkv + (rowbase + kv0 + skey) * QS + 2 * EE + hh * HS + sd0;
            uint4 va = *(const uint4*)vg;
            uint4 vb2 = *(const uint4*)(vg + 8);
            char* vbp = (char*)Vt;
            const short* vs0 = (const short*)&va;
#pragma unroll
            for (int e = 0; e < 8; ++e) {
                int dd = sd0 + e;
                *(short*)(vbp + ((dd * 128 + skey * 2) ^ ((dd & 7) << 4))) = vs0[e];
            }
            const short* vs1 = (const short*)&vb2;
#pragma unroll
            for (int e = 0; e < 8; ++e) {
                int dd = sd0 + 8 + e;
                *(short*)(vbp + ((dd * 128 + skey * 2) ^ ((dd & 7) << 4))) = vs1[e];
            }
        }
        __syncthreads();

        // ---- S^T = K Q^T (operand-swapped) ----
        f32x4_t sa[2][4];
#pragma unroll
        for (int mi = 0; mi < 2; ++mi)
#pragma unroll
            for (int ni = 0; ni < 4; ++ni)
#pragma unroll
                for (int r = 0; r < 4; ++r) sa[mi][ni][r] = 0.f;
#pragma unroll
        for (int kc = 0; kc < 2; ++kc) {
            bf16x8_t kf[4];
#pragma unroll
            for (int ni = 0; ni < 4; ++ni) {
                int krow = ni * 16 + fr;
                kf[ni] = *(const bf16x8_t*)((char*)Ks +
                    ((krow * 128 + (kc * 32 + hi4 * 8) * 2) ^ ((krow & 7) << 4)));
            }
#pragma unroll
            for (int mi = 0; mi < 2; ++mi)
#pragma unroll
                for (int ni = 0; ni < 4; ++ni)
                    sa[mi][ni] = __builtin_amdgcn_mfma_f32_16x16x32_bf16(kf[ni], qf[mi][kc], sa[mi][ni], 0, 0, 0);
        }

        // ---- causal mask: key = kv0+ni*16+hi4*4+r, qrow = wq0+mi*16+fr ----
        if (kv0 + KVB - 1 > wq0) {
#pragma unroll
            for (int mi = 0; mi < 2; ++mi) {
                int qrow = wq0 + mi * 16 + fr;
#pragma unroll
                for (int ni = 0; ni < 4; ++ni)
#pragma unroll
                    for (int r = 0; r < 4; ++r) {
                        int key = kv0 + ni * 16 + hi4 * 4 + r;
                        if (key > qrow) sa[mi][ni][r] = -1e30f;
                    }
            }
        }

        // ---- online softmax (in-lane 16 values + 2 shfl across hi4 groups) ----
        char* Pw = (char*)Pl + wave * 4096;
#pragma unroll
        for (int mi = 0; mi < 2; ++mi) {
            float mx = sa[mi][0][0];
#pragma unroll
            for (int ni = 0; ni < 4; ++ni)
#pragma unroll
                for (int r = 0; r < 4; ++r) mx = fmaxf(mx, sa[mi][ni][r]);
            mx = fmaxf(mx, __shfl_xor(mx, 16));
            mx = fmaxf(mx, __shfl_xor(mx, 32));
            float mnew = fmaxf(m_r[mi], mx);
            float al = __expf(m_r[mi] - mnew);
            m_r[mi] = mnew;
            float ps = 0.f;
#pragma unroll
            for (int ni = 0; ni < 4; ++ni) {
#pragma unroll
                for (int r = 0; r < 4; ++r) {
                    float p = __expf(sa[mi][ni][r] - mnew);
                    sa[mi][ni][r] = p;
                    ps += p;
                }
                // packed P write: 4 consecutive keys (r=0..3) -> one b64
                uint2 pw;
                pw.x = pk2bf(sa[mi][ni][0], sa[mi][ni][1]);
                pw.y = pk2bf(sa[mi][ni][2], sa[mi][ni][3]);
                int prow = mi * 16 + fr;
                int cb = ni * 32 + hi4 * 8;   // bytes
                *(uint2*)(Pw + ((prow * 128 + cb) ^ ((prow & 7) << 4))) = pw;
            }
            ps += __shfl_xor(ps, 16);
            ps += __shfl_xor(ps, 32);
            l_r[mi] = l_r[mi] * al + ps;
            // O-rescale: alpha for O row (hi4*4+r) lives in lane (hi4*4+r)
#pragma unroll
            for (int r = 0; r < 4; ++r) {
                float a_r = __shfl(al, hi4 * 4 + r);
#pragma unroll
                for (int nd = 0; nd < 4; ++nd) oa[mi][nd][r] *= a_r;
            }
        }

        // ---- O += P V ----
#pragma unroll
        for (int kc = 0; kc < 2; ++kc) {
            bf16x8_t pf[2], vf[4];
#pragma unroll
            for (int mi = 0; mi < 2; ++mi) {
                int prow = mi * 16 + fr;
                pf[mi] = *(const bf16x8_t*)(Pw +
                    ((prow * 128 + (kc * 32 + hi4 * 8) * 2) ^ ((prow & 7) << 4)));
            }
#pragma unroll
            for (int nd = 0; nd < 4; ++nd) {
                int vrow = nd * 16 + fr;
                vf[nd] = *(const bf16x8_t*)((char*)Vt +
                    ((vrow * 128 + (kc * 32 + hi4 * 8) * 2) ^ ((vrow & 7) << 4)));
            }
#pragma unroll
            for (int mi = 0; mi < 2; ++mi)
#pragma unroll
                for (int nd = 0; nd < 4; ++nd)
                    oa[mi][nd] = __builtin_amdgcn_mfma_f32_16x16x32_bf16(pf[mi], vf[nd], oa[mi][nd], 0, 0, 0);
        }
    }

    // ---- epilogue: O / l -> global (l for row hi4*4+r via shfl) ----
#pragma unroll
    for (int mi = 0; mi < 2; ++mi)
#pragma unroll
        for (int r = 0; r < 4; ++r) {
            float lr = __shfl(l_r[mi], hi4 * 4 + r);
            float inv = 1.0f / lr;
            int row = wq0 + mi * 16 + hi4 * 4 + r;
            __hip_bfloat16* orow = o + (rowbase + row) * EE + hh * HS;
#pragma unroll
            for (int nd = 0; nd < 4; ++nd)
                orow[nd * 16 + fr] = __float2bfloat16(oa[mi][nd][r] * inv);
        }
}

// ---------------- loss: merge per-block LSE partials ----------------
__global__ __launch_bounds__(256) void rowloss2_k(const float2* __restrict__ partials,
                                                  const float* __restrict__ logits,
                                                  const int* __restrict__ targets,
                                                  float* __restrict__ rowloss, int ntn) {
    __shared__ float red[4];
    int row = blockIdx.x;
    int tid = threadIdx.x;
    float m = -INFINITY, l = 0.f;
    if (tid < ntn) {
        float2 p = partials[(size_t)row * ntn + tid];
        m = p.x; l = p.y;
    }
    float mg = block_max256(m, red);
    float s = (tid < ntn) ? l * __expf(m - mg) : 0.f;
    s = block_sum256(s, red);
    if (tid == 0)
        rowloss[row] = mg + logf(s) - logits[(size_t)row * VV + targets[row]];
}

__global__ __launch_bounds__(256) void loss_final_k(const float* __restrict__ rowloss,
                                                    float* __restrict__ out) {
    __shared__ float red[4];
    float s = 0.f;
    for (int i = threadIdx.x; i < MROWS; i += 256) s += rowloss[i];
    s = block_sum256(s, red);
    if (threadIdx.x == 0) out[0] = s * (1.0f / MROWS);
}

// ---------------- launcher ----------------
extern "C" void kernel_launch(void* const* d_in, const int* in_sizes, int n_in,
                              void* d_out, int out_size, void* d_ws, size_t ws_size,
                              hipStream_t stream) {
    const int* idx      = (const int*)d_in[0];
    const int* targets  = (const int*)d_in[1];
    const float* tok    = (const float*)d_in[2];
    const float* pos    = (const float*)d_in[3];
    const float* Wq     = (const float*)d_in[4];
    const float* Wk     = (const float*)d_in[5];
    const float* Wv     = (const float*)d_in[6];
    const float* Wp     = (const float*)d_in[7];
    const float* bp     = (const float*)d_in[8];
    const float* W1     = (const float*)d_in[9];
    const float* b1     = (const float*)d_in[10];
    const float* W2     = (const float*)d_in[11];
    const float* b2     = (const float*)d_in[12];
    const float* ln1_g  = (const float*)d_in[13];
    const float* ln1_b  = (const float*)d_in[14];
    const float* ln2_g  = (const float*)d_in[15];
    const float* ln2_b  = (const float*)d_in[16];
    const float* lnf_g  = (const float*)d_in[17];
    const float* lnf_b  = (const float*)d_in[18];
    const float* Wlm    = (const float*)d_in[19];
    const float* blm    = (const float*)d_in[20];

    float* out = (float*)d_out;

    // ---- workspace carve ----
    char* w = (char*)d_ws;
    float* x = (float*)w;                             w += (size_t)MROWS * EE * 4;
    __hip_bfloat16* hbf = (__hip_bfloat16*)w;         w += (size_t)MROWS * EE * 2;
    __hip_bfloat16* qkv = (__hip_bfloat16*)w;         w += (size_t)MROWS * QS * 2;
    __hip_bfloat16* obf = (__hip_bfloat16*)w;         w += (size_t)MROWS * EE * 2;
    __hip_bfloat16* ff1 = (__hip_bfloat16*)w;         w += (size_t)MROWS * FFD * 2;
    float2* partials = (float2*)ff1;                  // aliases ff1: dead by LM-head time
    __hip_bfloat16* wlmT = (__hip_bfloat16*)w;        w += (size_t)VV * EE * 2;
    float* rowloss = (float*)w;                       w += (size_t)MROWS * 4 + 256;
    __hip_bfloat16* wbase = (__hip_bfloat16*)w;       // layer weights from here

    const size_t base_used = (size_t)(w - (char*)d_ws);
    const size_t per_layer_w = ((size_t)QS * EE + (size_t)EE * EE +
                                (size_t)FFD * EE + (size_t)EE * FFD) * 2;
    const bool hoist = ws_size >= base_used + per_layer_w * LAYERS;
    const int nlw = hoist ? LAYERS : 1;

    __hip_bfloat16* qkvwT = wbase;
    __hip_bfloat16* wpT   = qkvwT + (size_t)nlw * QS * EE;
    __hip_bfloat16* w1T   = wpT   + (size_t)nlw * EE * EE;
    __hip_bfloat16* w2T   = w1T   + (size_t)nlw * FFD * EE;

    dim3 blk(256);

    embed_k<<<MROWS, blk, 0, stream>>>(idx, tok, pos, x);

    if (hoist) {
        tconv_b_k<<<dim3(EE / 32, EE / 32, LAYERS), blk, 0, stream>>>(
            Wq, qkvwT, EE, EE, (size_t)EE * EE, (size_t)QS * EE);
        tconv_b_k<<<dim3(EE / 32, EE / 32, LAYERS), blk, 0, stream>>>(
            Wk, qkvwT + (size_t)EE * EE, EE, EE, (size_t)EE * EE, (size_t)QS * EE);
        tconv_b_k<<<dim3(EE / 32, EE / 32, LAYERS), blk, 0, stream>>>(
            Wv, qkvwT + (size_t)2 * EE * EE, EE, EE, (size_t)EE * EE, (size_t)QS * EE);
        tconv_b_k<<<dim3(EE / 32, EE / 32, LAYERS), blk, 0, stream>>>(
            Wp, wpT, EE, EE, (size_t)EE * EE, (size_t)EE * EE);
        tconv_b_k<<<dim3(FFD / 32, EE / 32, LAYERS), blk, 0, stream>>>(
            W1, w1T, EE, FFD, (size_t)EE * FFD, (size_t)FFD * EE);
        tconv_b_k<<<dim3(EE / 32, FFD / 32, LAYERS), blk, 0, stream>>>(
            W2, w2T, FFD, EE, (size_t)FFD * EE, (size_t)EE * FFD);
    }
    tconv_b_k<<<dim3(VV / 32, EE / 32, 1), blk, 0, stream>>>(Wlm, wlmT, EE, VV, 0, 0);

    for (int l = 0; l < LAYERS; ++l) {
        __hip_bfloat16* qkvwT_l = qkvwT + (hoist ? (size_t)l * QS * EE : 0);
        __hip_bfloat16* wpT_l   = wpT   + (hoist ? (size_t)l * EE * EE : 0);
        __hip_bfloat16* w1T_l   = w1T   + (hoist ? (size_t)l * FFD * EE : 0);
        __hip_bfloat16* w2T_l   = w2T   + (hoist ? (size_t)l * EE * FFD : 0);
        if (!hoist) {
            tconv_b_k<<<dim3(EE / 32, EE / 32, 1), blk, 0, stream>>>(
                Wq + (size_t)l * EE * EE, qkvwT_l, EE, EE, 0, 0);
            tconv_b_k<<<dim3(EE / 32, EE / 32, 1), blk, 0, stream>>>(
                Wk + (size_t)l * EE * EE, qkvwT_l + (size_t)EE * EE, EE, EE, 0, 0);
            tconv_b_k<<<dim3(EE / 32, EE / 32, 1), blk, 0, stream>>>(
                Wv + (size_t)l * EE * EE, qkvwT_l + (size_t)2 * EE * EE, EE, EE, 0, 0);
            tconv_b_k<<<dim3(EE / 32, EE / 32, 1), blk, 0, stream>>>(
                Wp + (size_t)l * EE * EE, wpT_l, EE, EE, 0, 0);
            tconv_b_k<<<dim3(FFD / 32, EE / 32, 1), blk, 0, stream>>>(
                W1 + (size_t)l * EE * FFD, w1T_l, EE, FFD, 0, 0);
            tconv_b_k<<<dim3(EE / 32, FFD / 32, 1), blk, 0, stream>>>(
                W2 + (size_t)l * FFD * EE, w2T_l, FFD, EE, 0, 0);
        }

        ln_k<<<MROWS, blk, 0, stream>>>(x, ln1_g + l * EE, ln1_b + l * EE, hbf);
        mgemm_k<false, false, false, true><<<dim3((MROWS / 128) * (QS / 128)), blk, 0, stream>>>(
            hbf, qkvwT_l, nullptr, qkv, MROWS, QS, EE, QS / 128);
        fattn_k<<<dim3(BB * HH, TT / QBLK), blk, 0, stream>>>(qkv, obf);
        mgemm_k<true, false, true, false><<<dim3((MROWS / 128) * (EE / 128)), blk, 0, stream>>>(
            obf, wpT_l, bp + l * EE, x, MROWS, EE, EE, EE / 128);
        ln_k<<<MROWS, blk, 0, stream>>>(x, ln2_g + l * EE, ln2_b + l * EE, hbf);
        mgemm_k<true, true, false, true><<<dim3((MROWS / 128) * (FFD / 128)), blk, 0, stream>>>(
            hbf, w1T_l, b1 + l * FFD, ff1, MROWS, FFD, EE, FFD / 128);
        mgemm_k<true, false, true, false><<<dim3((MROWS / 128) * (EE / 128)), blk, 0, stream>>>(
            ff1, w2T_l, b2 + l * EE, x, MROWS, EE, FFD, EE / 128);
    }

    ln_k<<<MROWS, blk, 0, stream>>>(x, lnf_g, lnf_b, hbf);
    mgemm256_k<true, false, false, true><<<dim3((MROWS / 256) * (VV / 256)), dim3(512), 0, stream>>>(
        hbf, wlmT, blm, out, MROWS, VV, EE, VV / 256, NPART, partials);

    rowloss2_k<<<MROWS, blk, 0, stream>>>(partials, out, targets, rowloss, NPART);
    loss_final_k<<<1, blk, 0, stream>>>(rowloss, out + (size_t)MROWS * VV);
}

// Round 7
// 1823.399 us; speedup vs baseline: 8.5602x; 1.0145x over previous
//
#include <hip/hip_runtime.h>
#include <hip/hip_bf16.h>
#include <math.h>

#define LAYERS 6
#define BB 4
#define TT 1024
#define EE 768
#define HH 12
#define HS 64
#define VV 32000
#define FFD 3072
#define MROWS (BB * TT)   // 4096
#define QS (3 * EE)       // 2304, fused qkv row stride
#define KVB 64
#define QBLK 128
#define NPART (VV / 256)  // 125 LSE partial blocks per row

typedef __attribute__((ext_vector_type(8))) short bf16x8_t;
typedef __attribute__((ext_vector_type(4))) float f32x4_t;

// ---------------- helpers ----------------
__device__ __forceinline__ float wave_sum(float v) {
#pragma unroll
    for (int o = 32; o > 0; o >>= 1) v += __shfl_xor(v, o);
    return v;
}
__device__ __forceinline__ float wave_max(float v) {
#pragma unroll
    for (int o = 32; o > 0; o >>= 1) v = fmaxf(v, __shfl_xor(v, o));
    return v;
}
__device__ __forceinline__ float block_sum256(float v, float* red) {
    v = wave_sum(v);
    int tid = threadIdx.x;
    if ((tid & 63) == 0) red[tid >> 6] = v;
    __syncthreads();
    float r = red[0] + red[1] + red[2] + red[3];
    __syncthreads();
    return r;
}
__device__ __forceinline__ float block_max256(float v, float* red) {
    v = wave_max(v);
    int tid = threadIdx.x;
    if ((tid & 63) == 0) red[tid >> 6] = v;
    __syncthreads();
    float r = fmaxf(fmaxf(red[0], red[1]), fmaxf(red[2], red[3]));
    __syncthreads();
    return r;
}

__device__ __forceinline__ void gload_lds16(const void* g, void* l) {
    __builtin_amdgcn_global_load_lds((const __attribute__((address_space(1))) void*)g,
                                     (__attribute__((address_space(3))) void*)l, 16, 0, 0);
}

// pack two f32 -> u32 of 2 bf16 (lo at low address)
__device__ __forceinline__ unsigned pk2bf(float lo, float hi) {
    __hip_bfloat162 h2 = __float22bfloat162_rn(make_float2(lo, hi));
    return *reinterpret_cast<unsigned*>(&h2);
}

// ---------------- embedding: 4 rows/block, wave per row, float4 ----------------
__global__ __launch_bounds__(256) void embed4_k(const int* __restrict__ idx,
                                                const float* __restrict__ tok,
                                                const float* __restrict__ pos,
                                                float* __restrict__ x) {
    int row = blockIdx.x * 4 + (threadIdx.x >> 6);
    int lane = threadIdx.x & 63;
    int t = row & (TT - 1);
    int token = idx[row];
    const float4* te = (const float4*)(tok + (size_t)token * EE);
    const float4* pe = (const float4*)(pos + (size_t)t * EE);
    float4* xr = (float4*)(x + (size_t)row * EE);
#pragma unroll
    for (int j = 0; j < 3; ++j) {
        int i = j * 64 + lane;
        float4 a = te[i], b = pe[i];
        xr[i] = make_float4(a.x + b.x, a.y + b.y, a.z + b.z, a.w + b.w);
    }
}

// ---------------- LayerNorm: wave per row, register-resident, fp32->bf16 -------
__global__ __launch_bounds__(256) void ln4_k(const float* __restrict__ x,
                                             const float* __restrict__ g,
                                             const float* __restrict__ b,
                                             __hip_bfloat16* __restrict__ out) {
    int row = blockIdx.x * 4 + (threadIdx.x >> 6);
    int lane = threadIdx.x & 63;
    const float4* xr = (const float4*)(x + (size_t)row * EE);
    float4 v[3];
    float s = 0.f;
#pragma unroll
    for (int j = 0; j < 3; ++j) {
        v[j] = xr[j * 64 + lane];
        s += v[j].x + v[j].y + v[j].z + v[j].w;
    }
    s = wave_sum(s);
    float m = s * (1.0f / EE);
    float vs = 0.f;
#pragma unroll
    for (int j = 0; j < 3; ++j) {
        float d0 = v[j].x - m, d1 = v[j].y - m, d2 = v[j].z - m, d3 = v[j].w - m;
        vs += d0 * d0 + d1 * d1 + d2 * d2 + d3 * d3;
    }
    vs = wave_sum(vs);
    float rstd = rsqrtf(vs * (1.0f / EE) + 1e-5f);
    const float4* g4 = (const float4*)g;
    const float4* b4 = (const float4*)b;
    uint2* orow = (uint2*)(out + (size_t)row * EE);
#pragma unroll
    for (int j = 0; j < 3; ++j) {
        int i = j * 64 + lane;
        float4 gg = g4[i], bb = b4[i];
        float n0 = (v[j].x - m) * rstd * gg.x + bb.x;
        float n1 = (v[j].y - m) * rstd * gg.y + bb.y;
        float n2 = (v[j].z - m) * rstd * gg.z + bb.z;
        float n3 = (v[j].w - m) * rstd * gg.w + bb.w;
        orow[i] = make_uint2(pk2bf(n0, n1), pk2bf(n2, n3));
    }
}

// ---------------- batched transpose-convert: W fp32 [R,C] -> WT bf16 [C,R] ------
__global__ __launch_bounds__(256) void tconv_b_k(const float* __restrict__ W,
                                                 __hip_bfloat16* __restrict__ WT,
                                                 int R, int C,
                                                 size_t wstride, size_t tstride) {
    __shared__ float t[32][33];
    const float* Wl = W + (size_t)blockIdx.z * wstride;
    __hip_bfloat16* Tl = WT + (size_t)blockIdx.z * tstride;
    int c0 = blockIdx.x * 32, r0 = blockIdx.y * 32;
    int tx = threadIdx.x & 31, ty = threadIdx.x >> 5;
#pragma unroll
    for (int i = 0; i < 4; ++i)
        t[ty + 8 * i][tx] = Wl[(size_t)(r0 + ty + 8 * i) * C + c0 + tx];
    __syncthreads();
#pragma unroll
    for (int i = 0; i < 4; ++i)
        Tl[(size_t)(c0 + ty + 8 * i) * R + r0 + tx] = __float2bfloat16(t[tx][ty + 8 * i]);
}

// ---------------- MFMA GEMM (m97 structure, 128x128, BK=32) ----------------
template <bool BIAS, bool RELU, bool ACCUM, bool OBF16>
__global__ __launch_bounds__(256) void mgemm_k(const __hip_bfloat16* __restrict__ A,
                                               const __hip_bfloat16* __restrict__ BT,
                                               const float* __restrict__ bias,
                                               void* __restrict__ Cv,
                                               int M, int N, int K, int ntn) {
    __shared__ __align__(16) short As[128 * 32];
    __shared__ __align__(16) short Bs[128 * 32];

    int nwg = gridDim.x;
    int bid = blockIdx.x;
    int cpx = nwg >> 3;
    int swz = (bid & 7) * cpx + (bid >> 3);
    int tm = swz / ntn, tn = swz - tm * ntn;
    int m0 = tm * 128, n0 = tn * 128;

    int tid = threadIdx.x;
    int lane = tid & 63;
    int wave = tid >> 6;
    int wr = wave >> 1, wc = wave & 1;

    f32x4_t acc[4][4];
#pragma unroll
    for (int i = 0; i < 4; ++i)
#pragma unroll
        for (int j = 0; j < 4; ++j)
#pragma unroll
            for (int r = 0; r < 4; ++r) acc[i][j][r] = 0.f;

    const short* Ag = (const short*)A;
    const short* Bg = (const short*)BT;
    const int arow0 = tid >> 2;
    const int arow1 = (tid + 256) >> 2;
    const int acol = (tid & 3) * 8;

    const int fr = lane & 15;
    const int kg = (lane >> 4) * 8;

    for (int k0 = 0; k0 < K; k0 += 32) {
        gload_lds16(Ag + (size_t)(m0 + arow0) * K + k0 + acol, &As[tid * 8]);
        gload_lds16(Ag + (size_t)(m0 + arow1) * K + k0 + acol, &As[(tid + 256) * 8]);
        gload_lds16(Bg + (size_t)(n0 + arow0) * K + k0 + acol, &Bs[tid * 8]);
        gload_lds16(Bg + (size_t)(n0 + arow1) * K + k0 + acol, &Bs[(tid + 256) * 8]);
        __syncthreads();

        bf16x8_t af[4], bq[4];
#pragma unroll
        for (int mi = 0; mi < 4; ++mi)
            af[mi] = *(const bf16x8_t*)&As[(wr * 64 + mi * 16 + fr) * 32 + kg];
#pragma unroll
        for (int ni = 0; ni < 4; ++ni)
            bq[ni] = *(const bf16x8_t*)&Bs[(wc * 64 + ni * 16 + fr) * 32 + kg];
#pragma unroll
        for (int mi = 0; mi < 4; ++mi)
#pragma unroll
            for (int ni = 0; ni < 4; ++ni)
                acc[mi][ni] = __builtin_amdgcn_mfma_f32_16x16x32_bf16(af[mi], bq[ni], acc[mi][ni], 0, 0, 0);
        __syncthreads();
    }

    float bvec[4];
    if (BIAS) {
#pragma unroll
        for (int ni = 0; ni < 4; ++ni) bvec[ni] = bias[n0 + wc * 64 + ni * 16 + fr];
    }
    const int rbase = m0 + wr * 64 + (lane >> 4) * 4;
    const int cbase = n0 + wc * 64 + fr;
#pragma unroll
    for (int mi = 0; mi < 4; ++mi) {
#pragma unroll
        for (int ni = 0; ni < 4; ++ni) {
#pragma unroll
            for (int r = 0; r < 4; ++r) {
                int row = rbase + mi * 16 + r;
                int col = cbase + ni * 16;
                float v = acc[mi][ni][r];
                if (BIAS) v += bvec[ni];
                if (RELU) v = fmaxf(v, 0.f);
                size_t off = (size_t)row * N + col;
                if (OBF16) {
                    ((__hip_bfloat16*)Cv)[off] = __float2bfloat16(v);
                } else {
                    float* Cf = (float*)Cv;
                    if (ACCUM) Cf[off] += v; else Cf[off] = v;
                }
            }
        }
    }
}

// ---------------- LM-head GEMM: 128(M)x256(N) tile, BK=32, 512 thr, 24 KB LDS ---
// m97 single-buffer schedule (stage -> bar -> ds_read+MFMA -> bar); 2-3 blocks/CU
// so staging stalls and the 128 KB fp32 write tail overlap across blocks.
// Waves: 2M x 4N, wave-tile 64x64. LSE epilogue -> partials[row][tn].
__global__ __launch_bounds__(512, 4) void mgemm_lm_k(const __hip_bfloat16* __restrict__ A,
                                                     const __hip_bfloat16* __restrict__ BT,
                                                     const float* __restrict__ bias,
                                                     float* __restrict__ C,
                                                     int M, int N, int K,
                                                     int ntn, int npart,
                                                     float2* __restrict__ partials) {
    __shared__ __align__(16) short As[128 * 32];
    __shared__ __align__(16) short Bs[256 * 32];

    const int nwg = gridDim.x;
    const int bid = blockIdx.x;
    const int cpx = nwg >> 3;
    const int swz = (bid & 7) * cpx + (bid >> 3);
    const int tm = swz / ntn, tn = swz - tm * ntn;
    const int m0 = tm * 128, n0 = tn * 256;

    const int tid = threadIdx.x;
    const int lane = tid & 63;
    const int wave = tid >> 6;
    const int wm = wave >> 2;    // 0..1 (64 rows each)
    const int wn = wave & 3;     // 0..3 (64 cols each)
    const int fr = lane & 15;
    const int hi4 = lane >> 4;

    f32x4_t acc[4][4];
#pragma unroll
    for (int i = 0; i < 4; ++i)
#pragma unroll
        for (int j = 0; j < 4; ++j)
#pragma unroll
            for (int r = 0; r < 4; ++r) acc[i][j][r] = 0.f;

    const short* Ag = (const short*)A;
    const short* Bg = (const short*)BT;
    const int srow = tid >> 2;          // 0..127
    const int scol = (tid & 3) * 8;     // bf16 elems
    const int kg = hi4 * 8;

    for (int k0 = 0; k0 < K; k0 += 32) {
        gload_lds16(Ag + (size_t)(m0 + srow) * K + k0 + scol, &As[tid * 8]);
        gload_lds16(Bg + (size_t)(n0 + srow) * K + k0 + scol, &Bs[tid * 8]);
        gload_lds16(Bg + (size_t)(n0 + 128 + srow) * K + k0 + scol, &Bs[(tid + 512) * 8]);
        __syncthreads();

        bf16x8_t af[4], bq[4];
#pragma unroll
        for (int mi = 0; mi < 4; ++mi)
            af[mi] = *(const bf16x8_t*)&As[(wm * 64 + mi * 16 + fr) * 32 + kg];
#pragma unroll
        for (int ni = 0; ni < 4; ++ni)
            bq[ni] = *(const bf16x8_t*)&Bs[(wn * 64 + ni * 16 + fr) * 32 + kg];
#pragma unroll
        for (int mi = 0; mi < 4; ++mi)
#pragma unroll
            for (int ni = 0; ni < 4; ++ni)
                acc[mi][ni] = __builtin_amdgcn_mfma_f32_16x16x32_bf16(af[mi], bq[ni], acc[mi][ni], 0, 0, 0);
        __syncthreads();
    }

    // epilogue: C write + per-row LSE over this block's 256 cols
    float bvec[4];
#pragma unroll
    for (int ni = 0; ni < 4; ++ni) bvec[ni] = bias[n0 + wn * 64 + ni * 16 + fr];

    float2* red = (float2*)As;          // [128][4], 4 KB; loop done, LDS free
    const int cbase = n0 + wn * 64 + fr;
#pragma unroll
    for (int mi = 0; mi < 4; ++mi) {
#pragma unroll
        for (int r = 0; r < 4; ++r) {
            const int rl = wm * 64 + mi * 16 + hi4 * 4 + r;
            const size_t grow = (size_t)(m0 + rl);
            float v4[4];
#pragma unroll
            for (int ni = 0; ni < 4; ++ni) {
                float v = acc[mi][ni][r] + bvec[ni];
                v4[ni] = v;
                C[grow * N + cbase + ni * 16] = v;
            }
            float mx = fmaxf(fmaxf(v4[0], v4[1]), fmaxf(v4[2], v4[3]));
#pragma unroll
            for (int o = 1; o < 16; o <<= 1) mx = fmaxf(mx, __shfl_xor(mx, o));
            float sm = 0.f;
#pragma unroll
            for (int ni = 0; ni < 4; ++ni) sm += __expf(v4[ni] - mx);
#pragma unroll
            for (int o = 1; o < 16; o <<= 1) sm += __shfl_xor(sm, o);
            if (fr == 0) red[rl * 4 + wn] = make_float2(mx, sm);
        }
    }
    __syncthreads();
    if (tid < 128) {
        float2 p0 = red[tid * 4 + 0], p1 = red[tid * 4 + 1];
        float2 p2 = red[tid * 4 + 2], p3 = red[tid * 4 + 3];
        float M2 = fmaxf(fmaxf(p0.x, p1.x), fmaxf(p2.x, p3.x));
        float L2 = p0.y * __expf(p0.x - M2) + p1.y * __expf(p1.x - M2) +
                   p2.y * __expf(p2.x - M2) + p3.y * __expf(p3.x - M2);
        partials[(size_t)(m0 + tid) * npart + tn] = make_float2(M2, L2);
    }
}

// ---------------- MFMA flash attention: swapped QK^T + T14 async staging -------
__global__ __launch_bounds__(256) void fattn_k(const __hip_bfloat16* __restrict__ qkv,
                                               __hip_bfloat16* __restrict__ o) {
    __shared__ short Ks[KVB * HS];
    __shared__ short Vt[HS * KVB];
    __shared__ short Pl[4 * 32 * KVB];

    const int bh = blockIdx.x;
    const int hh = bh % HH;
    const int bI = bh / HH;
    const int qt = (TT / QBLK - 1) - blockIdx.y;   // heavy tiles first
    const int q0 = qt * QBLK;

    const int tid = threadIdx.x;
    const int lane = tid & 63;
    const int wave = tid >> 6;
    const int fr = lane & 15;
    const int hi4 = lane >> 4;

    const size_t rowbase = (size_t)bI * TT;
    const int wq0 = q0 + wave * 32;

    // Q fragments, pre-scaled by 1/8 (exact exponent shift in bf16)
    bf16x8_t qf[2][2];
#pragma unroll
    for (int mi = 0; mi < 2; ++mi)
#pragma unroll
        for (int kc = 0; kc < 2; ++kc) {
            const short* src = (const short*)qkv +
                (rowbase + wq0 + mi * 16 + fr) * QS + hh * HS + kc * 32 + hi4 * 8;
            bf16x8_t v = *(const bf16x8_t*)src;
#pragma unroll
            for (int e = 0; e < 8; ++e) {
                float f = __uint_as_float(((unsigned)(unsigned short)v[e]) << 16) * 0.125f;
                v[e] = (short)(__float_as_uint(f) >> 16);
            }
            qf[mi][kc] = v;
        }

    f32x4_t oa[2][4];
    float m_r[2], l_r[2];
#pragma unroll
    for (int mi = 0; mi < 2; ++mi) {
        m_r[mi] = -INFINITY;
        l_r[mi] = 0.f;
#pragma unroll
        for (int nd = 0; nd < 4; ++nd)
#pragma unroll
            for (int r = 0; r < 4; ++r) oa[mi][nd][r] = 0.f;
    }

    const int skey = tid >> 2;
    const int sd0 = (tid & 3) * 16;
    const int niter = 2 * (qt + 1);

    // T14: K/V tile regs loaded one iteration ahead
    uint4 ka, kb2, va, vb2;
    {
        const short* kg = (const short*)qkv + (rowbase + skey) * QS + EE + hh * HS + sd0;
        ka = *(const uint4*)kg; kb2 = *(const uint4*)(kg + 8);
        const short* vg = (const short*)qkv + (rowbase + skey) * QS + 2 * EE + hh * HS + sd0;
        va = *(const uint4*)vg; vb2 = *(const uint4*)(vg + 8);
    }

    for (int it = 0; it < niter; ++it) {
        __syncthreads();   // previous iter's LDS reads done
        // ---- write pre-loaded K and V^T regs into swizzled LDS ----
        {
            const int rs = (skey & 7) << 4;
            char* kbp = (char*)Ks;
            *(uint4*)(kbp + ((skey * 128 + sd0 * 2) ^ rs)) = ka;
            *(uint4*)(kbp + ((skey * 128 + sd0 * 2 + 16) ^ rs)) = kb2;

            char* vbp = (char*)Vt;
            const short* vs0 = (const short*)&va;
#pragma unroll
            for (int e = 0; e < 8; ++e) {
                int dd = sd0 + e;
                *(short*)(vbp + ((dd * 128 + skey * 2) ^ ((dd & 7) << 4))) = vs0[e];
            }
            const short* vs1 = (const short*)&vb2;
#pragma unroll
            for (int e = 0; e < 8; ++e) {
                int dd = sd0 + 8 + e;
                *(short*)(vbp + ((dd * 128 + skey * 2) ^ ((dd & 7) << 4))) = vs1[e];
            }
        }
        __syncthreads();

        // ---- issue next tile's loads (latency hides under compute below) ----
        if (it + 1 < niter) {
            const int kvn = (it + 1) * KVB;
            const short* kg = (const short*)qkv + (rowbase + kvn + skey) * QS + EE + hh * HS + sd0;
            ka = *(const uint4*)kg; kb2 = *(const uint4*)(kg + 8);
            const short* vg = (const short*)qkv + (rowbase + kvn + skey) * QS + 2 * EE + hh * HS + sd0;
            va = *(const uint4*)vg; vb2 = *(const uint4*)(vg + 8);
        }

        const int kv0 = it * KVB;

        // ---- S^T = K Q^T (operand-swapped) ----
        f32x4_t sa[2][4];
#pragma unroll
        for (int mi = 0; mi < 2; ++mi)
#pragma unroll
            for (int ni = 0; ni < 4; ++ni)
#pragma unroll
                for (int r = 0; r < 4; ++r) sa[mi][ni][r] = 0.f;
#pragma unroll
        for (int kc = 0; kc < 2; ++kc) {
            bf16x8_t kf[4];
#pragma unroll
            for (int ni = 0; ni < 4; ++ni) {
                int krow = ni * 16 + fr;
                kf[ni] = *(const bf16x8_t*)((char*)Ks +
                    ((krow * 128 + (kc * 32 + hi4 * 8) * 2) ^ ((krow & 7) << 4)));
            }
#pragma unroll
            for (int mi = 0; mi < 2; ++mi)
#pragma unroll
                for (int ni = 0; ni < 4; ++ni)
                    sa[mi][ni] = __builtin_amdgcn_mfma_f32_16x16x32_bf16(kf[ni], qf[mi][kc], sa[mi][ni], 0, 0, 0);
        }

        // ---- causal mask ----
        if (kv0 + KVB - 1 > wq0) {
#pragma unroll
            for (int mi = 0; mi < 2; ++mi) {
                int qrow = wq0 + mi * 16 + fr;
#pragma unroll
                for (int ni = 0; ni < 4; ++ni)
#pragma unroll
                    for (int r = 0; r < 4; ++r) {
                        int key = kv0 + ni * 16 + hi4 * 4 + r;
                        if (key > qrow) sa[mi][ni][r] = -1e30f;
                    }
            }
        }

        // ---- online softmax (in-lane 16 values + 2 shfl) ----
        char* Pw = (char*)Pl + wave * 4096;
#pragma unroll
        for (int mi = 0; mi < 2; ++mi) {
            float mx = sa[mi][0][0];
#pragma unroll
            for (int ni = 0; ni < 4; ++ni)
#pragma unroll
                for (int r = 0; r < 4; ++r) mx = fmaxf(mx, sa[mi][ni][r]);
            mx = fmaxf(mx, __shfl_xor(mx, 16));
            mx = fmaxf(mx, __shfl_xor(mx, 32));
            float mnew = fmaxf(m_r[mi], mx);
            float al = __expf(m_r[mi] - mnew);
            m_r[mi] = mnew;
            float ps = 0.f;
#pragma unroll
            for (int ni = 0; ni < 4; ++ni) {
#pragma unroll
                for (int r = 0; r < 4; ++r) {
                    float p = __expf(sa[mi][ni][r] - mnew);
                    sa[mi][ni][r] = p;
                    ps += p;
                }
                uint2 pw;
                pw.x = pk2bf(sa[mi][ni][0], sa[mi][ni][1]);
                pw.y = pk2bf(sa[mi][ni][2], sa[mi][ni][3]);
                int prow = mi * 16 + fr;
                int cb = ni * 32 + hi4 * 8;
                *(uint2*)(Pw + ((prow * 128 + cb) ^ ((prow & 7) << 4))) = pw;
            }
            ps += __shfl_xor(ps, 16);
            ps += __shfl_xor(ps, 32);
            l_r[mi] = l_r[mi] * al + ps;
#pragma unroll
            for (int r = 0; r < 4; ++r) {
                float a_r = __shfl(al, hi4 * 4 + r);
#pragma unroll
                for (int nd = 0; nd < 4; ++nd) oa[mi][nd][r] *= a_r;
            }
        }

        // ---- O += P V ----
#pragma unroll
        for (int kc = 0; kc < 2; ++kc) {
            bf16x8_t pf[2], vf[4];
#pragma unroll
            for (int mi = 0; mi < 2; ++mi) {
                int prow = mi * 16 + fr;
                pf[mi] = *(const bf16x8_t*)(Pw +
                    ((prow * 128 + (kc * 32 + hi4 * 8) * 2) ^ ((prow & 7) << 4)));
            }
#pragma unroll
            for (int nd = 0; nd < 4; ++nd) {
                int vrow = nd * 16 + fr;
                vf[nd] = *(const bf16x8_t*)((char*)Vt +
                    ((vrow * 128 + (kc * 32 + hi4 * 8) * 2) ^ ((vrow & 7) << 4)));
            }
#pragma unroll
            for (int mi = 0; mi < 2; ++mi)
#pragma unroll
                for (int nd = 0; nd < 4; ++nd)
                    oa[mi][nd] = __builtin_amdgcn_mfma_f32_16x16x32_bf16(pf[mi], vf[nd], oa[mi][nd], 0, 0, 0);
        }
    }

    // ---- epilogue ----
#pragma unroll
    for (int mi = 0; mi < 2; ++mi)
#pragma unroll
        for (int r = 0; r < 4; ++r) {
            float lr = __shfl(l_r[mi], hi4 * 4 + r);
            float inv = 1.0f / lr;
            int row = wq0 + mi * 16 + hi4 * 4 + r;
            __hip_bfloat16* orow = o + (rowbase + row) * EE + hh * HS;
#pragma unroll
            for (int nd = 0; nd < 4; ++nd)
                orow[nd * 16 + fr] = __float2bfloat16(oa[mi][nd][r] * inv);
        }
}

// ---------------- loss: merge per-block LSE partials ----------------
__global__ __launch_bounds__(256) void rowloss2_k(const float2* __restrict__ partials,
                                                  const float* __restrict__ logits,
                                                  const int* __restrict__ targets,
                                                  float* __restrict__ rowloss, int ntn) {
    __shared__ float red[4];
    int row = blockIdx.x;
    int tid = threadIdx.x;
    float m = -INFINITY, l = 0.f;
    if (tid < ntn) {
        float2 p = partials[(size_t)row * ntn + tid];
        m = p.x; l = p.y;
    }
    float mg = block_max256(m, red);
    float s = (tid < ntn) ? l * __expf(m - mg) : 0.f;
    s = block_sum256(s, red);
    if (tid == 0)
        rowloss[row] = mg + logf(s) - logits[(size_t)row * VV + targets[row]];
}

__global__ __launch_bounds__(256) void loss_final_k(const float* __restrict__ rowloss,
                                                    float* __restrict__ out) {
    __shared__ float red[4];
    float s = 0.f;
    for (int i = threadIdx.x; i < MROWS; i += 256) s += rowloss[i];
    s = block_sum256(s, red);
    if (threadIdx.x == 0) out[0] = s * (1.0f / MROWS);
}

// ---------------- launcher ----------------
extern "C" void kernel_launch(void* const* d_in, const int* in_sizes, int n_in,
                              void* d_out, int out_size, void* d_ws, size_t ws_size,
                              hipStream_t stream) {
    const int* idx      = (const int*)d_in[0];
    const int* targets  = (const int*)d_in[1];
    const float* tok    = (const float*)d_in[2];
    const float* pos    = (const float*)d_in[3];
    const float* Wq     = (const float*)d_in[4];
    const float* Wk     = (const float*)d_in[5];
    const float* Wv     = (const float*)d_in[6];
    const float* Wp     = (const float*)d_in[7];
    const float* bp     = (const float*)d_in[8];
    const float* W1     = (const float*)d_in[9];
    const float* b1     = (const float*)d_in[10];
    const float* W2     = (const float*)d_in[11];
    const float* b2     = (const float*)d_in[12];
    const float* ln1_g  = (const float*)d_in[13];
    const float* ln1_b  = (const float*)d_in[14];
    const float* ln2_g  = (const float*)d_in[15];
    const float* ln2_b  = (const float*)d_in[16];
    const float* lnf_g  = (const float*)d_in[17];
    const float* lnf_b  = (const float*)d_in[18];
    const float* Wlm    = (const float*)d_in[19];
    const float* blm    = (const float*)d_in[20];

    float* out = (float*)d_out;

    // ---- workspace carve ----
    char* w = (char*)d_ws;
    float* x = (float*)w;                             w += (size_t)MROWS * EE * 4;
    __hip_bfloat16* hbf = (__hip_bfloat16*)w;         w += (size_t)MROWS * EE * 2;
    __hip_bfloat16* qkv = (__hip_bfloat16*)w;         w += (size_t)MROWS * QS * 2;
    __hip_bfloat16* obf = (__hip_bfloat16*)w;         w += (size_t)MROWS * EE * 2;
    __hip_bfloat16* ff1 = (__hip_bfloat16*)w;         w += (size_t)MROWS * FFD * 2;
    float2* partials = (float2*)ff1;                  // aliases ff1: dead by LM-head time
    __hip_bfloat16* wlmT = (__hip_bfloat16*)w;        w += (size_t)VV * EE * 2;
    float* rowloss = (float*)w;                       w += (size_t)MROWS * 4 + 256;
    __hip_bfloat16* wbase = (__hip_bfloat16*)w;       // layer weights from here

    const size_t base_used = (size_t)(w - (char*)d_ws);
    const size_t per_layer_w = ((size_t)QS * EE + (size_t)EE * EE +
                                (size_t)FFD * EE + (size_t)EE * FFD) * 2;
    const bool hoist = ws_size >= base_used + per_layer_w * LAYERS;
    const int nlw = hoist ? LAYERS : 1;

    __hip_bfloat16* qkvwT = wbase;
    __hip_bfloat16* wpT   = qkvwT + (size_t)nlw * QS * EE;
    __hip_bfloat16* w1T   = wpT   + (size_t)nlw * EE * EE;
    __hip_bfloat16* w2T   = w1T   + (size_t)nlw * FFD * EE;

    dim3 blk(256);

    embed4_k<<<MROWS / 4, blk, 0, stream>>>(idx, tok, pos, x);

    if (hoist) {
        tconv_b_k<<<dim3(EE / 32, EE / 32, LAYERS), blk, 0, stream>>>(
            Wq, qkvwT, EE, EE, (size_t)EE * EE, (size_t)QS * EE);
        tconv_b_k<<<dim3(EE / 32, EE / 32, LAYERS), blk, 0, stream>>>(
            Wk, qkvwT + (size_t)EE * EE, EE, EE, (size_t)EE * EE, (size_t)QS * EE);
        tconv_b_k<<<dim3(EE / 32, EE / 32, LAYERS), blk, 0, stream>>>(
            Wv, qkvwT + (size_t)2 * EE * EE, EE, EE, (size_t)EE * EE, (size_t)QS * EE);
        tconv_b_k<<<dim3(EE / 32, EE / 32, LAYERS), blk, 0, stream>>>(
            Wp, wpT, EE, EE, (size_t)EE * EE, (size_t)EE * EE);
        tconv_b_k<<<dim3(FFD / 32, EE / 32, LAYERS), blk, 0, stream>>>(
            W1, w1T, EE, FFD, (size_t)EE * FFD, (size_t)FFD * EE);
        tconv_b_k<<<dim3(EE / 32, FFD / 32, LAYERS), blk, 0, stream>>>(
            W2, w2T, FFD, EE, (size_t)FFD * EE, (size_t)EE * FFD);
    }
    tconv_b_k<<<dim3(VV / 32, EE / 32, 1), blk, 0, stream>>>(Wlm, wlmT, EE, VV, 0, 0);

    for (int l = 0; l < LAYERS; ++l) {
        __hip_bfloat16* qkvwT_l = qkvwT + (hoist ? (size_t)l * QS * EE : 0);
        __hip_bfloat16* wpT_l   = wpT   + (hoist ? (size_t)l * EE * EE : 0);
        __hip_bfloat16* w1T_l   = w1T   + (hoist ? (size_t)l * FFD * EE : 0);
        __hip_bfloat16* w2T_l   = w2T   + (hoist ? (size_t)l * EE * FFD : 0);
        if (!hoist) {
            tconv_b_k<<<dim3(EE / 32, EE / 32, 1), blk, 0, stream>>>(
                Wq + (size_t)l * EE * EE, qkvwT_l, EE, EE, 0, 0);
            tconv_b_k<<<dim3(EE / 32, EE / 32, 1), blk, 0, stream>>>(
                Wk + (size_t)l * EE * EE, qkvwT_l + (size_t)EE * EE, EE, EE, 0, 0);
            tconv_b_k<<<dim3(EE / 32, EE / 32, 1), blk, 0, stream>>>(
                Wv + (size_t)l * EE * EE, qkvwT_l + (size_t)2 * EE * EE, EE, EE, 0, 0);
            tconv_b_k<<<dim3(EE / 32, EE / 32, 1), blk, 0, stream>>>(
                Wp + (size_t)l * EE * EE, wpT_l, EE, EE, 0, 0);
            tconv_b_k<<<dim3(FFD / 32, EE / 32, 1), blk, 0, stream>>>(
                W1 + (size_t)l * EE * FFD, w1T_l, EE, FFD, 0, 0);
            tconv_b_k<<<dim3(EE / 32, FFD / 32, 1), blk, 0, stream>>>(
                W2 + (size_t)l * FFD * EE, w2T_l, FFD, EE, 0, 0);
        }

        ln4_k<<<MROWS / 4, blk, 0, stream>>>(x, ln1_g + l * EE, ln1_b + l * EE, hbf);
        mgemm_k<false, false, false, true><<<dim3((MROWS / 128) * (QS / 128)), blk, 0, stream>>>(
            hbf, qkvwT_l, nullptr, qkv, MROWS, QS, EE, QS / 128);
        fattn_k<<<dim3(BB * HH, TT / QBLK), blk, 0, stream>>>(qkv, obf);
        mgemm_k<true, false, true, false><<<dim3((MROWS / 128) * (EE / 128)), blk, 0, stream>>>(
            obf, wpT_l, bp + l * EE, x, MROWS, EE, EE, EE / 128);
        ln4_k<<<MROWS / 4, blk, 0, stream>>>(x, ln2_g + l * EE, ln2_b + l * EE, hbf);
        mgemm_k<true, true, false, true><<<dim3((MROWS / 128) * (FFD / 128)), blk, 0, stream>>>(
            hbf, w1T_l, b1 + l * FFD, ff1, MROWS, FFD, EE, FFD / 128);
        mgemm_k<true, false, true, false><<<dim3((MROWS / 128) * (EE / 128)), blk, 0, stream>>>(
            ff1, w2T_l, b2 + l * EE, x, MROWS, EE, FFD, EE / 128);
    }

    ln4_k<<<MROWS / 4, blk, 0, stream>>>(x, lnf_g, lnf_b, hbf);
    // LM head: 128x256-tile, 24 KB LDS, multi-block/CU + fused LSE partials
    mgemm_lm_k<<<dim3((MROWS / 128) * (VV / 256)), dim3(512), 0, stream>>>(
        hbf, wlmT, blm, out, MROWS, VV, EE, VV / 256, NPART, partials);

    rowloss2_k<<<MROWS, blk, 0, stream>>>(partials, out, targets, rowloss, NPART);
    loss_final_k<<<1, blk, 0, stream>>>(rowloss, out + (size_t)MROWS * VV);
}

// Round 8
// 1614.221 us; speedup vs baseline: 9.6695x; 1.1296x over previous
//
#include <hip/hip_runtime.h>
#include <hip/hip_bf16.h>
#include <math.h>

#define LAYERS 6
#define BB 4
#define TT 1024
#define EE 768
#define HH 12
#define HS 64
#define VV 32000
#define FFD 3072
#define MROWS (BB * TT)   // 4096
#define QS (3 * EE)       // 2304, fused qkv row stride
#define KVB 64
#define QBLK 128
#define NPART (VV / 256)  // 125 LSE partial blocks per row

typedef __attribute__((ext_vector_type(8))) short bf16x8_t;
typedef __attribute__((ext_vector_type(4))) float f32x4_t;

// ---------------- helpers ----------------
__device__ __forceinline__ float wave_sum(float v) {
#pragma unroll
    for (int o = 32; o > 0; o >>= 1) v += __shfl_xor(v, o);
    return v;
}
__device__ __forceinline__ float wave_max(float v) {
#pragma unroll
    for (int o = 32; o > 0; o >>= 1) v = fmaxf(v, __shfl_xor(v, o));
    return v;
}
__device__ __forceinline__ float block_sum256(float v, float* red) {
    v = wave_sum(v);
    int tid = threadIdx.x;
    if ((tid & 63) == 0) red[tid >> 6] = v;
    __syncthreads();
    float r = red[0] + red[1] + red[2] + red[3];
    __syncthreads();
    return r;
}
__device__ __forceinline__ float block_max256(float v, float* red) {
    v = wave_max(v);
    int tid = threadIdx.x;
    if ((tid & 63) == 0) red[tid >> 6] = v;
    __syncthreads();
    float r = fmaxf(fmaxf(red[0], red[1]), fmaxf(red[2], red[3]));
    __syncthreads();
    return r;
}

__device__ __forceinline__ void gload_lds16(const void* g, void* l) {
    __builtin_amdgcn_global_load_lds((const __attribute__((address_space(1))) void*)g,
                                     (__attribute__((address_space(3))) void*)l, 16, 0, 0);
}

// pack two f32 -> u32 of 2 bf16 (lo at low address)
__device__ __forceinline__ unsigned pk2bf(float lo, float hi) {
    __hip_bfloat162 h2 = __float22bfloat162_rn(make_float2(lo, hi));
    return *reinterpret_cast<unsigned*>(&h2);
}

// ---------------- embedding: 4 rows/block, wave per row, float4 ----------------
__global__ __launch_bounds__(256) void embed4_k(const int* __restrict__ idx,
                                                const float* __restrict__ tok,
                                                const float* __restrict__ pos,
                                                float* __restrict__ x) {
    int row = blockIdx.x * 4 + (threadIdx.x >> 6);
    int lane = threadIdx.x & 63;
    int t = row & (TT - 1);
    int token = idx[row];
    const float4* te = (const float4*)(tok + (size_t)token * EE);
    const float4* pe = (const float4*)(pos + (size_t)t * EE);
    float4* xr = (float4*)(x + (size_t)row * EE);
#pragma unroll
    for (int j = 0; j < 3; ++j) {
        int i = j * 64 + lane;
        float4 a = te[i], b = pe[i];
        xr[i] = make_float4(a.x + b.x, a.y + b.y, a.z + b.z, a.w + b.w);
    }
}

// ---------------- LayerNorm: wave per row, register-resident, fp32->bf16 -------
__global__ __launch_bounds__(256) void ln4_k(const float* __restrict__ x,
                                             const float* __restrict__ g,
                                             const float* __restrict__ b,
                                             __hip_bfloat16* __restrict__ out) {
    int row = blockIdx.x * 4 + (threadIdx.x >> 6);
    int lane = threadIdx.x & 63;
    const float4* xr = (const float4*)(x + (size_t)row * EE);
    float4 v[3];
    float s = 0.f;
#pragma unroll
    for (int j = 0; j < 3; ++j) {
        v[j] = xr[j * 64 + lane];
        s += v[j].x + v[j].y + v[j].z + v[j].w;
    }
    s = wave_sum(s);
    float m = s * (1.0f / EE);
    float vs = 0.f;
#pragma unroll
    for (int j = 0; j < 3; ++j) {
        float d0 = v[j].x - m, d1 = v[j].y - m, d2 = v[j].z - m, d3 = v[j].w - m;
        vs += d0 * d0 + d1 * d1 + d2 * d2 + d3 * d3;
    }
    vs = wave_sum(vs);
    float rstd = rsqrtf(vs * (1.0f / EE) + 1e-5f);
    const float4* g4 = (const float4*)g;
    const float4* b4 = (const float4*)b;
    uint2* orow = (uint2*)(out + (size_t)row * EE);
#pragma unroll
    for (int j = 0; j < 3; ++j) {
        int i = j * 64 + lane;
        float4 gg = g4[i], bb = b4[i];
        float n0 = (v[j].x - m) * rstd * gg.x + bb.x;
        float n1 = (v[j].y - m) * rstd * gg.y + bb.y;
        float n2 = (v[j].z - m) * rstd * gg.z + bb.z;
        float n3 = (v[j].w - m) * rstd * gg.w + bb.w;
        orow[i] = make_uint2(pk2bf(n0, n1), pk2bf(n2, n3));
    }
}

// ---------------- batched transpose-convert: W fp32 [R,C] -> WT bf16 [C,R] ------
__global__ __launch_bounds__(256) void tconv_b_k(const float* __restrict__ W,
                                                 __hip_bfloat16* __restrict__ WT,
                                                 int R, int C,
                                                 size_t wstride, size_t tstride) {
    __shared__ float t[32][33];
    const float* Wl = W + (size_t)blockIdx.z * wstride;
    __hip_bfloat16* Tl = WT + (size_t)blockIdx.z * tstride;
    int c0 = blockIdx.x * 32, r0 = blockIdx.y * 32;
    int tx = threadIdx.x & 31, ty = threadIdx.x >> 5;
#pragma unroll
    for (int i = 0; i < 4; ++i)
        t[ty + 8 * i][tx] = Wl[(size_t)(r0 + ty + 8 * i) * C + c0 + tx];
    __syncthreads();
#pragma unroll
    for (int i = 0; i < 4; ++i)
        Tl[(size_t)(c0 + ty + 8 * i) * R + r0 + tx] = __float2bfloat16(t[tx][ty + 8 * i]);
}

// ---------------- MFMA GEMM (m97 structure, MI*32 x 128 tile, BK=32) -----------
// MI=4: 128-row tile (wave owns 64 rows). MI=2: 64-row tile (wave owns 32 rows;
// grid 2x larger -> occupancy fix for skinny-N GEMMs like proj/FF2).
template <bool BIAS, bool RELU, bool ACCUM, bool OBF16, int MI>
__global__ __launch_bounds__(256) void mgemm_k(const __hip_bfloat16* __restrict__ A,
                                               const __hip_bfloat16* __restrict__ BT,
                                               const float* __restrict__ bias,
                                               void* __restrict__ Cv,
                                               int M, int N, int K, int ntn) {
    __shared__ __align__(16) short As[MI * 32 * 32];
    __shared__ __align__(16) short Bs[128 * 32];

    int nwg = gridDim.x;
    int bid = blockIdx.x;
    int cpx = nwg >> 3;
    int swz = (bid & 7) * cpx + (bid >> 3);
    int tm = swz / ntn, tn = swz - tm * ntn;
    int m0 = tm * (MI * 32), n0 = tn * 128;

    int tid = threadIdx.x;
    int lane = tid & 63;
    int wave = tid >> 6;
    int wr = wave >> 1, wc = wave & 1;

    f32x4_t acc[MI][4];
#pragma unroll
    for (int i = 0; i < MI; ++i)
#pragma unroll
        for (int j = 0; j < 4; ++j)
#pragma unroll
            for (int r = 0; r < 4; ++r) acc[i][j][r] = 0.f;

    const short* Ag = (const short*)A;
    const short* Bg = (const short*)BT;
    const int arow0 = tid >> 2;
    const int arow1 = (tid + 256) >> 2;
    const int acol = (tid & 3) * 8;

    const int fr = lane & 15;
    const int kg = (lane >> 4) * 8;

    for (int k0 = 0; k0 < K; k0 += 32) {
        gload_lds16(Ag + (size_t)(m0 + arow0) * K + k0 + acol, &As[tid * 8]);
        if (MI == 4)
            gload_lds16(Ag + (size_t)(m0 + arow1) * K + k0 + acol, &As[(tid + 256) * 8]);
        gload_lds16(Bg + (size_t)(n0 + arow0) * K + k0 + acol, &Bs[tid * 8]);
        gload_lds16(Bg + (size_t)(n0 + arow1) * K + k0 + acol, &Bs[(tid + 256) * 8]);
        __syncthreads();

        bf16x8_t af[MI], bq[4];
#pragma unroll
        for (int mi = 0; mi < MI; ++mi)
            af[mi] = *(const bf16x8_t*)&As[(wr * (MI * 16) + mi * 16 + fr) * 32 + kg];
#pragma unroll
        for (int ni = 0; ni < 4; ++ni)
            bq[ni] = *(const bf16x8_t*)&Bs[(wc * 64 + ni * 16 + fr) * 32 + kg];
#pragma unroll
        for (int mi = 0; mi < MI; ++mi)
#pragma unroll
            for (int ni = 0; ni < 4; ++ni)
                acc[mi][ni] = __builtin_amdgcn_mfma_f32_16x16x32_bf16(af[mi], bq[ni], acc[mi][ni], 0, 0, 0);
        __syncthreads();
    }

    float bvec[4];
    if (BIAS) {
#pragma unroll
        for (int ni = 0; ni < 4; ++ni) bvec[ni] = bias[n0 + wc * 64 + ni * 16 + fr];
    }
    const int rbase = m0 + wr * (MI * 16) + (lane >> 4) * 4;
    const int cbase = n0 + wc * 64 + fr;
#pragma unroll
    for (int mi = 0; mi < MI; ++mi) {
#pragma unroll
        for (int ni = 0; ni < 4; ++ni) {
#pragma unroll
            for (int r = 0; r < 4; ++r) {
                int row = rbase + mi * 16 + r;
                int col = cbase + ni * 16;
                float v = acc[mi][ni][r];
                if (BIAS) v += bvec[ni];
                if (RELU) v = fmaxf(v, 0.f);
                size_t off = (size_t)row * N + col;
                if (OBF16) {
                    ((__hip_bfloat16*)Cv)[off] = __float2bfloat16(v);
                } else {
                    float* Cf = (float*)Cv;
                    if (ACCUM) Cf[off] += v; else Cf[off] = v;
                }
            }
        }
    }
}

// ---------------- 256x256 8-phase MFMA GEMM (proven r5 form) — LM head ---------
__device__ __forceinline__ bf16x8_t ldsrd256(const short* base, int row, int colb) {
    return *(const bf16x8_t*)((const char*)base + ((row << 7) + (colb ^ ((row & 7) << 4))));
}

template <bool BIAS, bool RELU, bool OBF16, bool LSE>
__global__ __launch_bounds__(512, 2) void mgemm256_k(const __hip_bfloat16* __restrict__ A,
                                                     const __hip_bfloat16* __restrict__ BT,
                                                     const float* __restrict__ bias,
                                                     void* __restrict__ Cv,
                                                     int M, int N, int K,
                                                     int ntn, int npart,
                                                     float2* __restrict__ partials) {
    __shared__ __align__(16) short lds[2][2][2][8192];   // [buf][A/B][half][128*64]

    const int nwg = gridDim.x;
    const int bid = blockIdx.x;
    const int cpx = nwg >> 3;
    const int swz = (bid & 7) * cpx + (bid >> 3);
    const int tm = swz / ntn, tn = swz - tm * ntn;
    const int m0 = tm * 256, n0 = tn * 256;

    const int tid = threadIdx.x;
    const int lane = tid & 63;
    const int wave = tid >> 6;
    const int wm = wave >> 2;       // 0..1
    const int wn = wave & 3;        // 0..3
    const int fr = lane & 15;
    const int hi4 = lane >> 4;

    const short* Ag = (const short*)A;
    const short* Bg = (const short*)BT;
    const int nt = K >> 6;          // 12

    auto stage_half = [&](const short* g, int grow0, int k0, short* lbase) {
#pragma unroll
        for (int sub = 0; sub < 2; ++sub) {
            int d = sub * 8192 + tid * 16;
            int row = d >> 7;
            int cb = d & 127;
            int col = (cb ^ ((row & 7) << 4)) >> 1;
            gload_lds16(g + (size_t)(grow0 + row) * K + k0 + col, (char*)lbase + d);
        }
    };

    f32x4_t acc[2][2][4][2];
#pragma unroll
    for (int ah = 0; ah < 2; ++ah)
#pragma unroll
        for (int s = 0; s < 2; ++s)
#pragma unroll
            for (int mi = 0; mi < 4; ++mi)
#pragma unroll
                for (int ni = 0; ni < 2; ++ni)
#pragma unroll
                    for (int r = 0; r < 4; ++r) acc[ah][s][mi][ni][r] = 0.f;

    stage_half(Ag, m0 + 0,   0,  &lds[0][0][0][0]);
    stage_half(Bg, n0 + 0,   0,  &lds[0][1][0][0]);
    stage_half(Ag, m0 + 128, 0,  &lds[0][0][1][0]);
    stage_half(Bg, n0 + 128, 0,  &lds[0][1][1][0]);
    stage_half(Ag, m0 + 0,   64, &lds[1][0][0][0]);
    stage_half(Bg, n0 + 0,   64, &lds[1][1][0][0]);
    asm volatile("s_waitcnt vmcnt(4)" ::: "memory");
    __builtin_amdgcn_s_barrier();

    for (int t = 0; t < nt; ++t) {
        const int c = t & 1, o = c ^ 1;
        bf16x8_t a[4][2];
#pragma unroll
        for (int p = 0; p < 4; ++p) {
            const int ah = p >> 1, s = p & 1;
            if (s == 0) {
#pragma unroll
                for (int mi = 0; mi < 4; ++mi)
#pragma unroll
                    for (int kk = 0; kk < 2; ++kk)
                        a[mi][kk] = ldsrd256(&lds[c][0][ah][0],
                                             wm * 64 + mi * 16 + fr, kk * 64 + hi4 * 16);
            }
            bf16x8_t b[2][2];
#pragma unroll
            for (int ni = 0; ni < 2; ++ni)
#pragma unroll
                for (int kk = 0; kk < 2; ++kk)
                    b[ni][kk] = ldsrd256(&lds[c][1][s][0],
                                         wn * 32 + ni * 16 + fr, kk * 64 + hi4 * 16);
            if (p == 0 && t + 1 < nt) stage_half(Ag, m0 + 128, (t + 1) * 64, &lds[o][0][1][0]);
            if (p == 1 && t + 1 < nt) stage_half(Bg, n0 + 128, (t + 1) * 64, &lds[o][1][1][0]);
            if (p == 2 && t + 2 < nt) stage_half(Ag, m0 + 0,   (t + 2) * 64, &lds[c][0][0][0]);
            if (p == 3 && t + 2 < nt) stage_half(Bg, n0 + 0,   (t + 2) * 64, &lds[c][1][0][0]);
            if (p == 3) {
                if (t < nt - 2)       asm volatile("s_waitcnt vmcnt(4)" ::: "memory");
                else if (t == nt - 2) asm volatile("s_waitcnt vmcnt(0)" ::: "memory");
            }
            __builtin_amdgcn_s_barrier();
            asm volatile("s_waitcnt lgkmcnt(0)" ::: "memory");
            __builtin_amdgcn_sched_barrier(0);
            __builtin_amdgcn_s_setprio(1);
#pragma unroll
            for (int mi = 0; mi < 4; ++mi)
#pragma unroll
                for (int ni = 0; ni < 2; ++ni)
#pragma unroll
                    for (int kk = 0; kk < 2; ++kk)
                        acc[ah][s][mi][ni] = __builtin_amdgcn_mfma_f32_16x16x32_bf16(
                            a[mi][kk], b[ni][kk], acc[ah][s][mi][ni], 0, 0, 0);
            __builtin_amdgcn_s_setprio(0);
            __builtin_amdgcn_s_barrier();
        }
    }

    float bv[2][2];
    if (BIAS) {
#pragma unroll
        for (int s = 0; s < 2; ++s)
#pragma unroll
            for (int ni = 0; ni < 2; ++ni)
                bv[s][ni] = bias[n0 + s * 128 + wn * 32 + ni * 16 + fr];
    }
    float2* red = (float2*)&lds[0][0][0][0];
#pragma unroll
    for (int ah = 0; ah < 2; ++ah) {
#pragma unroll
        for (int mi = 0; mi < 4; ++mi) {
#pragma unroll
            for (int r = 0; r < 4; ++r) {
                const int rb = ah * 128 + wm * 64 + mi * 16 + hi4 * 4 + r;
                const size_t grow = (size_t)(m0 + rb);
                float v[2][2];
#pragma unroll
                for (int s = 0; s < 2; ++s)
#pragma unroll
                    for (int ni = 0; ni < 2; ++ni) {
                        float vv = acc[ah][s][mi][ni][r];
                        if (BIAS) vv += bv[s][ni];
                        if (RELU) vv = fmaxf(vv, 0.f);
                        v[s][ni] = vv;
                        size_t off = grow * N + n0 + s * 128 + wn * 32 + ni * 16 + fr;
                        if (OBF16) ((__hip_bfloat16*)Cv)[off] = __float2bfloat16(vv);
                        else       ((float*)Cv)[off] = vv;
                    }
                if (LSE) {
                    float mx = fmaxf(fmaxf(v[0][0], v[0][1]), fmaxf(v[1][0], v[1][1]));
#pragma unroll
                    for (int off2 = 1; off2 < 16; off2 <<= 1) mx = fmaxf(mx, __shfl_xor(mx, off2));
                    float sm = 0.f;
#pragma unroll
                    for (int s = 0; s < 2; ++s)
#pragma unroll
                        for (int ni = 0; ni < 2; ++ni) sm += __expf(v[s][ni] - mx);
#pragma unroll
                    for (int off2 = 1; off2 < 16; off2 <<= 1) sm += __shfl_xor(sm, off2);
                    if (fr == 0) red[rb * 4 + wn] = make_float2(mx, sm);
                }
            }
        }
    }
    if (LSE) {
        __syncthreads();
        if (tid < 256) {
            float2 p0 = red[tid * 4 + 0], p1 = red[tid * 4 + 1];
            float2 p2 = red[tid * 4 + 2], p3 = red[tid * 4 + 3];
            float M2 = fmaxf(fmaxf(p0.x, p1.x), fmaxf(p2.x, p3.x));
            float L2 = p0.y * __expf(p0.x - M2) + p1.y * __expf(p1.x - M2) +
                       p2.y * __expf(p2.x - M2) + p3.y * __expf(p3.x - M2);
            partials[(size_t)(m0 + tid) * npart + tn] = make_float2(M2, L2);
        }
    }
}

// ---------------- MFMA flash attention: swapped QK^T + T14 async staging -------
__global__ __launch_bounds__(256) void fattn_k(const __hip_bfloat16* __restrict__ qkv,
                                               __hip_bfloat16* __restrict__ o) {
    __shared__ short Ks[KVB * HS];
    __shared__ short Vt[HS * KVB];
    __shared__ short Pl[4 * 32 * KVB];

    const int bh = blockIdx.x;
    const int hh = bh % HH;
    const int bI = bh / HH;
    const int qt = (TT / QBLK - 1) - blockIdx.y;   // heavy tiles first
    const int q0 = qt * QBLK;

    const int tid = threadIdx.x;
    const int lane = tid & 63;
    const int wave = tid >> 6;
    const int fr = lane & 15;
    const int hi4 = lane >> 4;

    const size_t rowbase = (size_t)bI * TT;
    const int wq0 = q0 + wave * 32;

    bf16x8_t qf[2][2];
#pragma unroll
    for (int mi = 0; mi < 2; ++mi)
#pragma unroll
        for (int kc = 0; kc < 2; ++kc) {
            const short* src = (const short*)qkv +
                (rowbase + wq0 + mi * 16 + fr) * QS + hh * HS + kc * 32 + hi4 * 8;
            bf16x8_t v = *(const bf16x8_t*)src;
#pragma unroll
            for (int e = 0; e < 8; ++e) {
                float f = __uint_as_float(((unsigned)(unsigned short)v[e]) << 16) * 0.125f;
                v[e] = (short)(__float_as_uint(f) >> 16);
            }
            qf[mi][kc] = v;
        }

    f32x4_t oa[2][4];
    float m_r[2], l_r[2];
#pragma unroll
    for (int mi = 0; mi < 2; ++mi) {
        m_r[mi] = -INFINITY;
        l_r[mi] = 0.f;
#pragma unroll
        for (int nd = 0; nd < 4; ++nd)
#pragma unroll
            for (int r = 0; r < 4; ++r) oa[mi][nd][r] = 0.f;
    }

    const int skey = tid >> 2;
    const int sd0 = (tid & 3) * 16;
    const int niter = 2 * (qt + 1);

    uint4 ka, kb2, va, vb2;
    {
        const short* kg = (const short*)qkv + (rowbase + skey) * QS + EE + hh * HS + sd0;
        ka = *(const uint4*)kg; kb2 = *(const uint4*)(kg + 8);
        const short* vg = (const short*)qkv + (rowbase + skey) * QS + 2 * EE + hh * HS + sd0;
        va = *(const uint4*)vg; vb2 = *(const uint4*)(vg + 8);
    }

    for (int it = 0; it < niter; ++it) {
        __syncthreads();
        {
            const int rs = (skey & 7) << 4;
            char* kbp = (char*)Ks;
            *(uint4*)(kbp + ((skey * 128 + sd0 * 2) ^ rs)) = ka;
            *(uint4*)(kbp + ((skey * 128 + sd0 * 2 + 16) ^ rs)) = kb2;

            char* vbp = (char*)Vt;
            const short* vs0 = (const short*)&va;
#pragma unroll
            for (int e = 0; e < 8; ++e) {
                int dd = sd0 + e;
                *(short*)(vbp + ((dd * 128 + skey * 2) ^ ((dd & 7) << 4))) = vs0[e];
            }
            const short* vs1 = (const short*)&vb2;
#pragma unroll
            for (int e = 0; e < 8; ++e) {
                int dd = sd0 + 8 + e;
                *(short*)(vbp + ((dd * 128 + skey * 2) ^ ((dd & 7) << 4))) = vs1[e];
            }
        }
        __syncthreads();

        if (it + 1 < niter) {
            const int kvn = (it + 1) * KVB;
            const short* kg = (const short*)qkv + (rowbase + kvn + skey) * QS + EE + hh * HS + sd0;
            ka = *(const uint4*)kg; kb2 = *(const uint4*)(kg + 8);
            const short* vg = (const short*)qkv + (rowbase + kvn + skey) * QS + 2 * EE + hh * HS + sd0;
            va = *(const uint4*)vg; vb2 = *(const uint4*)(vg + 8);
        }

        const int kv0 = it * KVB;

        f32x4_t sa[2][4];
#pragma unroll
        for (int mi = 0; mi < 2; ++mi)
#pragma unroll
            for (int ni = 0; ni < 4; ++ni)
#pragma unroll
                for (int r = 0; r < 4; ++r) sa[mi][ni][r] = 0.f;
#pragma unroll
        for (int kc = 0; kc < 2; ++kc) {
            bf16x8_t kf[4];
#pragma unroll
            for (int ni = 0; ni < 4; ++ni) {
                int krow = ni * 16 + fr;
                kf[ni] = *(const bf16x8_t*)((char*)Ks +
                    ((krow * 128 + (kc * 32 + hi4 * 8) * 2) ^ ((krow & 7) << 4)));
            }
#pragma unroll
            for (int mi = 0; mi < 2; ++mi)
#pragma unroll
                for (int ni = 0; ni < 4; ++ni)
                    sa[mi][ni] = __builtin_amdgcn_mfma_f32_16x16x32_bf16(kf[ni], qf[mi][kc], sa[mi][ni], 0, 0, 0);
        }

        if (kv0 + KVB - 1 > wq0) {
#pragma unroll
            for (int mi = 0; mi < 2; ++mi) {
                int qrow = wq0 + mi * 16 + fr;
#pragma unroll
                for (int ni = 0; ni < 4; ++ni)
#pragma unroll
                    for (int r = 0; r < 4; ++r) {
                        int key = kv0 + ni * 16 + hi4 * 4 + r;
                        if (key > qrow) sa[mi][ni][r] = -1e30f;
                    }
            }
        }

        char* Pw = (char*)Pl + wave * 4096;
#pragma unroll
        for (int mi = 0; mi < 2; ++mi) {
            float mx = sa[mi][0][0];
#pragma unroll
            for (int ni = 0; ni < 4; ++ni)
#pragma unroll
                for (int r = 0; r < 4; ++r) mx = fmaxf(mx, sa[mi][ni][r]);
            mx = fmaxf(mx, __shfl_xor(mx, 16));
            mx = fmaxf(mx, __shfl_xor(mx, 32));
            float mnew = fmaxf(m_r[mi], mx);
            float al = __expf(m_r[mi] - mnew);
            m_r[mi] = mnew;
            float ps = 0.f;
#pragma unroll
            for (int ni = 0; ni < 4; ++ni) {
#pragma unroll
                for (int r = 0; r < 4; ++r) {
                    float p = __expf(sa[mi][ni][r] - mnew);
                    sa[mi][ni][r] = p;
                    ps += p;
                }
                uint2 pw;
                pw.x = pk2bf(sa[mi][ni][0], sa[mi][ni][1]);
                pw.y = pk2bf(sa[mi][ni][2], sa[mi][ni][3]);
                int prow = mi * 16 + fr;
                int cb = ni * 32 + hi4 * 8;
                *(uint2*)(Pw + ((prow * 128 + cb) ^ ((prow & 7) << 4))) = pw;
            }
            ps += __shfl_xor(ps, 16);
            ps += __shfl_xor(ps, 32);
            l_r[mi] = l_r[mi] * al + ps;
#pragma unroll
            for (int r = 0; r < 4; ++r) {
                float a_r = __shfl(al, hi4 * 4 + r);
#pragma unroll
                for (int nd = 0; nd < 4; ++nd) oa[mi][nd][r] *= a_r;
            }
        }

#pragma unroll
        for (int kc = 0; kc < 2; ++kc) {
            bf16x8_t pf[2], vf[4];
#pragma unroll
            for (int mi = 0; mi < 2; ++mi) {
                int prow = mi * 16 + fr;
                pf[mi] = *(const bf16x8_t*)(Pw +
                    ((prow * 128 + (kc * 32 + hi4 * 8) * 2) ^ ((prow & 7) << 4)));
            }
#pragma unroll
            for (int nd = 0; nd < 4; ++nd) {
                int vrow = nd * 16 + fr;
                vf[nd] = *(const bf16x8_t*)((char*)Vt +
                    ((vrow * 128 + (kc * 32 + hi4 * 8) * 2) ^ ((vrow & 7) << 4)));
            }
#pragma unroll
            for (int mi = 0; mi < 2; ++mi)
#pragma unroll
                for (int nd = 0; nd < 4; ++nd)
                    oa[mi][nd] = __builtin_amdgcn_mfma_f32_16x16x32_bf16(pf[mi], vf[nd], oa[mi][nd], 0, 0, 0);
        }
    }

#pragma unroll
    for (int mi = 0; mi < 2; ++mi)
#pragma unroll
        for (int r = 0; r < 4; ++r) {
            float lr = __shfl(l_r[mi], hi4 * 4 + r);
            float inv = 1.0f / lr;
            int row = wq0 + mi * 16 + hi4 * 4 + r;
            __hip_bfloat16* orow = o + (rowbase + row) * EE + hh * HS;
#pragma unroll
            for (int nd = 0; nd < 4; ++nd)
                orow[nd * 16 + fr] = __float2bfloat16(oa[mi][nd][r] * inv);
        }
}

// ---------------- loss: merge per-block LSE partials ----------------
__global__ __launch_bounds__(256) void rowloss2_k(const float2* __restrict__ partials,
                                                  const float* __restrict__ logits,
                                                  const int* __restrict__ targets,
                                                  float* __restrict__ rowloss, int ntn) {
    __shared__ float red[4];
    int row = blockIdx.x;
    int tid = threadIdx.x;
    float m = -INFINITY, l = 0.f;
    if (tid < ntn) {
        float2 p = partials[(size_t)row * ntn + tid];
        m = p.x; l = p.y;
    }
    float mg = block_max256(m, red);
    float s = (tid < ntn) ? l * __expf(m - mg) : 0.f;
    s = block_sum256(s, red);
    if (tid == 0)
        rowloss[row] = mg + logf(s) - logits[(size_t)row * VV + targets[row]];
}

__global__ __launch_bounds__(256) void loss_final_k(const float* __restrict__ rowloss,
                                                    float* __restrict__ out) {
    __shared__ float red[4];
    float s = 0.f;
    for (int i = threadIdx.x; i < MROWS; i += 256) s += rowloss[i];
    s = block_sum256(s, red);
    if (threadIdx.x == 0) out[0] = s * (1.0f / MROWS);
}

// ---------------- launcher ----------------
extern "C" void kernel_launch(void* const* d_in, const int* in_sizes, int n_in,
                              void* d_out, int out_size, void* d_ws, size_t ws_size,
                              hipStream_t stream) {
    const int* idx      = (const int*)d_in[0];
    const int* targets  = (const int*)d_in[1];
    const float* tok    = (const float*)d_in[2];
    const float* pos    = (const float*)d_in[3];
    const float* Wq     = (const float*)d_in[4];
    const float* Wk     = (const float*)d_in[5];
    const float* Wv     = (const float*)d_in[6];
    const float* Wp     = (const float*)d_in[7];
    const float* bp     = (const float*)d_in[8];
    const float* W1     = (const float*)d_in[9];
    const float* b1     = (const float*)d_in[10];
    const float* W2     = (const float*)d_in[11];
    const float* b2     = (const float*)d_in[12];
    const float* ln1_g  = (const float*)d_in[13];
    const float* ln1_b  = (const float*)d_in[14];
    const float* ln2_g  = (const float*)d_in[15];
    const float* ln2_b  = (const float*)d_in[16];
    const float* lnf_g  = (const float*)d_in[17];
    const float* lnf_b  = (const float*)d_in[18];
    const float* Wlm    = (const float*)d_in[19];
    const float* blm    = (const float*)d_in[20];

    float* out = (float*)d_out;

    // ---- workspace carve ----
    char* w = (char*)d_ws;
    float* x = (float*)w;                             w += (size_t)MROWS * EE * 4;
    __hip_bfloat16* hbf = (__hip_bfloat16*)w;         w += (size_t)MROWS * EE * 2;
    __hip_bfloat16* qkv = (__hip_bfloat16*)w;         w += (size_t)MROWS * QS * 2;
    __hip_bfloat16* obf = (__hip_bfloat16*)w;         w += (size_t)MROWS * EE * 2;
    __hip_bfloat16* ff1 = (__hip_bfloat16*)w;         w += (size_t)MROWS * FFD * 2;
    float2* partials = (float2*)ff1;                  // aliases ff1: dead by LM-head time
    __hip_bfloat16* wlmT = (__hip_bfloat16*)w;        w += (size_t)VV * EE * 2;
    float* rowloss = (float*)w;                       w += (size_t)MROWS * 4 + 256;
    __hip_bfloat16* wbase = (__hip_bfloat16*)w;       // layer weights from here

    const size_t base_used = (size_t)(w - (char*)d_ws);
    const size_t per_layer_w = ((size_t)QS * EE + (size_t)EE * EE +
                                (size_t)FFD * EE + (size_t)EE * FFD) * 2;
    const bool hoist = ws_size >= base_used + per_layer_w * LAYERS;
    const int nlw = hoist ? LAYERS : 1;

    __hip_bfloat16* qkvwT = wbase;
    __hip_bfloat16* wpT   = qkvwT + (size_t)nlw * QS * EE;
    __hip_bfloat16* w1T   = wpT   + (size_t)nlw * EE * EE;
    __hip_bfloat16* w2T   = w1T   + (size_t)nlw * FFD * EE;

    dim3 blk(256);

    embed4_k<<<MROWS / 4, blk, 0, stream>>>(idx, tok, pos, x);

    if (hoist) {
        tconv_b_k<<<dim3(EE / 32, EE / 32, LAYERS), blk, 0, stream>>>(
            Wq, qkvwT, EE, EE, (size_t)EE * EE, (size_t)QS * EE);
        tconv_b_k<<<dim3(EE / 32, EE / 32, LAYERS), blk, 0, stream>>>(
            Wk, qkvwT + (size_t)EE * EE, EE, EE, (size_t)EE * EE, (size_t)QS * EE);
        tconv_b_k<<<dim3(EE / 32, EE / 32, LAYERS), blk, 0, stream>>>(
            Wv, qkvwT + (size_t)2 * EE * EE, EE, EE, (size_t)EE * EE, (size_t)QS * EE);
        tconv_b_k<<<dim3(EE / 32, EE / 32, LAYERS), blk, 0, stream>>>(
            Wp, wpT, EE, EE, (size_t)EE * EE, (size_t)EE * EE);
        tconv_b_k<<<dim3(FFD / 32, EE / 32, LAYERS), blk, 0, stream>>>(
            W1, w1T, EE, FFD, (size_t)EE * FFD, (size_t)FFD * EE);
        tconv_b_k<<<dim3(EE / 32, FFD / 32, LAYERS), blk, 0, stream>>>(
            W2, w2T, FFD, EE, (size_t)FFD * EE, (size_t)EE * FFD);
    }
    tconv_b_k<<<dim3(VV / 32, EE / 32, 1), blk, 0, stream>>>(Wlm, wlmT, EE, VV, 0, 0);

    for (int l = 0; l < LAYERS; ++l) {
        __hip_bfloat16* qkvwT_l = qkvwT + (hoist ? (size_t)l * QS * EE : 0);
        __hip_bfloat16* wpT_l   = wpT   + (hoist ? (size_t)l * EE * EE : 0);
        __hip_bfloat16* w1T_l   = w1T   + (hoist ? (size_t)l * FFD * EE : 0);
        __hip_bfloat16* w2T_l   = w2T   + (hoist ? (size_t)l * EE * FFD : 0);
        if (!hoist) {
            tconv_b_k<<<dim3(EE / 32, EE / 32, 1), blk, 0, stream>>>(
                Wq + (size_t)l * EE * EE, qkvwT_l, EE, EE, 0, 0);
            tconv_b_k<<<dim3(EE / 32, EE / 32, 1), blk, 0, stream>>>(
                Wk + (size_t)l * EE * EE, qkvwT_l + (size_t)EE * EE, EE, EE, 0, 0);
            tconv_b_k<<<dim3(EE / 32, EE / 32, 1), blk, 0, stream>>>(
                Wv + (size_t)l * EE * EE, qkvwT_l + (size_t)2 * EE * EE, EE, EE, 0, 0);
            tconv_b_k<<<dim3(EE / 32, EE / 32, 1), blk, 0, stream>>>(
                Wp + (size_t)l * EE * EE, wpT_l, EE, EE, 0, 0);
            tconv_b_k<<<dim3(FFD / 32, EE / 32, 1), blk, 0, stream>>>(
                W1 + (size_t)l * EE * FFD, w1T_l, EE, FFD, 0, 0);
            tconv_b_k<<<dim3(EE / 32, FFD / 32, 1), blk, 0, stream>>>(
                W2 + (size_t)l * FFD * EE, w2T_l, FFD, EE, 0, 0);
        }

        ln4_k<<<MROWS / 4, blk, 0, stream>>>(x, ln1_g + l * EE, ln1_b + l * EE, hbf);
        mgemm_k<false, false, false, true, 4><<<dim3((MROWS / 128) * (QS / 128)), blk, 0, stream>>>(
            hbf, qkvwT_l, nullptr, qkv, MROWS, QS, EE, QS / 128);
        fattn_k<<<dim3(BB * HH, TT / QBLK), blk, 0, stream>>>(qkv, obf);
        // proj: occupancy-starved shape -> 64-row tiles (grid 384)
        mgemm_k<true, false, true, false, 2><<<dim3((MROWS / 64) * (EE / 128)), blk, 0, stream>>>(
            obf, wpT_l, bp + l * EE, x, MROWS, EE, EE, EE / 128);
        ln4_k<<<MROWS / 4, blk, 0, stream>>>(x, ln2_g + l * EE, ln2_b + l * EE, hbf);
        mgemm_k<true, true, false, true, 4><<<dim3((MROWS / 128) * (FFD / 128)), blk, 0, stream>>>(
            hbf, w1T_l, b1 + l * FFD, ff1, MROWS, FFD, EE, FFD / 128);
        // FF2: occupancy-starved shape -> 64-row tiles (grid 384)
        mgemm_k<true, false, true, false, 2><<<dim3((MROWS / 64) * (EE / 128)), blk, 0, stream>>>(
            ff1, w2T_l, b2 + l * EE, x, MROWS, EE, FFD, EE / 128);
    }

    ln4_k<<<MROWS / 4, blk, 0, stream>>>(x, lnf_g, lnf_b, hbf);
    // LM head: 256x256 8-phase (proven) + fused LSE partials
    mgemm256_k<true, false, false, true><<<dim3((MROWS / 256) * (VV / 256)), dim3(512), 0, stream>>>(
        hbf, wlmT, blm, out, MROWS, VV, EE, VV / 256, NPART, partials);

    rowloss2_k<<<MROWS, blk, 0, stream>>>(partials, out, targets, rowloss, NPART);
    loss_final_k<<<1, blk, 0, stream>>>(rowloss, out + (size_t)MROWS * VV);
}

// Round 9
// 1547.097 us; speedup vs baseline: 10.0890x; 1.0434x over previous
//
#include <hip/hip_runtime.h>
#include <hip/hip_bf16.h>
#include <math.h>

#define LAYERS 6
#define BB 4
#define TT 1024
#define EE 768
#define HH 12
#define HS 64
#define VV 32000
#define FFD 3072
#define MROWS (BB * TT)   // 4096
#define QS (3 * EE)       // 2304, fused qkv row stride
#define KVB 64
#define QBLK 128
#define NPART (VV / 256)  // 125 LSE partial blocks per row

typedef __attribute__((ext_vector_type(8))) short bf16x8_t;
typedef __attribute__((ext_vector_type(4))) float f32x4_t;

// ---------------- helpers ----------------
__device__ __forceinline__ float wave_sum(float v) {
#pragma unroll
    for (int o = 32; o > 0; o >>= 1) v += __shfl_xor(v, o);
    return v;
}
__device__ __forceinline__ float wave_max(float v) {
#pragma unroll
    for (int o = 32; o > 0; o >>= 1) v = fmaxf(v, __shfl_xor(v, o));
    return v;
}
__device__ __forceinline__ float block_sum256(float v, float* red) {
    v = wave_sum(v);
    int tid = threadIdx.x;
    if ((tid & 63) == 0) red[tid >> 6] = v;
    __syncthreads();
    float r = red[0] + red[1] + red[2] + red[3];
    __syncthreads();
    return r;
}
__device__ __forceinline__ float block_max256(float v, float* red) {
    v = wave_max(v);
    int tid = threadIdx.x;
    if ((tid & 63) == 0) red[tid >> 6] = v;
    __syncthreads();
    float r = fmaxf(fmaxf(red[0], red[1]), fmaxf(red[2], red[3]));
    __syncthreads();
    return r;
}

__device__ __forceinline__ void gload_lds16(const void* g, void* l) {
    __builtin_amdgcn_global_load_lds((const __attribute__((address_space(1))) void*)g,
                                     (__attribute__((address_space(3))) void*)l, 16, 0, 0);
}

// pack two f32 -> u32 of 2 bf16 (lo at low address)
__device__ __forceinline__ unsigned pk2bf(float lo, float hi) {
    __hip_bfloat162 h2 = __float22bfloat162_rn(make_float2(lo, hi));
    return *reinterpret_cast<unsigned*>(&h2);
}

// ---------------- embedding: 4 rows/block, wave per row, float4 ----------------
__global__ __launch_bounds__(256) void embed4_k(const int* __restrict__ idx,
                                                const float* __restrict__ tok,
                                                const float* __restrict__ pos,
                                                float* __restrict__ x) {
    int row = blockIdx.x * 4 + (threadIdx.x >> 6);
    int lane = threadIdx.x & 63;
    int t = row & (TT - 1);
    int token = idx[row];
    const float4* te = (const float4*)(tok + (size_t)token * EE);
    const float4* pe = (const float4*)(pos + (size_t)t * EE);
    float4* xr = (float4*)(x + (size_t)row * EE);
#pragma unroll
    for (int j = 0; j < 3; ++j) {
        int i = j * 64 + lane;
        float4 a = te[i], b = pe[i];
        xr[i] = make_float4(a.x + b.x, a.y + b.y, a.z + b.z, a.w + b.w);
    }
}

// ---------------- LayerNorm: wave per row, register-resident, fp32->bf16 -------
__global__ __launch_bounds__(256) void ln4_k(const float* __restrict__ x,
                                             const float* __restrict__ g,
                                             const float* __restrict__ b,
                                             __hip_bfloat16* __restrict__ out) {
    int row = blockIdx.x * 4 + (threadIdx.x >> 6);
    int lane = threadIdx.x & 63;
    const float4* xr = (const float4*)(x + (size_t)row * EE);
    float4 v[3];
    float s = 0.f;
#pragma unroll
    for (int j = 0; j < 3; ++j) {
        v[j] = xr[j * 64 + lane];
        s += v[j].x + v[j].y + v[j].z + v[j].w;
    }
    s = wave_sum(s);
    float m = s * (1.0f / EE);
    float vs = 0.f;
#pragma unroll
    for (int j = 0; j < 3; ++j) {
        float d0 = v[j].x - m, d1 = v[j].y - m, d2 = v[j].z - m, d3 = v[j].w - m;
        vs += d0 * d0 + d1 * d1 + d2 * d2 + d3 * d3;
    }
    vs = wave_sum(vs);
    float rstd = rsqrtf(vs * (1.0f / EE) + 1e-5f);
    const float4* g4 = (const float4*)g;
    const float4* b4 = (const float4*)b;
    uint2* orow = (uint2*)(out + (size_t)row * EE);
#pragma unroll
    for (int j = 0; j < 3; ++j) {
        int i = j * 64 + lane;
        float4 gg = g4[i], bb = b4[i];
        float n0 = (v[j].x - m) * rstd * gg.x + bb.x;
        float n1 = (v[j].y - m) * rstd * gg.y + bb.y;
        float n2 = (v[j].z - m) * rstd * gg.z + bb.z;
        float n3 = (v[j].w - m) * rstd * gg.w + bb.w;
        orow[i] = make_uint2(pk2bf(n0, n1), pk2bf(n2, n3));
    }
}

// ---------------- batched transpose-convert: W fp32 [R,C] -> WT bf16 [C,R] ------
__global__ __launch_bounds__(256) void tconv_b_k(const float* __restrict__ W,
                                                 __hip_bfloat16* __restrict__ WT,
                                                 int R, int C,
                                                 size_t wstride, size_t tstride) {
    __shared__ float t[32][33];
    const float* Wl = W + (size_t)blockIdx.z * wstride;
    __hip_bfloat16* Tl = WT + (size_t)blockIdx.z * tstride;
    int c0 = blockIdx.x * 32, r0 = blockIdx.y * 32;
    int tx = threadIdx.x & 31, ty = threadIdx.x >> 5;
#pragma unroll
    for (int i = 0; i < 4; ++i)
        t[ty + 8 * i][tx] = Wl[(size_t)(r0 + ty + 8 * i) * C + c0 + tx];
    __syncthreads();
#pragma unroll
    for (int i = 0; i < 4; ++i)
        Tl[(size_t)(c0 + ty + 8 * i) * R + r0 + tx] = __float2bfloat16(t[tx][ty + 8 * i]);
}

// ---------------- MFMA GEMM (m97 structure, MI*32 x 128 tile, BK=32) -----------
template <bool BIAS, bool RELU, bool ACCUM, bool OBF16, int MI>
__global__ __launch_bounds__(256) void mgemm_k(const __hip_bfloat16* __restrict__ A,
                                               const __hip_bfloat16* __restrict__ BT,
                                               const float* __restrict__ bias,
                                               void* __restrict__ Cv,
                                               int M, int N, int K, int ntn) {
    __shared__ __align__(16) short As[MI * 32 * 32];
    __shared__ __align__(16) short Bs[128 * 32];

    int nwg = gridDim.x;
    int bid = blockIdx.x;
    int cpx = nwg >> 3;
    int swz = (bid & 7) * cpx + (bid >> 3);
    int tm = swz / ntn, tn = swz - tm * ntn;
    int m0 = tm * (MI * 32), n0 = tn * 128;

    int tid = threadIdx.x;
    int lane = tid & 63;
    int wave = tid >> 6;
    int wr = wave >> 1, wc = wave & 1;

    f32x4_t acc[MI][4];
#pragma unroll
    for (int i = 0; i < MI; ++i)
#pragma unroll
        for (int j = 0; j < 4; ++j)
#pragma unroll
            for (int r = 0; r < 4; ++r) acc[i][j][r] = 0.f;

    const short* Ag = (const short*)A;
    const short* Bg = (const short*)BT;
    const int arow0 = tid >> 2;
    const int arow1 = (tid + 256) >> 2;
    const int acol = (tid & 3) * 8;

    const int fr = lane & 15;
    const int kg = (lane >> 4) * 8;

    for (int k0 = 0; k0 < K; k0 += 32) {
        gload_lds16(Ag + (size_t)(m0 + arow0) * K + k0 + acol, &As[tid * 8]);
        if (MI == 4)
            gload_lds16(Ag + (size_t)(m0 + arow1) * K + k0 + acol, &As[(tid + 256) * 8]);
        gload_lds16(Bg + (size_t)(n0 + arow0) * K + k0 + acol, &Bs[tid * 8]);
        gload_lds16(Bg + (size_t)(n0 + arow1) * K + k0 + acol, &Bs[(tid + 256) * 8]);
        __syncthreads();

        bf16x8_t af[MI], bq[4];
#pragma unroll
        for (int mi = 0; mi < MI; ++mi)
            af[mi] = *(const bf16x8_t*)&As[(wr * (MI * 16) + mi * 16 + fr) * 32 + kg];
#pragma unroll
        for (int ni = 0; ni < 4; ++ni)
            bq[ni] = *(const bf16x8_t*)&Bs[(wc * 64 + ni * 16 + fr) * 32 + kg];
#pragma unroll
        for (int mi = 0; mi < MI; ++mi)
#pragma unroll
            for (int ni = 0; ni < 4; ++ni)
                acc[mi][ni] = __builtin_amdgcn_mfma_f32_16x16x32_bf16(af[mi], bq[ni], acc[mi][ni], 0, 0, 0);
        __syncthreads();
    }

    float bvec[4];
    if (BIAS) {
#pragma unroll
        for (int ni = 0; ni < 4; ++ni) bvec[ni] = bias[n0 + wc * 64 + ni * 16 + fr];
    }
    const int rbase = m0 + wr * (MI * 16) + (lane >> 4) * 4;
    const int cbase = n0 + wc * 64 + fr;
#pragma unroll
    for (int mi = 0; mi < MI; ++mi) {
#pragma unroll
        for (int ni = 0; ni < 4; ++ni) {
#pragma unroll
            for (int r = 0; r < 4; ++r) {
                int row = rbase + mi * 16 + r;
                int col = cbase + ni * 16;
                float v = acc[mi][ni][r];
                if (BIAS) v += bvec[ni];
                if (RELU) v = fmaxf(v, 0.f);
                size_t off = (size_t)row * N + col;
                if (OBF16) {
                    ((__hip_bfloat16*)Cv)[off] = __float2bfloat16(v);
                } else {
                    float* Cf = (float*)Cv;
                    if (ACCUM) Cf[off] += v; else Cf[off] = v;
                }
            }
        }
    }
}

// ---------------- 256x256 8-phase MFMA GEMM — LM head (NT logits stores) -------
__device__ __forceinline__ bf16x8_t ldsrd256(const short* base, int row, int colb) {
    return *(const bf16x8_t*)((const char*)base + ((row << 7) + (colb ^ ((row & 7) << 4))));
}

template <bool BIAS, bool RELU, bool OBF16, bool LSE>
__global__ __launch_bounds__(512, 2) void mgemm256_k(const __hip_bfloat16* __restrict__ A,
                                                     const __hip_bfloat16* __restrict__ BT,
                                                     const float* __restrict__ bias,
                                                     void* __restrict__ Cv,
                                                     int M, int N, int K,
                                                     int ntn, int npart,
                                                     float2* __restrict__ partials) {
    __shared__ __align__(16) short lds[2][2][2][8192];   // [buf][A/B][half][128*64]

    const int nwg = gridDim.x;
    const int bid = blockIdx.x;
    const int cpx = nwg >> 3;
    const int swz = (bid & 7) * cpx + (bid >> 3);
    const int tm = swz / ntn, tn = swz - tm * ntn;
    const int m0 = tm * 256, n0 = tn * 256;

    const int tid = threadIdx.x;
    const int lane = tid & 63;
    const int wave = tid >> 6;
    const int wm = wave >> 2;       // 0..1
    const int wn = wave & 3;        // 0..3
    const int fr = lane & 15;
    const int hi4 = lane >> 4;

    const short* Ag = (const short*)A;
    const short* Bg = (const short*)BT;
    const int nt = K >> 6;          // 12

    auto stage_half = [&](const short* g, int grow0, int k0, short* lbase) {
#pragma unroll
        for (int sub = 0; sub < 2; ++sub) {
            int d = sub * 8192 + tid * 16;
            int row = d >> 7;
            int cb = d & 127;
            int col = (cb ^ ((row & 7) << 4)) >> 1;
            gload_lds16(g + (size_t)(grow0 + row) * K + k0 + col, (char*)lbase + d);
        }
    };

    f32x4_t acc[2][2][4][2];
#pragma unroll
    for (int ah = 0; ah < 2; ++ah)
#pragma unroll
        for (int s = 0; s < 2; ++s)
#pragma unroll
            for (int mi = 0; mi < 4; ++mi)
#pragma unroll
                for (int ni = 0; ni < 2; ++ni)
#pragma unroll
                    for (int r = 0; r < 4; ++r) acc[ah][s][mi][ni][r] = 0.f;

    stage_half(Ag, m0 + 0,   0,  &lds[0][0][0][0]);
    stage_half(Bg, n0 + 0,   0,  &lds[0][1][0][0]);
    stage_half(Ag, m0 + 128, 0,  &lds[0][0][1][0]);
    stage_half(Bg, n0 + 128, 0,  &lds[0][1][1][0]);
    stage_half(Ag, m0 + 0,   64, &lds[1][0][0][0]);
    stage_half(Bg, n0 + 0,   64, &lds[1][1][0][0]);
    asm volatile("s_waitcnt vmcnt(4)" ::: "memory");
    __builtin_amdgcn_s_barrier();

    for (int t = 0; t < nt; ++t) {
        const int c = t & 1, o = c ^ 1;
        bf16x8_t a[4][2];
#pragma unroll
        for (int p = 0; p < 4; ++p) {
            const int ah = p >> 1, s = p & 1;
            if (s == 0) {
#pragma unroll
                for (int mi = 0; mi < 4; ++mi)
#pragma unroll
                    for (int kk = 0; kk < 2; ++kk)
                        a[mi][kk] = ldsrd256(&lds[c][0][ah][0],
                                             wm * 64 + mi * 16 + fr, kk * 64 + hi4 * 16);
            }
            bf16x8_t b[2][2];
#pragma unroll
            for (int ni = 0; ni < 2; ++ni)
#pragma unroll
                for (int kk = 0; kk < 2; ++kk)
                    b[ni][kk] = ldsrd256(&lds[c][1][s][0],
                                         wn * 32 + ni * 16 + fr, kk * 64 + hi4 * 16);
            if (p == 0 && t + 1 < nt) stage_half(Ag, m0 + 128, (t + 1) * 64, &lds[o][0][1][0]);
            if (p == 1 && t + 1 < nt) stage_half(Bg, n0 + 128, (t + 1) * 64, &lds[o][1][1][0]);
            if (p == 2 && t + 2 < nt) stage_half(Ag, m0 + 0,   (t + 2) * 64, &lds[c][0][0][0]);
            if (p == 3 && t + 2 < nt) stage_half(Bg, n0 + 0,   (t + 2) * 64, &lds[c][1][0][0]);
            if (p == 3) {
                if (t < nt - 2)       asm volatile("s_waitcnt vmcnt(4)" ::: "memory");
                else if (t == nt - 2) asm volatile("s_waitcnt vmcnt(0)" ::: "memory");
            }
            __builtin_amdgcn_s_barrier();
            asm volatile("s_waitcnt lgkmcnt(0)" ::: "memory");
            __builtin_amdgcn_sched_barrier(0);
            __builtin_amdgcn_s_setprio(1);
#pragma unroll
            for (int mi = 0; mi < 4; ++mi)
#pragma unroll
                for (int ni = 0; ni < 2; ++ni)
#pragma unroll
                    for (int kk = 0; kk < 2; ++kk)
                        acc[ah][s][mi][ni] = __builtin_amdgcn_mfma_f32_16x16x32_bf16(
                            a[mi][kk], b[ni][kk], acc[ah][s][mi][ni], 0, 0, 0);
            __builtin_amdgcn_s_setprio(0);
            __builtin_amdgcn_s_barrier();
        }
    }

    float bv[2][2];
    if (BIAS) {
#pragma unroll
        for (int s = 0; s < 2; ++s)
#pragma unroll
            for (int ni = 0; ni < 2; ++ni)
                bv[s][ni] = bias[n0 + s * 128 + wn * 32 + ni * 16 + fr];
    }
    float2* red = (float2*)&lds[0][0][0][0];
#pragma unroll
    for (int ah = 0; ah < 2; ++ah) {
#pragma unroll
        for (int mi = 0; mi < 4; ++mi) {
#pragma unroll
            for (int r = 0; r < 4; ++r) {
                const int rb = ah * 128 + wm * 64 + mi * 16 + hi4 * 4 + r;
                const size_t grow = (size_t)(m0 + rb);
                float v[2][2];
#pragma unroll
                for (int s = 0; s < 2; ++s)
#pragma unroll
                    for (int ni = 0; ni < 2; ++ni) {
                        float vv = acc[ah][s][mi][ni][r];
                        if (BIAS) vv += bv[s][ni];
                        if (RELU) vv = fmaxf(vv, 0.f);
                        v[s][ni] = vv;
                        size_t off = grow * N + n0 + s * 128 + wn * 32 + ni * 16 + fr;
                        if (OBF16) ((__hip_bfloat16*)Cv)[off] = __float2bfloat16(vv);
                        else __builtin_nontemporal_store(vv, (float*)Cv + off);  // stream logits past L3
                    }
                if (LSE) {
                    float mx = fmaxf(fmaxf(v[0][0], v[0][1]), fmaxf(v[1][0], v[1][1]));
#pragma unroll
                    for (int off2 = 1; off2 < 16; off2 <<= 1) mx = fmaxf(mx, __shfl_xor(mx, off2));
                    float sm = 0.f;
#pragma unroll
                    for (int s = 0; s < 2; ++s)
#pragma unroll
                        for (int ni = 0; ni < 2; ++ni) sm += __expf(v[s][ni] - mx);
#pragma unroll
                    for (int off2 = 1; off2 < 16; off2 <<= 1) sm += __shfl_xor(sm, off2);
                    if (fr == 0) red[rb * 4 + wn] = make_float2(mx, sm);
                }
            }
        }
    }
    if (LSE) {
        __syncthreads();
        if (tid < 256) {
            float2 p0 = red[tid * 4 + 0], p1 = red[tid * 4 + 1];
            float2 p2 = red[tid * 4 + 2], p3 = red[tid * 4 + 3];
            float M2 = fmaxf(fmaxf(p0.x, p1.x), fmaxf(p2.x, p3.x));
            float L2 = p0.y * __expf(p0.x - M2) + p1.y * __expf(p1.x - M2) +
                       p2.y * __expf(p2.x - M2) + p3.y * __expf(p3.x - M2);
            partials[(size_t)(m0 + tid) * npart + tn] = make_float2(M2, L2);
        }
    }
}

// ---------------- MFMA flash attention: swapped QK^T + T14 + T13 + T5 ----------
__global__ __launch_bounds__(256) void fattn_k(const __hip_bfloat16* __restrict__ qkv,
                                               __hip_bfloat16* __restrict__ o) {
    __shared__ short Ks[KVB * HS];
    __shared__ short Vt[HS * KVB];
    __shared__ short Pl[4 * 32 * KVB];

    const int bh = blockIdx.x;
    const int hh = bh % HH;
    const int bI = bh / HH;
    const int qt = (TT / QBLK - 1) - blockIdx.y;   // heavy tiles first
    const int q0 = qt * QBLK;

    const int tid = threadIdx.x;
    const int lane = tid & 63;
    const int wave = tid >> 6;
    const int fr = lane & 15;
    const int hi4 = lane >> 4;

    const size_t rowbase = (size_t)bI * TT;
    const int wq0 = q0 + wave * 32;

    bf16x8_t qf[2][2];
#pragma unroll
    for (int mi = 0; mi < 2; ++mi)
#pragma unroll
        for (int kc = 0; kc < 2; ++kc) {
            const short* src = (const short*)qkv +
                (rowbase + wq0 + mi * 16 + fr) * QS + hh * HS + kc * 32 + hi4 * 8;
            bf16x8_t v = *(const bf16x8_t*)src;
#pragma unroll
            for (int e = 0; e < 8; ++e) {
                float f = __uint_as_float(((unsigned)(unsigned short)v[e]) << 16) * 0.125f;
                v[e] = (short)(__float_as_uint(f) >> 16);
            }
            qf[mi][kc] = v;
        }

    f32x4_t oa[2][4];
    float m_r[2], l_r[2];
#pragma unroll
    for (int mi = 0; mi < 2; ++mi) {
        m_r[mi] = -INFINITY;
        l_r[mi] = 0.f;
#pragma unroll
        for (int nd = 0; nd < 4; ++nd)
#pragma unroll
            for (int r = 0; r < 4; ++r) oa[mi][nd][r] = 0.f;
    }

    const int skey = tid >> 2;
    const int sd0 = (tid & 3) * 16;
    const int niter = 2 * (qt + 1);

    uint4 ka, kb2, va, vb2;
    {
        const short* kg = (const short*)qkv + (rowbase + skey) * QS + EE + hh * HS + sd0;
        ka = *(const uint4*)kg; kb2 = *(const uint4*)(kg + 8);
        const short* vg = (const short*)qkv + (rowbase + skey) * QS + 2 * EE + hh * HS + sd0;
        va = *(const uint4*)vg; vb2 = *(const uint4*)(vg + 8);
    }

    for (int it = 0; it < niter; ++it) {
        __syncthreads();
        {
            const int rs = (skey & 7) << 4;
            char* kbp = (char*)Ks;
            *(uint4*)(kbp + ((skey * 128 + sd0 * 2) ^ rs)) = ka;
            *(uint4*)(kbp + ((skey * 128 + sd0 * 2 + 16) ^ rs)) = kb2;

            char* vbp = (char*)Vt;
            const short* vs0 = (const short*)&va;
#pragma unroll
            for (int e = 0; e < 8; ++e) {
                int dd = sd0 + e;
                *(short*)(vbp + ((dd * 128 + skey * 2) ^ ((dd & 7) << 4))) = vs0[e];
            }
            const short* vs1 = (const short*)&vb2;
#pragma unroll
            for (int e = 0; e < 8; ++e) {
                int dd = sd0 + 8 + e;
                *(short*)(vbp + ((dd * 128 + skey * 2) ^ ((dd & 7) << 4))) = vs1[e];
            }
        }
        __syncthreads();

        if (it + 1 < niter) {
            const int kvn = (it + 1) * KVB;
            const short* kg = (const short*)qkv + (rowbase + kvn + skey) * QS + EE + hh * HS + sd0;
            ka = *(const uint4*)kg; kb2 = *(const uint4*)(kg + 8);
            const short* vg = (const short*)qkv + (rowbase + kvn + skey) * QS + 2 * EE + hh * HS + sd0;
            va = *(const uint4*)vg; vb2 = *(const uint4*)(vg + 8);
        }

        const int kv0 = it * KVB;

        f32x4_t sa[2][4];
#pragma unroll
        for (int mi = 0; mi < 2; ++mi)
#pragma unroll
            for (int ni = 0; ni < 4; ++ni)
#pragma unroll
                for (int r = 0; r < 4; ++r) sa[mi][ni][r] = 0.f;
        __builtin_amdgcn_s_setprio(1);
#pragma unroll
        for (int kc = 0; kc < 2; ++kc) {
            bf16x8_t kf[4];
#pragma unroll
            for (int ni = 0; ni < 4; ++ni) {
                int krow = ni * 16 + fr;
                kf[ni] = *(const bf16x8_t*)((char*)Ks +
                    ((krow * 128 + (kc * 32 + hi4 * 8) * 2) ^ ((krow & 7) << 4)));
            }
#pragma unroll
            for (int mi = 0; mi < 2; ++mi)
#pragma unroll
                for (int ni = 0; ni < 4; ++ni)
                    sa[mi][ni] = __builtin_amdgcn_mfma_f32_16x16x32_bf16(kf[ni], qf[mi][kc], sa[mi][ni], 0, 0, 0);
        }
        __builtin_amdgcn_s_setprio(0);

        if (kv0 + KVB - 1 > wq0) {
#pragma unroll
            for (int mi = 0; mi < 2; ++mi) {
                int qrow = wq0 + mi * 16 + fr;
#pragma unroll
                for (int ni = 0; ni < 4; ++ni)
#pragma unroll
                    for (int r = 0; r < 4; ++r) {
                        int key = kv0 + ni * 16 + hi4 * 4 + r;
                        if (key > qrow) sa[mi][ni][r] = -1e30f;
                    }
            }
        }

        char* Pw = (char*)Pl + wave * 4096;
#pragma unroll
        for (int mi = 0; mi < 2; ++mi) {
            float mx = sa[mi][0][0];
#pragma unroll
            for (int ni = 0; ni < 4; ++ni)
#pragma unroll
                for (int r = 0; r < 4; ++r) mx = fmaxf(mx, sa[mi][ni][r]);
            mx = fmaxf(mx, __shfl_xor(mx, 16));
            mx = fmaxf(mx, __shfl_xor(mx, 32));
            // T13 defer-max: skip rescale while tile max stays within 8 of running max
            if (!__all(mx <= m_r[mi] + 8.0f)) {
                float mnew = fmaxf(m_r[mi], mx);
                float al = __expf(m_r[mi] - mnew);
                m_r[mi] = mnew;
                l_r[mi] *= al;
#pragma unroll
                for (int r = 0; r < 4; ++r) {
                    float a_r = __shfl(al, hi4 * 4 + r);
#pragma unroll
                    for (int nd = 0; nd < 4; ++nd) oa[mi][nd][r] *= a_r;
                }
            }
            float ps = 0.f;
#pragma unroll
            for (int ni = 0; ni < 4; ++ni) {
#pragma unroll
                for (int r = 0; r < 4; ++r) {
                    float p = __expf(sa[mi][ni][r] - m_r[mi]);
                    sa[mi][ni][r] = p;
                    ps += p;
                }
                uint2 pw;
                pw.x = pk2bf(sa[mi][ni][0], sa[mi][ni][1]);
                pw.y = pk2bf(sa[mi][ni][2], sa[mi][ni][3]);
                int prow = mi * 16 + fr;
                int cb = ni * 32 + hi4 * 8;
                *(uint2*)(Pw + ((prow * 128 + cb) ^ ((prow & 7) << 4))) = pw;
            }
            ps += __shfl_xor(ps, 16);
            ps += __shfl_xor(ps, 32);
            l_r[mi] += ps;
        }

        __builtin_amdgcn_s_setprio(1);
#pragma unroll
        for (int kc = 0; kc < 2; ++kc) {
            bf16x8_t pf[2], vf[4];
#pragma unroll
            for (int mi = 0; mi < 2; ++mi) {
                int prow = mi * 16 + fr;
                pf[mi] = *(const bf16x8_t*)(Pw +
                    ((prow * 128 + (kc * 32 + hi4 * 8) * 2) ^ ((prow & 7) << 4)));
            }
#pragma unroll
            for (int nd = 0; nd < 4; ++nd) {
                int vrow = nd * 16 + fr;
                vf[nd] = *(const bf16x8_t*)((char*)Vt +
                    ((vrow * 128 + (kc * 32 + hi4 * 8) * 2) ^ ((vrow & 7) << 4)));
            }
#pragma unroll
            for (int mi = 0; mi < 2; ++mi)
#pragma unroll
                for (int nd = 0; nd < 4; ++nd)
                    oa[mi][nd] = __builtin_amdgcn_mfma_f32_16x16x32_bf16(pf[mi], vf[nd], oa[mi][nd], 0, 0, 0);
        }
        __builtin_amdgcn_s_setprio(0);
    }

#pragma unroll
    for (int mi = 0; mi < 2; ++mi)
#pragma unroll
        for (int r = 0; r < 4; ++r) {
            float lr = __shfl(l_r[mi], hi4 * 4 + r);
            float inv = 1.0f / lr;
            int row = wq0 + mi * 16 + hi4 * 4 + r;
            __hip_bfloat16* orow = o + (rowbase + row) * EE + hh * HS;
#pragma unroll
            for (int nd = 0; nd < 4; ++nd)
                orow[nd * 16 + fr] = __float2bfloat16(oa[mi][nd][r] * inv);
        }
}

// ---------------- loss: merge per-block LSE partials ----------------
__global__ __launch_bounds__(256) void rowloss2_k(const float2* __restrict__ partials,
                                                  const float* __restrict__ logits,
                                                  const int* __restrict__ targets,
                                                  float* __restrict__ rowloss, int ntn) {
    __shared__ float red[4];
    int row = blockIdx.x;
    int tid = threadIdx.x;
    float m = -INFINITY, l = 0.f;
    if (tid < ntn) {
        float2 p = partials[(size_t)row * ntn + tid];
        m = p.x; l = p.y;
    }
    float mg = block_max256(m, red);
    float s = (tid < ntn) ? l * __expf(m - mg) : 0.f;
    s = block_sum256(s, red);
    if (tid == 0)
        rowloss[row] = mg + logf(s) - logits[(size_t)row * VV + targets[row]];
}

__global__ __launch_bounds__(256) void loss_final_k(const float* __restrict__ rowloss,
                                                    float* __restrict__ out) {
    __shared__ float red[4];
    float s = 0.f;
    for (int i = threadIdx.x; i < MROWS; i += 256) s += rowloss[i];
    s = block_sum256(s, red);
    if (threadIdx.x == 0) out[0] = s * (1.0f / MROWS);
}

// ---------------- launcher ----------------
extern "C" void kernel_launch(void* const* d_in, const int* in_sizes, int n_in,
                              void* d_out, int out_size, void* d_ws, size_t ws_size,
                              hipStream_t stream) {
    const int* idx      = (const int*)d_in[0];
    const int* targets  = (const int*)d_in[1];
    const float* tok    = (const float*)d_in[2];
    const float* pos    = (const float*)d_in[3];
    const float* Wq     = (const float*)d_in[4];
    const float* Wk     = (const float*)d_in[5];
    const float* Wv     = (const float*)d_in[6];
    const float* Wp     = (const float*)d_in[7];
    const float* bp     = (const float*)d_in[8];
    const float* W1     = (const float*)d_in[9];
    const float* b1     = (const float*)d_in[10];
    const float* W2     = (const float*)d_in[11];
    const float* b2     = (const float*)d_in[12];
    const float* ln1_g  = (const float*)d_in[13];
    const float* ln1_b  = (const float*)d_in[14];
    const float* ln2_g  = (const float*)d_in[15];
    const float* ln2_b  = (const float*)d_in[16];
    const float* lnf_g  = (const float*)d_in[17];
    const float* lnf_b  = (const float*)d_in[18];
    const float* Wlm    = (const float*)d_in[19];
    const float* blm    = (const float*)d_in[20];

    float* out = (float*)d_out;

    // ---- workspace carve ----
    char* w = (char*)d_ws;
    float* x = (float*)w;                             w += (size_t)MROWS * EE * 4;
    __hip_bfloat16* hbf = (__hip_bfloat16*)w;         w += (size_t)MROWS * EE * 2;
    __hip_bfloat16* qkv = (__hip_bfloat16*)w;         w += (size_t)MROWS * QS * 2;
    __hip_bfloat16* obf = (__hip_bfloat16*)w;         w += (size_t)MROWS * EE * 2;
    __hip_bfloat16* ff1 = (__hip_bfloat16*)w;         w += (size_t)MROWS * FFD * 2;
    float2* partials = (float2*)ff1;                  // aliases ff1: dead by LM-head time
    __hip_bfloat16* wlmT = (__hip_bfloat16*)w;        w += (size_t)VV * EE * 2;
    float* rowloss = (float*)w;                       w += (size_t)MROWS * 4 + 256;
    __hip_bfloat16* wbase = (__hip_bfloat16*)w;       // layer weights from here

    const size_t base_used = (size_t)(w - (char*)d_ws);
    const size_t per_layer_w = ((size_t)QS * EE + (size_t)EE * EE +
                                (size_t)FFD * EE + (size_t)EE * FFD) * 2;
    const bool hoist = ws_size >= base_used + per_layer_w * LAYERS;
    const int nlw = hoist ? LAYERS : 1;

    __hip_bfloat16* qkvwT = wbase;
    __hip_bfloat16* wpT   = qkvwT + (size_t)nlw * QS * EE;
    __hip_bfloat16* w1T   = wpT   + (size_t)nlw * EE * EE;
    __hip_bfloat16* w2T   = w1T   + (size_t)nlw * FFD * EE;

    dim3 blk(256);

    embed4_k<<<MROWS / 4, blk, 0, stream>>>(idx, tok, pos, x);

    if (hoist) {
        tconv_b_k<<<dim3(EE / 32, EE / 32, LAYERS), blk, 0, stream>>>(
            Wq, qkvwT, EE, EE, (size_t)EE * EE, (size_t)QS * EE);
        tconv_b_k<<<dim3(EE / 32, EE / 32, LAYERS), blk, 0, stream>>>(
            Wk, qkvwT + (size_t)EE * EE, EE, EE, (size_t)EE * EE, (size_t)QS * EE);
        tconv_b_k<<<dim3(EE / 32, EE / 32, LAYERS), blk, 0, stream>>>(
            Wv, qkvwT + (size_t)2 * EE * EE, EE, EE, (size_t)EE * EE, (size_t)QS * EE);
        tconv_b_k<<<dim3(EE / 32, EE / 32, LAYERS), blk, 0, stream>>>(
            Wp, wpT, EE, EE, (size_t)EE * EE, (size_t)EE * EE);
        tconv_b_k<<<dim3(FFD / 32, EE / 32, LAYERS), blk, 0, stream>>>(
            W1, w1T, EE, FFD, (size_t)EE * FFD, (size_t)FFD * EE);
        tconv_b_k<<<dim3(EE / 32, FFD / 32, LAYERS), blk, 0, stream>>>(
            W2, w2T, FFD, EE, (size_t)FFD * EE, (size_t)EE * FFD);
    }
    tconv_b_k<<<dim3(VV / 32, EE / 32, 1), blk, 0, stream>>>(Wlm, wlmT, EE, VV, 0, 0);

    for (int l = 0; l < LAYERS; ++l) {
        __hip_bfloat16* qkvwT_l = qkvwT + (hoist ? (size_t)l * QS * EE : 0);
        __hip_bfloat16* wpT_l   = wpT   + (hoist ? (size_t)l * EE * EE : 0);
        __hip_bfloat16* w1T_l   = w1T   + (hoist ? (size_t)l * FFD * EE : 0);
        __hip_bfloat16* w2T_l   = w2T   + (hoist ? (size_t)l * EE * FFD : 0);
        if (!hoist) {
            tconv_b_k<<<dim3(EE / 32, EE / 32, 1), blk, 0, stream>>>(
                Wq + (size_t)l * EE * EE, qkvwT_l, EE, EE, 0, 0);
            tconv_b_k<<<dim3(EE / 32, EE / 32, 1), blk, 0, stream>>>(
                Wk + (size_t)l * EE * EE, qkvwT_l + (size_t)EE * EE, EE, EE, 0, 0);
            tconv_b_k<<<dim3(EE / 32, EE / 32, 1), blk, 0, stream>>>(
                Wv + (size_t)l * EE * EE, qkvwT_l + (size_t)2 * EE * EE, EE, EE, 0, 0);
            tconv_b_k<<<dim3(EE / 32, EE / 32, 1), blk, 0, stream>>>(
                Wp + (size_t)l * EE * EE, wpT_l, EE, EE, 0, 0);
            tconv_b_k<<<dim3(FFD / 32, EE / 32, 1), blk, 0, stream>>>(
                W1 + (size_t)l * EE * FFD, w1T_l, EE, FFD, 0, 0);
            tconv_b_k<<<dim3(EE / 32, FFD / 32, 1), blk, 0, stream>>>(
                W2 + (size_t)l * FFD * EE, w2T_l, FFD, EE, 0, 0);
        }

        ln4_k<<<MROWS / 4, blk, 0, stream>>>(x, ln1_g + l * EE, ln1_b + l * EE, hbf);
        mgemm_k<false, false, false, true, 4><<<dim3((MROWS / 128) * (QS / 128)), blk, 0, stream>>>(
            hbf, qkvwT_l, nullptr, qkv, MROWS, QS, EE, QS / 128);
        fattn_k<<<dim3(BB * HH, TT / QBLK), blk, 0, stream>>>(qkv, obf);
        mgemm_k<true, false, true, false, 2><<<dim3((MROWS / 64) * (EE / 128)), blk, 0, stream>>>(
            obf, wpT_l, bp + l * EE, x, MROWS, EE, EE, EE / 128);
        ln4_k<<<MROWS / 4, blk, 0, stream>>>(x, ln2_g + l * EE, ln2_b + l * EE, hbf);
        mgemm_k<true, true, false, true, 4><<<dim3((MROWS / 128) * (FFD / 128)), blk, 0, stream>>>(
            hbf, w1T_l, b1 + l * FFD, ff1, MROWS, FFD, EE, FFD / 128);
        mgemm_k<true, false, true, false, 2><<<dim3((MROWS / 64) * (EE / 128)), blk, 0, stream>>>(
            ff1, w2T_l, b2 + l * EE, x, MROWS, EE, FFD, EE / 128);
    }

    ln4_k<<<MROWS / 4, blk, 0, stream>>>(x, lnf_g, lnf_b, hbf);
    mgemm256_k<true, false, false, true><<<dim3((MROWS / 256) * (VV / 256)), dim3(512), 0, stream>>>(
        hbf, wlmT, blm, out, MROWS, VV, EE, VV / 256, NPART, partials);

    rowloss2_k<<<MROWS, blk, 0, stream>>>(partials, out, targets, rowloss, NPART);
    loss_final_k<<<1, blk, 0, stream>>>(rowloss, out + (size_t)MROWS * VV);
}